// Round 6
// baseline (1396.330 us; speedup 1.0000x reference)
//
#include <hip/hip_runtime.h>
#include <cstdint>
#include <cstddef>

typedef unsigned short u16;
typedef __attribute__((ext_vector_type(8))) __bf16 bf16x8;
typedef __attribute__((ext_vector_type(4))) float f32x4;

__device__ __forceinline__ f32x4 mfma_16x16x32(bf16x8 a, bf16x8 b, f32x4 c) {
  return __builtin_amdgcn_mfma_f32_16x16x32_bf16(a, b, c, 0, 0, 0);
}

__device__ __forceinline__ u16 f2bf(float f) {
  union { float f; uint32_t u; } c; c.f = f;
  uint32_t u = c.u + 0x7FFFu + ((c.u >> 16) & 1u);
  return (u16)(u >> 16);
}

__device__ __forceinline__ float bf2f(u16 x) {
  union { uint32_t u; float f; } c; c.u = ((uint32_t)x) << 16;
  return c.f;
}

__device__ __forceinline__ void gload_lds16(const void* g, void* l) {
  __builtin_amdgcn_global_load_lds(
      (__attribute__((address_space(1))) void*)(uintptr_t)g,
      (__attribute__((address_space(3))) void*)l, 16, 0, 0);
}

// ===========================================================================
// Ring GEMM v3.  C[M,N] = A[M,K] @ Bt[N,K]^T (+bias)(+C if ACC)(ReLU)
// BM=256, BN=128, BK=32. 256 threads = 4 waves (2x2), wave tile 128x64.
// 3-slot LDS ring (72 KB -> 2 blocks/CU), prefetch dist 2, counted vmcnt(6),
// ONE barrier per K-step. 23 B/kFLOP LDS-read traffic (vs 31 for the old
// 128x256/8-wave shape) — below the 128 B/cy LDS ceiling at full MFMA rate.
// Swizzle sigma(r)=(r>>1)&3 on 16B granules, applied on BOTH the pre-swizzled
// global source of global_load_lds and the ds_read offset (round-4, verified
// conflict-free).
// ===========================================================================
template<bool OUT_BF16, bool RELU, bool ACC>
__global__ __launch_bounds__(256, 2) void gemm_ring3(
    const u16* __restrict__ A, int lda, const u16* __restrict__ Bt, int ldb,
    const float* __restrict__ bias, void* Cout, int ldc,
    int M, int N, int K)
{
  constexpr int BM = 256, BN = 128;
  constexpr int SLOT = (BM + BN) * 32;      // 12288 elems = 24 KB
  __shared__ u16 ring[3 * SLOT];            // 72 KB

  const int tid = threadIdx.x;
  const int lane = tid & 63, wave = tid >> 6;
  const int wm = wave >> 1, wn = wave & 1;
  const int m0 = blockIdx.x * BM, n0 = blockIdx.y * BN;

  // staging: A = 1024 chunks of 16B (4/row), B = 512 chunks (4/row).
  // chunk c: row r=c>>2, physical granule q=c&3 receives logical granule
  // q ^ ((r>>1)&3) -> pre-swizzled global source.
  const u16* gA[4];
  #pragma unroll
  for (int i = 0; i < 4; i++) {
    int c = tid + i * 256, r = c >> 2;
    gA[i] = A + (size_t)(m0 + r) * lda + (((c & 3) ^ ((r >> 1) & 3)) * 8);
  }
  const u16* gB[2];
  #pragma unroll
  for (int i = 0; i < 2; i++) {
    int c = tid + i * 256, r = c >> 2;
    gB[i] = Bt + (size_t)(n0 + r) * ldb + (((c & 3) ^ ((r >> 1) & 3)) * 8);
  }

  const int NK = K >> 5;

  auto STAGE = [&](int s, int ph) {
    u16* Sb = &ring[ph * SLOT];
    const int ko = s * 32;
    #pragma unroll
    for (int i = 0; i < 4; i++)
      gload_lds16(gA[i] + ko, Sb + (tid + i * 256) * 8);
    #pragma unroll
    for (int i = 0; i < 2; i++)
      gload_lds16(gB[i] + ko, Sb + BM * 32 + (tid + i * 256) * 8);
  };

  // ds_read lane constants: logical granule g lives at physical g^((fr>>1)&3)
  const int fr = lane & 15, g = lane >> 4;
  const int foff = fr * 32 + ((g ^ ((fr >> 1) & 3)) * 8);

  f32x4 acc[8][4];
  #pragma unroll
  for (int m = 0; m < 8; m++)
    #pragma unroll
    for (int n = 0; n < 4; n++) acc[m][n] = f32x4{0.f, 0.f, 0.f, 0.f};

  // prologue: stage slots 0,1 (dist 2)
  STAGE(0, 0);
  if (NK > 1) {
    STAGE(1, 1);
    asm volatile("s_waitcnt vmcnt(6)" ::: "memory");   // slot0's 6 loads done
  } else {
    asm volatile("s_waitcnt vmcnt(0)" ::: "memory");
  }
  __builtin_amdgcn_s_barrier();
  __builtin_amdgcn_sched_barrier(0);

  int phys = 0;                 // physical slot of step s
  int physN = (NK > 1) ? 1 : 0; // scratch for next stage slot
  for (int s = 0; s < NK; ++s) {
    const u16* As = &ring[phys * SLOT];
    const u16* Bs = As + BM * 32;

    bf16x8 bf[4];
    #pragma unroll
    for (int n = 0; n < 4; n++)
      bf[n] = *(const bf16x8*)(Bs + (wn * 64 + n * 16) * 32 + foff);
    bf16x8 af[8];
    #pragma unroll
    for (int m = 0; m < 8; m++)
      af[m] = *(const bf16x8*)(As + (wm * 128 + m * 16) * 32 + foff);

    // stage slot s+2 into the slot step s-1 just vacated
    if (s + 2 < NK) {
      int ph2 = physN + 1 == 3 ? 0 : physN + 1;
      STAGE(s + 2, ph2);
      physN = ph2;
    }

    __builtin_amdgcn_s_setprio(1);
    #pragma unroll
    for (int m = 0; m < 8; m++)
      #pragma unroll
      for (int n = 0; n < 4; n++)
        acc[m][n] = mfma_16x16x32(af[m], bf[n], acc[m][n]);
    __builtin_amdgcn_s_setprio(0);

    // RAW: slot s+1 fully staged (counted; drains only at the tail)
    if (s + 2 < NK) asm volatile("s_waitcnt vmcnt(6)" ::: "memory");
    else            asm volatile("s_waitcnt vmcnt(0)" ::: "memory");
    // WAR: this step's ds_reads complete before next step stages over s-1/s
    asm volatile("s_waitcnt lgkmcnt(0)" ::: "memory");
    __builtin_amdgcn_sched_barrier(0);
    __builtin_amdgcn_s_barrier();
    __builtin_amdgcn_sched_barrier(0);

    phys = phys + 1 == 3 ? 0 : phys + 1;
  }

  #pragma unroll
  for (int n = 0; n < 4; n++) {
    const int gcol = n0 + wn * 64 + n * 16 + fr;
    const float bv = bias ? bias[gcol] : 0.f;
    #pragma unroll
    for (int m = 0; m < 8; m++) {
      #pragma unroll
      for (int r = 0; r < 4; r++) {
        const int grow = m0 + wm * 128 + m * 16 + g * 4 + r;
        float v = acc[m][n][r] + bv;
        if (ACC) v += bf2f(((const u16*)Cout)[(size_t)grow * ldc + gcol]);
        if (RELU) v = fmaxf(v, 0.f);
        if (OUT_BF16) ((u16*)Cout)[(size_t)grow * ldc + gcol] = f2bf(v);
        else         ((float*)Cout)[(size_t)grow * ldc + gcol] = v;
      }
    }
  }
}

// ---------------------------------------------------------------------------
// Small GEMM (M=400 K/V projections): 128x128 tile, BK=32.
// TRANS=true: store C transposed into vtb[((b*16+h)*64+d)*128 + j]
// ---------------------------------------------------------------------------
template<bool TRANS>
__global__ __launch_bounds__(256, 2) void gemm_bt(
    const u16* __restrict__ A, int lda, const u16* __restrict__ Bt, int ldb,
    const float* __restrict__ bias, u16* Cout, int ldc,
    int M, int N, int K)
{
  __shared__ u16 ldsA[128 * 32];
  __shared__ u16 ldsB[128 * 32];

  const int tid = threadIdx.x;
  const int lane = tid & 63, wave = tid >> 6;
  const int wr = wave >> 1, wc = wave & 1;
  const int m0 = blockIdx.x * 128, n0 = blockIdx.y * 128;

  const int c0 = tid, c1 = tid + 256;
  const int ar0 = c0 >> 2, ak0 = (c0 & 3) * 8;
  const int ar1 = c1 >> 2, ak1 = (c1 & 3) * 8;

  const bool av0 = (m0 + ar0) < M;
  const bool av1 = (m0 + ar1) < M;
  const u16* Ag0 = A + (size_t)(m0 + ar0) * lda + ak0;
  const u16* Ag1 = A + (size_t)(m0 + ar1) * lda + ak1;
  const u16* Bg0 = Bt + (size_t)(n0 + ar0) * ldb + ak0;
  const u16* Bg1 = Bt + (size_t)(n0 + ar1) * ldb + ak1;

  f32x4 acc[4][4] = {};
  const int fr = lane & 15, fo = (lane >> 4) * 8;

  for (int k0 = 0; k0 < K; k0 += 32) {
    if (av0) gload_lds16(Ag0 + k0, &ldsA[c0 * 8]);
    if (av1) gload_lds16(Ag1 + k0, &ldsA[c1 * 8]);
    gload_lds16(Bg0 + k0, &ldsB[c0 * 8]);
    gload_lds16(Bg1 + k0, &ldsB[c1 * 8]);
    asm volatile("s_waitcnt vmcnt(0)" ::: "memory");
    __syncthreads();

    bf16x8 af[4], bfr[4];
    #pragma unroll
    for (int m = 0; m < 4; m++)
      af[m] = *(const bf16x8*)&ldsA[(wr * 64 + m * 16 + fr) * 32 + fo];
    #pragma unroll
    for (int n = 0; n < 4; n++)
      bfr[n] = *(const bf16x8*)&ldsB[(wc * 64 + n * 16 + fr) * 32 + fo];
    #pragma unroll
    for (int m = 0; m < 4; m++)
      #pragma unroll
      for (int n = 0; n < 4; n++)
        acc[m][n] = mfma_16x16x32(af[m], bfr[n], acc[m][n]);
    __syncthreads();
  }

  const int g = lane >> 4;
  #pragma unroll
  for (int m = 0; m < 4; m++) {
    #pragma unroll
    for (int n = 0; n < 4; n++) {
      const int gcol = n0 + wc * 64 + n * 16 + fr;
      const float bv = bias[gcol];
      #pragma unroll
      for (int r = 0; r < 4; r++) {
        const int grow = m0 + wr * 64 + m * 16 + g * 4 + r;
        if (grow < M) {
          float v = acc[m][n][r] + bv;
          if (TRANS) {
            int bb = grow / 100, jj = grow - bb * 100;
            int h = gcol >> 6, d = gcol & 63;
            Cout[(size_t)(((bb * 16 + h) * 64 + d)) * 128 + jj] = f2bf(v);
          } else {
            Cout[(size_t)grow * ldc + gcol] = f2bf(v);
          }
        }
      }
    }
  }
}

// ---------------------------------------------------------------------------
// Weight transpose+convert: src f32 [K][N] -> dst bf16 [N][K]
// ---------------------------------------------------------------------------
__global__ void wconv_t(const float* __restrict__ src, u16* __restrict__ dst,
                        int K, int N)
{
  __shared__ float tile[32][33];
  const int n0 = blockIdx.x * 32, k0 = blockIdx.y * 32;
  const int tx = threadIdx.x, ty = threadIdx.y;
  #pragma unroll
  for (int i = 0; i < 4; i++)
    tile[ty + i * 8][tx] = src[(size_t)(k0 + ty + i * 8) * N + n0 + tx];
  __syncthreads();
  #pragma unroll
  for (int i = 0; i < 4; i++)
    dst[(size_t)(n0 + ty + i * 8) * K + k0 + tx] = f2bf(tile[tx][ty + i * 8]);
}

// ---------------------------------------------------------------------------
// Positional encoding add -> bf16 only
// ---------------------------------------------------------------------------
__global__ __launch_bounds__(256) void pe_video_k(const float* __restrict__ video,
                                                  u16* __restrict__ vbf)
{
  const int r = blockIdx.x;
  const int s = r & 2047;
  const int d0 = threadIdx.x * 4;
  const size_t base = (size_t)r * 1024 + d0;
  float4 v = *(const float4*)&video[base];
  const float coef = -9.210340371976184f / 1024.f;
  float o[4];
  float in[4] = {v.x, v.y, v.z, v.w};
  #pragma unroll
  for (int i = 0; i < 4; i++) {
    int d = d0 + i;
    int j = d >> 1;
    float dv = expf((float)(2 * j) * coef);
    float arg = (float)s * dv;
    float pe = (d & 1) ? cosf(arg) : sinf(arg);
    o[i] = in[i] + pe;
  }
  uint2 pk;
  pk.x = (uint32_t)f2bf(o[0]) | ((uint32_t)f2bf(o[1]) << 16);
  pk.y = (uint32_t)f2bf(o[2]) | ((uint32_t)f2bf(o[3]) << 16);
  *(uint2*)&vbf[base] = pk;
}

__global__ __launch_bounds__(128) void pe_text_k(const float* __restrict__ text,
                                                 u16* __restrict__ tbf)
{
  const int r = blockIdx.x;
  const int s = r % 100;
  const int d0 = threadIdx.x * 4;
  const size_t base = (size_t)r * 512 + d0;
  float4 v = *(const float4*)&text[base];
  const float coef = -9.210340371976184f / 512.f;
  float o[4];
  float in[4] = {v.x, v.y, v.z, v.w};
  #pragma unroll
  for (int i = 0; i < 4; i++) {
    int d = d0 + i;
    int j = d >> 1;
    float dv = expf((float)(2 * j) * coef);
    float arg = (float)s * dv;
    float pe = (d & 1) ? cosf(arg) : sinf(arg);
    o[i] = in[i] + pe;
  }
  uint2 pk;
  pk.x = (uint32_t)f2bf(o[0]) | ((uint32_t)f2bf(o[1]) << 16);
  pk.y = (uint32_t)f2bf(o[2]) | ((uint32_t)f2bf(o[3]) << 16);
  *(uint2*)&tbf[base] = pk;
}

// ---------------------------------------------------------------------------
// LayerNorm, bf16 residual stream: x' = LN(x + delta)*g+b
// ---------------------------------------------------------------------------
template<bool LAST>
__global__ __launch_bounds__(256) void ln2(const u16* __restrict__ xin,
                                           const u16* __restrict__ delta,
                                           const float* __restrict__ gamma,
                                           const float* __restrict__ beta,
                                           u16* __restrict__ xbf,
                                           float* __restrict__ fout)
{
  const int row = blockIdx.x;
  const size_t base = (size_t)row * 1024;
  const int t = threadIdx.x;
  const int d0 = t * 4;
  uint2 xv = *(const uint2*)&xin[base + d0];
  uint2 dv = *(const uint2*)&delta[base + d0];
  float v0 = bf2f((u16)(xv.x & 0xFFFF)) + bf2f((u16)(dv.x & 0xFFFF));
  float v1 = bf2f((u16)(xv.x >> 16))    + bf2f((u16)(dv.x >> 16));
  float v2 = bf2f((u16)(xv.y & 0xFFFF)) + bf2f((u16)(dv.y & 0xFFFF));
  float v3 = bf2f((u16)(xv.y >> 16))    + bf2f((u16)(dv.y >> 16));
  float s = v0 + v1 + v2 + v3;
  float q = v0 * v0 + v1 * v1 + v2 * v2 + v3 * v3;
  #pragma unroll
  for (int d = 32; d >= 1; d >>= 1) { s += __shfl_xor(s, d); q += __shfl_xor(q, d); }
  __shared__ float red[8];
  const int lane = t & 63, w = t >> 6;
  if (lane == 0) { red[w] = s; red[4 + w] = q; }
  __syncthreads();
  float S = red[0] + red[1] + red[2] + red[3];
  float Qs = red[4] + red[5] + red[6] + red[7];
  const float mu = S * (1.f / 1024.f);
  const float var = Qs * (1.f / 1024.f) - mu * mu;
  const float rs = rsqrtf(var + 1e-5f);
  float4 gv = *(const float4*)&gamma[d0];
  float4 bv = *(const float4*)&beta[d0];
  float o0 = (v0 - mu) * rs * gv.x + bv.x;
  float o1 = (v1 - mu) * rs * gv.y + bv.y;
  float o2 = (v2 - mu) * rs * gv.z + bv.z;
  float o3 = (v3 - mu) * rs * gv.w + bv.w;
  if (LAST) {
    *(float4*)&fout[base + d0] = make_float4(o0, o1, o2, o3);
  } else {
    uint2 pk;
    pk.x = (uint32_t)f2bf(o0) | ((uint32_t)f2bf(o1) << 16);
    pk.y = (uint32_t)f2bf(o2) | ((uint32_t)f2bf(o3) << 16);
    *(uint2*)&xbf[base + d0] = pk;
  }
}

// ---------------------------------------------------------------------------
// Cross attention v2 (verified): K from global (L2), V pre-transposed,
// P via LDS intra-wave, zero barriers.
// ---------------------------------------------------------------------------
__global__ __launch_bounds__(256) void attn_v2(
    const u16* __restrict__ Q, const u16* __restrict__ Kb,
    const u16* __restrict__ Vtb, const int* __restrict__ mask,
    u16* __restrict__ Out)
{
  __shared__ u16 ldsP[64 * 136];

  const int tid = threadIdx.x, lane = tid & 63, w = tid >> 6;
  const int qb = blockIdx.x, bh = blockIdx.y;
  const int b = bh >> 4, h = bh & 15;
  const int fr = lane & 15, g = lane >> 4, fo = g * 8;

  const size_t qrow = (size_t)(b * 2048 + qb * 64 + w * 16 + fr) * 1024 + h * 64;
  bf16x8 qf0 = *(const bf16x8*)&Q[qrow + fo];
  bf16x8 qf1 = *(const bf16x8*)&Q[qrow + 32 + fo];

  float madd[7];
  #pragma unroll
  for (int t = 0; t < 7; t++) {
    int col = t * 16 + fr;
    int mv = (col < 100) ? mask[b * 100 + col] : 0;
    madd[t] = mv ? 0.f : -1e30f;
  }

  float sc[7][4];
  #pragma unroll
  for (int t = 0; t < 7; t++) {
    int col = t * 16 + fr;
    int jr = (col < 100) ? col : 99;
    const u16* kp = Kb + (size_t)(b * 100 + jr) * 1024 + h * 64;
    bf16x8 kf0 = *(const bf16x8*)&kp[fo];
    bf16x8 kf1 = *(const bf16x8*)&kp[32 + fo];
    f32x4 a = {};
    a = mfma_16x16x32(qf0, kf0, a);
    a = mfma_16x16x32(qf1, kf1, a);
    #pragma unroll
    for (int r = 0; r < 4; r++)
      sc[t][r] = a[r] * 0.125f + madd[t];
  }

  #pragma unroll
  for (int r = 0; r < 4; r++) {
    float m = sc[0][r];
    #pragma unroll
    for (int t = 1; t < 7; t++) m = fmaxf(m, sc[t][r]);
    #pragma unroll
    for (int d = 8; d >= 1; d >>= 1) m = fmaxf(m, __shfl_xor(m, d));
    float ssum = 0.f;
    #pragma unroll
    for (int t = 0; t < 7; t++) { float p = __expf(sc[t][r] - m); sc[t][r] = p; ssum += p; }
    #pragma unroll
    for (int d = 8; d >= 1; d >>= 1) ssum += __shfl_xor(ssum, d);
    float is = 1.f / ssum;
    #pragma unroll
    for (int t = 0; t < 7; t++)
      ldsP[(w * 16 + g * 4 + r) * 136 + t * 16 + fr] = f2bf(sc[t][r] * is);
  }
  {
    u16* zp = &ldsP[(w * 16 + fr) * 136 + 112 + g * 6];
    #pragma unroll
    for (int i = 0; i < 6; i++) zp[i] = 0;
  }

  bf16x8 pa[4];
  #pragma unroll
  for (int kk = 0; kk < 4; kk++)
    pa[kk] = *(const bf16x8*)&ldsP[(w * 16 + fr) * 136 + kk * 32 + fo];
  const u16* vtbase = Vtb + (size_t)bh * 64 * 128;
  #pragma unroll
  for (int nt = 0; nt < 4; nt++) {
    f32x4 a = {};
    #pragma unroll
    for (int kk = 0; kk < 4; kk++) {
      bf16x8 vf = *(const bf16x8*)&vtbase[(size_t)(nt * 16 + fr) * 128 + kk * 32 + fo];
      a = mfma_16x16x32(pa[kk], vf, a);
    }
    #pragma unroll
    for (int r = 0; r < 4; r++) {
      size_t orow = (size_t)(b * 2048 + qb * 64 + w * 16 + g * 4 + r) * 1024 + h * 64 + nt * 16 + fr;
      Out[orow] = f2bf(a[r]);
    }
  }
}

// ---------------------------------------------------------------------------
extern "C" void kernel_launch(void* const* d_in, const int* in_sizes, int n_in,
                              void* d_out, int out_size, void* d_ws, size_t ws_size,
                              hipStream_t stream) {
  const float* video = (const float*)d_in[0];
  const float* text  = (const float*)d_in[1];
  const int*   text_mask = (const int*)d_in[2];
  const float* Wq_w = (const float*)d_in[3];
  const float* Wq_b = (const float*)d_in[4];
  const float* Wk_w = (const float*)d_in[5];
  const float* Wk_b = (const float*)d_in[6];
  const float* Wv_w = (const float*)d_in[7];
  const float* Wv_b = (const float*)d_in[8];
  const float* Wo_w = (const float*)d_in[9];
  const float* Wo_b = (const float*)d_in[10];
  const float* fc1_w = (const float*)d_in[11];
  const float* fc1_b = (const float*)d_in[12];
  const float* fc2_w = (const float*)d_in[13];
  const float* fc2_b = (const float*)d_in[14];
  const float* n2_g = (const float*)d_in[15];
  const float* n2_b = (const float*)d_in[16];
  const float* n3_g = (const float*)d_in[17];
  const float* n3_b = (const float*)d_in[18];

  char* ws = (char*)d_ws;
  size_t off = 0;
  auto alloc = [&](size_t bytes) {
    char* p = ws + off;
    off += (bytes + 255) & ~(size_t)255;
    return p;
  };
  u16* vbf = (u16*)alloc((size_t)8192 * 1024 * 2);     // 16 MB residual (bf16)
  u16* tbf = (u16*)alloc((size_t)400 * 512 * 2);
  u16* wqT = (u16*)alloc((size_t)1024 * 1024 * 2);
  u16* wkT = (u16*)alloc((size_t)1024 * 512 * 2);
  u16* wvT = (u16*)alloc((size_t)1024 * 512 * 2);
  u16* woT = (u16*)alloc((size_t)1024 * 1024 * 2);
  u16* f1T = (u16*)alloc((size_t)4096 * 1024 * 2);
  u16* f2T = (u16*)alloc((size_t)1024 * 4096 * 2);
  char* S = alloc((size_t)35192832);                   // union scratch
  u16* qbf  = (u16*)S;
  u16* kbf  = (u16*)(S + 16777216);
  u16* abf  = (u16*)(S + 16777216 + 1638400);
  u16* h1c  = (u16*)S;
  u16* vtb  = (u16*)alloc((size_t)64 * 64 * 128 * 2);  // 2 MB V^T (not aliased)
  u16* dbf  = (u16*)alloc((size_t)8192 * 1024 * 2);
  float* fout = (float*)d_out;

  hipMemsetAsync(vtb, 0, (size_t)64 * 64 * 128 * 2, stream);

  pe_video_k<<<8192, 256, 0, stream>>>(video, vbf);
  pe_text_k<<<400, 128, 0, stream>>>(text, tbf);

  dim3 tb(32, 8, 1);
  for (int l = 0; l < 4; ++l) {
    wconv_t<<<dim3(32, 32), tb, 0, stream>>>(Wq_w + (size_t)l * 1024 * 1024, wqT, 1024, 1024);
    wconv_t<<<dim3(32, 16), tb, 0, stream>>>(Wk_w + (size_t)l * 512 * 1024, wkT, 512, 1024);
    wconv_t<<<dim3(32, 16), tb, 0, stream>>>(Wv_w + (size_t)l * 512 * 1024, wvT, 512, 1024);
    wconv_t<<<dim3(32, 32), tb, 0, stream>>>(Wo_w + (size_t)l * 1024 * 1024, woT, 1024, 1024);
    wconv_t<<<dim3(128, 32), tb, 0, stream>>>(fc1_w + (size_t)l * 1024 * 4096, f1T, 1024, 4096);
    wconv_t<<<dim3(32, 128), tb, 0, stream>>>(fc2_w + (size_t)l * 4096 * 1024, f2T, 4096, 1024);

    gemm_ring3<true, false, false><<<dim3(32, 8), 256, 0, stream>>>(
        vbf, 1024, wqT, 1024, Wq_b + l * 1024, qbf, 1024, 8192, 1024, 1024);
    gemm_bt<false><<<dim3(4, 8), 256, 0, stream>>>(
        tbf, 512, wkT, 512, Wk_b + l * 1024, kbf, 1024, 400, 1024, 512);
    gemm_bt<true><<<dim3(4, 8), 256, 0, stream>>>(
        tbf, 512, wvT, 512, Wv_b + l * 1024, vtb, 1024, 400, 1024, 512);
    attn_v2<<<dim3(32, 64), 256, 0, stream>>>(qbf, kbf, vtb, text_mask, abf);
    gemm_ring3<true, false, false><<<dim3(32, 8), 256, 0, stream>>>(
        abf, 1024, woT, 1024, Wo_b + l * 1024, dbf, 1024, 8192, 1024, 1024);
    ln2<false><<<8192, 256, 0, stream>>>(vbf, dbf, n2_g + l * 1024, n2_b + l * 1024, vbf, nullptr);

    for (int c = 0; c < 2; ++c) {
      gemm_ring3<true, true, false><<<dim3(32, 16), 256, 0, stream>>>(
          vbf, 1024, f1T + (size_t)c * 2048 * 1024, 1024,
          fc1_b + l * 4096 + c * 2048, h1c, 2048, 8192, 2048, 1024);
      if (c == 0)
        gemm_ring3<true, false, false><<<dim3(32, 8), 256, 0, stream>>>(
            h1c, 2048, f2T + (size_t)c * 2048, 4096,
            fc2_b + l * 1024, dbf, 1024, 8192, 1024, 2048);
      else
        gemm_ring3<true, false, true><<<dim3(32, 8), 256, 0, stream>>>(
            h1c, 2048, f2T + (size_t)c * 2048, 4096,
            nullptr, dbf, 1024, 8192, 1024, 2048);
    }
    if (l == 3)
      ln2<true><<<8192, 256, 0, stream>>>(vbf, dbf, n3_g + l * 1024, n3_b + l * 1024, nullptr, fout);
    else
      ln2<false><<<8192, 256, 0, stream>>>(vbf, dbf, n3_g + l * 1024, n3_b + l * 1024, vbf, nullptr);
  }
}

// Round 7
// 1358.062 us; speedup vs baseline: 1.0282x; 1.0282x over previous
//
#include <hip/hip_runtime.h>
#include <cstdint>
#include <cstddef>

typedef unsigned short u16;
typedef __attribute__((ext_vector_type(8))) __bf16 bf16x8;
typedef __attribute__((ext_vector_type(4))) float f32x4;

__device__ __forceinline__ f32x4 mfma_16x16x32(bf16x8 a, bf16x8 b, f32x4 c) {
  return __builtin_amdgcn_mfma_f32_16x16x32_bf16(a, b, c, 0, 0, 0);
}

__device__ __forceinline__ u16 f2bf(float f) {
  union { float f; uint32_t u; } c; c.f = f;
  uint32_t u = c.u + 0x7FFFu + ((c.u >> 16) & 1u);
  return (u16)(u >> 16);
}

__device__ __forceinline__ float bf2f(u16 x) {
  union { uint32_t u; float f; } c; c.u = ((uint32_t)x) << 16;
  return c.f;
}

__device__ __forceinline__ void gload_lds16(const void* g, void* l) {
  __builtin_amdgcn_global_load_lds(
      (__attribute__((address_space(1))) void*)(uintptr_t)g,
      (__attribute__((address_space(3))) void*)l, 16, 0, 0);
}

// ===========================================================================
// Ring GEMM v4.  C[M,N] = A[M,K] @ Bt[N,K]^T (+bias)(+C if ACC)(ReLU)
// BM=128, BN=128, BK=32. 256 threads = 4 waves (2x2), wave tile 64x64.
// 3-slot LDS ring (48 KB -> 3 blocks/CU co-resident; grids are 512-1024
// blocks -> 2-3 blocks/CU => 2-3 waves/SIMD so barrier drains overlap across
// blocks — the m97 mechanism; round-6 lost this with 1 block/CU).
// Counted vmcnt: LPT=4 loads/thread/stage, prefetch dist 2, steady vmcnt(4).
// Swizzle sigma(r)=(r>>1)&3 on 16B granules, applied on BOTH the pre-swizzled
// global source of global_load_lds and the ds_read offset (verified: bank
// conflicts == 0 in rounds 5/6).
// ===========================================================================
template<bool OUT_BF16, bool RELU, bool ACC>
__global__ __launch_bounds__(256, 2) void gemm_ring4(
    const u16* __restrict__ A, int lda, const u16* __restrict__ Bt, int ldb,
    const float* __restrict__ bias, void* Cout, int ldc,
    int M, int N, int K)
{
  constexpr int BM = 128, BN = 128;
  constexpr int SLOT = (BM + BN) * 32;      // 8192 elems = 16 KB
  __shared__ u16 ring[3 * SLOT];            // 48 KB

  const int tid = threadIdx.x;
  const int lane = tid & 63, wave = tid >> 6;
  const int wm = wave >> 1, wn = wave & 1;
  const int m0 = blockIdx.x * BM, n0 = blockIdx.y * BN;

  // staging: A and B each 512 chunks of 16B (4/row); thread does 2 of each.
  // chunk c: row r=c>>2, physical granule q=c&3 receives logical granule
  // q ^ ((r>>1)&3)  -> pre-swizzled global source.
  const u16* gA[2];
  const u16* gB[2];
  #pragma unroll
  for (int i = 0; i < 2; i++) {
    int c = tid + i * 256, r = c >> 2;
    gA[i] = A + (size_t)(m0 + r) * lda + (((c & 3) ^ ((r >> 1) & 3)) * 8);
    gB[i] = Bt + (size_t)(n0 + r) * ldb + (((c & 3) ^ ((r >> 1) & 3)) * 8);
  }

  const int NK = K >> 5;

  auto STAGE = [&](int s, int ph) {
    u16* Sb = &ring[ph * SLOT];
    const int ko = s * 32;
    #pragma unroll
    for (int i = 0; i < 2; i++)
      gload_lds16(gA[i] + ko, Sb + (tid + i * 256) * 8);
    #pragma unroll
    for (int i = 0; i < 2; i++)
      gload_lds16(gB[i] + ko, Sb + BM * 32 + (tid + i * 256) * 8);
  };

  // ds_read lane constants: logical granule g lives at physical g^((fr>>1)&3)
  const int fr = lane & 15, g = lane >> 4;
  const int foff = fr * 32 + ((g ^ ((fr >> 1) & 3)) * 8);

  f32x4 acc[4][4];
  #pragma unroll
  for (int m = 0; m < 4; m++)
    #pragma unroll
    for (int n = 0; n < 4; n++) acc[m][n] = f32x4{0.f, 0.f, 0.f, 0.f};

  // prologue: stage slots 0,1 (prefetch dist 2)
  STAGE(0, 0);
  if (NK > 1) {
    STAGE(1, 1);
    asm volatile("s_waitcnt vmcnt(4)" ::: "memory");   // slot0's 4 loads done
  } else {
    asm volatile("s_waitcnt vmcnt(0)" ::: "memory");
  }
  __builtin_amdgcn_s_barrier();
  __builtin_amdgcn_sched_barrier(0);

  int phys = 0;
  for (int s = 0; s < NK; ++s) {
    const u16* As = &ring[phys * SLOT];
    const u16* Bs = As + BM * 32;

    bf16x8 bf[4];
    #pragma unroll
    for (int n = 0; n < 4; n++)
      bf[n] = *(const bf16x8*)(Bs + (wn * 64 + n * 16) * 32 + foff);
    bf16x8 af[4];
    #pragma unroll
    for (int m = 0; m < 4; m++)
      af[m] = *(const bf16x8*)(As + (wm * 64 + m * 16) * 32 + foff);

    // stage slot s+2 into the slot vacated at step s-1
    if (s + 2 < NK) {
      int ph2 = phys + 2; if (ph2 >= 3) ph2 -= 3;
      STAGE(s + 2, ph2);
    }

    __builtin_amdgcn_s_setprio(1);
    #pragma unroll
    for (int m = 0; m < 4; m++)
      #pragma unroll
      for (int n = 0; n < 4; n++)
        acc[m][n] = mfma_16x16x32(af[m], bf[n], acc[m][n]);
    __builtin_amdgcn_s_setprio(0);

    // RAW: slot s+1 fully staged (counted; only the tail drains)
    if (s + 2 < NK) asm volatile("s_waitcnt vmcnt(4)" ::: "memory");
    else            asm volatile("s_waitcnt vmcnt(0)" ::: "memory");
    // WAR: this step's ds_reads complete before the slot is re-staged
    asm volatile("s_waitcnt lgkmcnt(0)" ::: "memory");
    __builtin_amdgcn_sched_barrier(0);
    __builtin_amdgcn_s_barrier();
    __builtin_amdgcn_sched_barrier(0);

    phys = phys + 1 == 3 ? 0 : phys + 1;
  }

  #pragma unroll
  for (int n = 0; n < 4; n++) {
    const int gcol = n0 + wn * 64 + n * 16 + fr;
    const float bv = bias ? bias[gcol] : 0.f;
    #pragma unroll
    for (int m = 0; m < 4; m++) {
      #pragma unroll
      for (int r = 0; r < 4; r++) {
        const int grow = m0 + wm * 64 + m * 16 + g * 4 + r;
        float v = acc[m][n][r] + bv;
        if (ACC) v += bf2f(((const u16*)Cout)[(size_t)grow * ldc + gcol]);
        if (RELU) v = fmaxf(v, 0.f);
        if (OUT_BF16) ((u16*)Cout)[(size_t)grow * ldc + gcol] = f2bf(v);
        else         ((float*)Cout)[(size_t)grow * ldc + gcol] = v;
      }
    }
  }
}

// ---------------------------------------------------------------------------
// Small GEMM (M=400 K/V projections): 128x128 tile, BK=32.
// TRANS=true: store C transposed into vtb[((b*16+h)*64+d)*128 + j]
// ---------------------------------------------------------------------------
template<bool TRANS>
__global__ __launch_bounds__(256, 2) void gemm_bt(
    const u16* __restrict__ A, int lda, const u16* __restrict__ Bt, int ldb,
    const float* __restrict__ bias, u16* Cout, int ldc,
    int M, int N, int K)
{
  __shared__ u16 ldsA[128 * 32];
  __shared__ u16 ldsB[128 * 32];

  const int tid = threadIdx.x;
  const int lane = tid & 63, wave = tid >> 6;
  const int wr = wave >> 1, wc = wave & 1;
  const int m0 = blockIdx.x * 128, n0 = blockIdx.y * 128;

  const int c0 = tid, c1 = tid + 256;
  const int ar0 = c0 >> 2, ak0 = (c0 & 3) * 8;
  const int ar1 = c1 >> 2, ak1 = (c1 & 3) * 8;

  const bool av0 = (m0 + ar0) < M;
  const bool av1 = (m0 + ar1) < M;
  const u16* Ag0 = A + (size_t)(m0 + ar0) * lda + ak0;
  const u16* Ag1 = A + (size_t)(m0 + ar1) * lda + ak1;
  const u16* Bg0 = Bt + (size_t)(n0 + ar0) * ldb + ak0;
  const u16* Bg1 = Bt + (size_t)(n0 + ar1) * ldb + ak1;

  f32x4 acc[4][4] = {};
  const int fr = lane & 15, fo = (lane >> 4) * 8;

  for (int k0 = 0; k0 < K; k0 += 32) {
    if (av0) gload_lds16(Ag0 + k0, &ldsA[c0 * 8]);
    if (av1) gload_lds16(Ag1 + k0, &ldsA[c1 * 8]);
    gload_lds16(Bg0 + k0, &ldsB[c0 * 8]);
    gload_lds16(Bg1 + k0, &ldsB[c1 * 8]);
    asm volatile("s_waitcnt vmcnt(0)" ::: "memory");
    __syncthreads();

    bf16x8 af[4], bfr[4];
    #pragma unroll
    for (int m = 0; m < 4; m++)
      af[m] = *(const bf16x8*)&ldsA[(wr * 64 + m * 16 + fr) * 32 + fo];
    #pragma unroll
    for (int n = 0; n < 4; n++)
      bfr[n] = *(const bf16x8*)&ldsB[(wc * 64 + n * 16 + fr) * 32 + fo];
    #pragma unroll
    for (int m = 0; m < 4; m++)
      #pragma unroll
      for (int n = 0; n < 4; n++)
        acc[m][n] = mfma_16x16x32(af[m], bfr[n], acc[m][n]);
    __syncthreads();
  }

  const int g = lane >> 4;
  #pragma unroll
  for (int m = 0; m < 4; m++) {
    #pragma unroll
    for (int n = 0; n < 4; n++) {
      const int gcol = n0 + wc * 64 + n * 16 + fr;
      const float bv = bias[gcol];
      #pragma unroll
      for (int r = 0; r < 4; r++) {
        const int grow = m0 + wr * 64 + m * 16 + g * 4 + r;
        if (grow < M) {
          float v = acc[m][n][r] + bv;
          if (TRANS) {
            int bb = grow / 100, jj = grow - bb * 100;
            int h = gcol >> 6, d = gcol & 63;
            Cout[(size_t)(((bb * 16 + h) * 64 + d)) * 128 + jj] = f2bf(v);
          } else {
            Cout[(size_t)grow * ldc + gcol] = f2bf(v);
          }
        }
      }
    }
  }
}

// ---------------------------------------------------------------------------
// Weight transpose+convert: src f32 [K][N] -> dst bf16 [N][K]
// ---------------------------------------------------------------------------
__global__ void wconv_t(const float* __restrict__ src, u16* __restrict__ dst,
                        int K, int N)
{
  __shared__ float tile[32][33];
  const int n0 = blockIdx.x * 32, k0 = blockIdx.y * 32;
  const int tx = threadIdx.x, ty = threadIdx.y;
  #pragma unroll
  for (int i = 0; i < 4; i++)
    tile[ty + i * 8][tx] = src[(size_t)(k0 + ty + i * 8) * N + n0 + tx];
  __syncthreads();
  #pragma unroll
  for (int i = 0; i < 4; i++)
    dst[(size_t)(n0 + ty + i * 8) * K + k0 + tx] = f2bf(tile[tx][ty + i * 8]);
}

// ---------------------------------------------------------------------------
// Positional encoding add -> bf16 only
// ---------------------------------------------------------------------------
__global__ __launch_bounds__(256) void pe_video_k(const float* __restrict__ video,
                                                  u16* __restrict__ vbf)
{
  const int r = blockIdx.x;
  const int s = r & 2047;
  const int d0 = threadIdx.x * 4;
  const size_t base = (size_t)r * 1024 + d0;
  float4 v = *(const float4*)&video[base];
  const float coef = -9.210340371976184f / 1024.f;
  float o[4];
  float in[4] = {v.x, v.y, v.z, v.w};
  #pragma unroll
  for (int i = 0; i < 4; i++) {
    int d = d0 + i;
    int j = d >> 1;
    float dv = expf((float)(2 * j) * coef);
    float arg = (float)s * dv;
    float pe = (d & 1) ? cosf(arg) : sinf(arg);
    o[i] = in[i] + pe;
  }
  uint2 pk;
  pk.x = (uint32_t)f2bf(o[0]) | ((uint32_t)f2bf(o[1]) << 16);
  pk.y = (uint32_t)f2bf(o[2]) | ((uint32_t)f2bf(o[3]) << 16);
  *(uint2*)&vbf[base] = pk;
}

__global__ __launch_bounds__(128) void pe_text_k(const float* __restrict__ text,
                                                 u16* __restrict__ tbf)
{
  const int r = blockIdx.x;
  const int s = r % 100;
  const int d0 = threadIdx.x * 4;
  const size_t base = (size_t)r * 512 + d0;
  float4 v = *(const float4*)&text[base];
  const float coef = -9.210340371976184f / 512.f;
  float o[4];
  float in[4] = {v.x, v.y, v.z, v.w};
  #pragma unroll
  for (int i = 0; i < 4; i++) {
    int d = d0 + i;
    int j = d >> 1;
    float dv = expf((float)(2 * j) * coef);
    float arg = (float)s * dv;
    float pe = (d & 1) ? cosf(arg) : sinf(arg);
    o[i] = in[i] + pe;
  }
  uint2 pk;
  pk.x = (uint32_t)f2bf(o[0]) | ((uint32_t)f2bf(o[1]) << 16);
  pk.y = (uint32_t)f2bf(o[2]) | ((uint32_t)f2bf(o[3]) << 16);
  *(uint2*)&tbf[base] = pk;
}

// ---------------------------------------------------------------------------
// LayerNorm, bf16 residual stream: x' = LN(x + delta)*g+b
// ---------------------------------------------------------------------------
template<bool LAST>
__global__ __launch_bounds__(256) void ln2(const u16* __restrict__ xin,
                                           const u16* __restrict__ delta,
                                           const float* __restrict__ gamma,
                                           const float* __restrict__ beta,
                                           u16* __restrict__ xbf,
                                           float* __restrict__ fout)
{
  const int row = blockIdx.x;
  const size_t base = (size_t)row * 1024;
  const int t = threadIdx.x;
  const int d0 = t * 4;
  uint2 xv = *(const uint2*)&xin[base + d0];
  uint2 dv = *(const uint2*)&delta[base + d0];
  float v0 = bf2f((u16)(xv.x & 0xFFFF)) + bf2f((u16)(dv.x & 0xFFFF));
  float v1 = bf2f((u16)(xv.x >> 16))    + bf2f((u16)(dv.x >> 16));
  float v2 = bf2f((u16)(xv.y & 0xFFFF)) + bf2f((u16)(dv.y & 0xFFFF));
  float v3 = bf2f((u16)(xv.y >> 16))    + bf2f((u16)(dv.y >> 16));
  float s = v0 + v1 + v2 + v3;
  float q = v0 * v0 + v1 * v1 + v2 * v2 + v3 * v3;
  #pragma unroll
  for (int d = 32; d >= 1; d >>= 1) { s += __shfl_xor(s, d); q += __shfl_xor(q, d); }
  __shared__ float red[8];
  const int lane = t & 63, w = t >> 6;
  if (lane == 0) { red[w] = s; red[4 + w] = q; }
  __syncthreads();
  float S = red[0] + red[1] + red[2] + red[3];
  float Qs = red[4] + red[5] + red[6] + red[7];
  const float mu = S * (1.f / 1024.f);
  const float var = Qs * (1.f / 1024.f) - mu * mu;
  const float rs = rsqrtf(var + 1e-5f);
  float4 gv = *(const float4*)&gamma[d0];
  float4 bv = *(const float4*)&beta[d0];
  float o0 = (v0 - mu) * rs * gv.x + bv.x;
  float o1 = (v1 - mu) * rs * gv.y + bv.y;
  float o2 = (v2 - mu) * rs * gv.z + bv.z;
  float o3 = (v3 - mu) * rs * gv.w + bv.w;
  if (LAST) {
    *(float4*)&fout[base + d0] = make_float4(o0, o1, o2, o3);
  } else {
    uint2 pk;
    pk.x = (uint32_t)f2bf(o0) | ((uint32_t)f2bf(o1) << 16);
    pk.y = (uint32_t)f2bf(o2) | ((uint32_t)f2bf(o3) << 16);
    *(uint2*)&xbf[base + d0] = pk;
  }
}

// ---------------------------------------------------------------------------
// Cross attention v2 (verified): K from global (L2), V pre-transposed,
// P via LDS intra-wave, zero barriers.
// ---------------------------------------------------------------------------
__global__ __launch_bounds__(256) void attn_v2(
    const u16* __restrict__ Q, const u16* __restrict__ Kb,
    const u16* __restrict__ Vtb, const int* __restrict__ mask,
    u16* __restrict__ Out)
{
  __shared__ u16 ldsP[64 * 136];

  const int tid = threadIdx.x, lane = tid & 63, w = tid >> 6;
  const int qb = blockIdx.x, bh = blockIdx.y;
  const int b = bh >> 4, h = bh & 15;
  const int fr = lane & 15, g = lane >> 4, fo = g * 8;

  const size_t qrow = (size_t)(b * 2048 + qb * 64 + w * 16 + fr) * 1024 + h * 64;
  bf16x8 qf0 = *(const bf16x8*)&Q[qrow + fo];
  bf16x8 qf1 = *(const bf16x8*)&Q[qrow + 32 + fo];

  float madd[7];
  #pragma unroll
  for (int t = 0; t < 7; t++) {
    int col = t * 16 + fr;
    int mv = (col < 100) ? mask[b * 100 + col] : 0;
    madd[t] = mv ? 0.f : -1e30f;
  }

  float sc[7][4];
  #pragma unroll
  for (int t = 0; t < 7; t++) {
    int col = t * 16 + fr;
    int jr = (col < 100) ? col : 99;
    const u16* kp = Kb + (size_t)(b * 100 + jr) * 1024 + h * 64;
    bf16x8 kf0 = *(const bf16x8*)&kp[fo];
    bf16x8 kf1 = *(const bf16x8*)&kp[32 + fo];
    f32x4 a = {};
    a = mfma_16x16x32(qf0, kf0, a);
    a = mfma_16x16x32(qf1, kf1, a);
    #pragma unroll
    for (int r = 0; r < 4; r++)
      sc[t][r] = a[r] * 0.125f + madd[t];
  }

  #pragma unroll
  for (int r = 0; r < 4; r++) {
    float m = sc[0][r];
    #pragma unroll
    for (int t = 1; t < 7; t++) m = fmaxf(m, sc[t][r]);
    #pragma unroll
    for (int d = 8; d >= 1; d >>= 1) m = fmaxf(m, __shfl_xor(m, d));
    float ssum = 0.f;
    #pragma unroll
    for (int t = 0; t < 7; t++) { float p = __expf(sc[t][r] - m); sc[t][r] = p; ssum += p; }
    #pragma unroll
    for (int d = 8; d >= 1; d >>= 1) ssum += __shfl_xor(ssum, d);
    float is = 1.f / ssum;
    #pragma unroll
    for (int t = 0; t < 7; t++)
      ldsP[(w * 16 + g * 4 + r) * 136 + t * 16 + fr] = f2bf(sc[t][r] * is);
  }
  {
    u16* zp = &ldsP[(w * 16 + fr) * 136 + 112 + g * 6];
    #pragma unroll
    for (int i = 0; i < 6; i++) zp[i] = 0;
  }

  bf16x8 pa[4];
  #pragma unroll
  for (int kk = 0; kk < 4; kk++)
    pa[kk] = *(const bf16x8*)&ldsP[(w * 16 + fr) * 136 + kk * 32 + fo];
  const u16* vtbase = Vtb + (size_t)bh * 64 * 128;
  #pragma unroll
  for (int nt = 0; nt < 4; nt++) {
    f32x4 a = {};
    #pragma unroll
    for (int kk = 0; kk < 4; kk++) {
      bf16x8 vf = *(const bf16x8*)&vtbase[(size_t)(nt * 16 + fr) * 128 + kk * 32 + fo];
      a = mfma_16x16x32(pa[kk], vf, a);
    }
    #pragma unroll
    for (int r = 0; r < 4; r++) {
      size_t orow = (size_t)(b * 2048 + qb * 64 + w * 16 + g * 4 + r) * 1024 + h * 64 + nt * 16 + fr;
      Out[orow] = f2bf(a[r]);
    }
  }
}

// ---------------------------------------------------------------------------
extern "C" void kernel_launch(void* const* d_in, const int* in_sizes, int n_in,
                              void* d_out, int out_size, void* d_ws, size_t ws_size,
                              hipStream_t stream) {
  const float* video = (const float*)d_in[0];
  const float* text  = (const float*)d_in[1];
  const int*   text_mask = (const int*)d_in[2];
  const float* Wq_w = (const float*)d_in[3];
  const float* Wq_b = (const float*)d_in[4];
  const float* Wk_w = (const float*)d_in[5];
  const float* Wk_b = (const float*)d_in[6];
  const float* Wv_w = (const float*)d_in[7];
  const float* Wv_b = (const float*)d_in[8];
  const float* Wo_w = (const float*)d_in[9];
  const float* Wo_b = (const float*)d_in[10];
  const float* fc1_w = (const float*)d_in[11];
  const float* fc1_b = (const float*)d_in[12];
  const float* fc2_w = (const float*)d_in[13];
  const float* fc2_b = (const float*)d_in[14];
  const float* n2_g = (const float*)d_in[15];
  const float* n2_b = (const float*)d_in[16];
  const float* n3_g = (const float*)d_in[17];
  const float* n3_b = (const float*)d_in[18];

  char* ws = (char*)d_ws;
  size_t off = 0;
  auto alloc = [&](size_t bytes) {
    char* p = ws + off;
    off += (bytes + 255) & ~(size_t)255;
    return p;
  };
  u16* vbf = (u16*)alloc((size_t)8192 * 1024 * 2);     // 16 MB residual (bf16)
  u16* tbf = (u16*)alloc((size_t)400 * 512 * 2);
  u16* wqT = (u16*)alloc((size_t)1024 * 1024 * 2);
  u16* wkT = (u16*)alloc((size_t)1024 * 512 * 2);
  u16* wvT = (u16*)alloc((size_t)1024 * 512 * 2);
  u16* woT = (u16*)alloc((size_t)1024 * 1024 * 2);
  u16* f1T = (u16*)alloc((size_t)4096 * 1024 * 2);
  u16* f2T = (u16*)alloc((size_t)1024 * 4096 * 2);
  char* S = alloc((size_t)35192832);                   // union scratch
  u16* qbf  = (u16*)S;
  u16* kbf  = (u16*)(S + 16777216);
  u16* abf  = (u16*)(S + 16777216 + 1638400);
  u16* h1c  = (u16*)S;
  u16* vtb  = (u16*)alloc((size_t)64 * 64 * 128 * 2);  // 2 MB V^T (not aliased)
  u16* dbf  = (u16*)alloc((size_t)8192 * 1024 * 2);
  float* fout = (float*)d_out;

  hipMemsetAsync(vtb, 0, (size_t)64 * 64 * 128 * 2, stream);

  pe_video_k<<<8192, 256, 0, stream>>>(video, vbf);
  pe_text_k<<<400, 128, 0, stream>>>(text, tbf);

  dim3 tb(32, 8, 1);
  for (int l = 0; l < 4; ++l) {
    wconv_t<<<dim3(32, 32), tb, 0, stream>>>(Wq_w + (size_t)l * 1024 * 1024, wqT, 1024, 1024);
    wconv_t<<<dim3(32, 16), tb, 0, stream>>>(Wk_w + (size_t)l * 512 * 1024, wkT, 512, 1024);
    wconv_t<<<dim3(32, 16), tb, 0, stream>>>(Wv_w + (size_t)l * 512 * 1024, wvT, 512, 1024);
    wconv_t<<<dim3(32, 32), tb, 0, stream>>>(Wo_w + (size_t)l * 1024 * 1024, woT, 1024, 1024);
    wconv_t<<<dim3(128, 32), tb, 0, stream>>>(fc1_w + (size_t)l * 1024 * 4096, f1T, 1024, 4096);
    wconv_t<<<dim3(32, 128), tb, 0, stream>>>(fc2_w + (size_t)l * 4096 * 1024, f2T, 4096, 1024);

    gemm_ring4<true, false, false><<<dim3(64, 8), 256, 0, stream>>>(
        vbf, 1024, wqT, 1024, Wq_b + l * 1024, qbf, 1024, 8192, 1024, 1024);
    gemm_bt<false><<<dim3(4, 8), 256, 0, stream>>>(
        tbf, 512, wkT, 512, Wk_b + l * 1024, kbf, 1024, 400, 1024, 512);
    gemm_bt<true><<<dim3(4, 8), 256, 0, stream>>>(
        tbf, 512, wvT, 512, Wv_b + l * 1024, vtb, 1024, 400, 1024, 512);
    attn_v2<<<dim3(32, 64), 256, 0, stream>>>(qbf, kbf, vtb, text_mask, abf);
    gemm_ring4<true, false, false><<<dim3(64, 8), 256, 0, stream>>>(
        abf, 1024, woT, 1024, Wo_b + l * 1024, dbf, 1024, 8192, 1024, 1024);
    ln2<false><<<8192, 256, 0, stream>>>(vbf, dbf, n2_g + l * 1024, n2_b + l * 1024, vbf, nullptr);

    for (int c = 0; c < 2; ++c) {
      gemm_ring4<true, true, false><<<dim3(64, 16), 256, 0, stream>>>(
          vbf, 1024, f1T + (size_t)c * 2048 * 1024, 1024,
          fc1_b + l * 4096 + c * 2048, h1c, 2048, 8192, 2048, 1024);
      if (c == 0)
        gemm_ring4<true, false, false><<<dim3(64, 8), 256, 0, stream>>>(
            h1c, 2048, f2T + (size_t)c * 2048, 4096,
            fc2_b + l * 1024, dbf, 1024, 8192, 1024, 2048);
      else
        gemm_ring4<true, false, true><<<dim3(64, 8), 256, 0, stream>>>(
            h1c, 2048, f2T + (size_t)c * 2048, 4096,
            nullptr, dbf, 1024, 8192, 1024, 2048);
    }
    if (l == 3)
      ln2<true><<<8192, 256, 0, stream>>>(vbf, dbf, n3_g + l * 1024, n3_b + l * 1024, nullptr, fout);
    else
      ln2<false><<<8192, 256, 0, stream>>>(vbf, dbf, n3_g + l * 1024, n3_b + l * 1024, vbf, nullptr);
  }
}

// Round 8
// 1355.115 us; speedup vs baseline: 1.0304x; 1.0022x over previous
//
#include <hip/hip_runtime.h>
#include <cstdint>
#include <cstddef>

typedef unsigned short u16;
typedef __attribute__((ext_vector_type(8))) __bf16 bf16x8;
typedef __attribute__((ext_vector_type(4))) float f32x4;

__device__ __forceinline__ f32x4 mfma_16x16x32(bf16x8 a, bf16x8 b, f32x4 c) {
  return __builtin_amdgcn_mfma_f32_16x16x32_bf16(a, b, c, 0, 0, 0);
}

__device__ __forceinline__ u16 f2bf(float f) {
  union { float f; uint32_t u; } c; c.f = f;
  uint32_t u = c.u + 0x7FFFu + ((c.u >> 16) & 1u);
  return (u16)(u >> 16);
}

__device__ __forceinline__ float bf2f(u16 x) {
  union { uint32_t u; float f; } c; c.u = ((uint32_t)x) << 16;
  return c.f;
}

__device__ __forceinline__ void gload_lds16(const void* g, void* l) {
  __builtin_amdgcn_global_load_lds(
      (__attribute__((address_space(1))) void*)(uintptr_t)g,
      (__attribute__((address_space(3))) void*)l, 16, 0, 0);
}

// ===========================================================================
// Ring GEMM v6 = round-4 ring-v2 geometry (measured best: FF2 49.5 us) with
// barriers/K-step cut 4 -> 2 (single MFMA cluster; keep the pre-MFMA barrier).
// MR=8: BM=256, MR=4: BM=128. BN=256. 512 threads = 8 waves (2x4),
// wave tile = (MR*16) x 64.  BK=32/step; 4-slot LDS ring; prefetch dist 3;
// counted vmcnt (LPT=4/3 -> steady vmcnt(8)/(6)).
// Swizzle sigma(r)=(r>>1)&3 on 16B granules, on BOTH global_load_lds source
// and ds_read offset (verified conflict-free rounds 5-7).
// Hazards with 2 barriers: RAW slot s+1 via counted WAITV at step end; WAR:
// STAGE(s+3) hits slot (s-1)&3 whose reads drained at step s-1's lgkmcnt(0)
// before its own MFMA cluster + end barrier.
// ===========================================================================
template<int MR, bool OUT_BF16, bool RELU, bool ACC>
__global__ __launch_bounds__(512, 2) void gemm_ring6(
    const u16* __restrict__ A, int lda, const u16* __restrict__ Bt, int ldb,
    const float* __restrict__ bias, void* Cout, int ldc,
    int M, int N, int K)
{
  constexpr int BM = MR * 32;
  constexpr int SLOT = (BM + 256) * 32;
  __shared__ u16 ring[4 * SLOT];          // 128 KB (MR8) / 96 KB (MR4)

  const int tid = threadIdx.x;
  const int lane = tid & 63, wave = tid >> 6;
  const int wm = wave >> 2, wn = wave & 3;
  const int m0 = blockIdx.x * BM, n0 = blockIdx.y * 256;

  // pre-swizzled global sources: chunk c -> row r=c>>2, physical granule c&3
  // receives logical granule (c&3)^((r>>1)&3)
  const int cA0 = tid, rA0 = cA0 >> 2;
  const u16* gA0 = A + (size_t)(m0 + rA0) * lda + (((cA0 & 3) ^ ((rA0 >> 1) & 3)) * 8);
  const int cA1 = tid + 512, rA1 = cA1 >> 2;
  const u16* gA1 = A + (size_t)(m0 + (MR == 8 ? rA1 : 0)) * lda + (((cA1 & 3) ^ ((rA1 >> 1) & 3)) * 8);
  const int cB0 = tid, rB0 = cB0 >> 2;
  const int cB1 = tid + 512, rB1 = cB1 >> 2;
  const u16* gB0 = Bt + (size_t)(n0 + rB0) * ldb + (((cB0 & 3) ^ ((rB0 >> 1) & 3)) * 8);
  const u16* gB1 = Bt + (size_t)(n0 + rB1) * ldb + (((cB1 & 3) ^ ((rB1 >> 1) & 3)) * 8);

  const int NK = K >> 5;

  auto STAGE = [&](int s) {
    u16* Sb = &ring[(s & 3) * SLOT];
    const int ko = s * 32;
    gload_lds16(gA0 + ko, Sb + cA0 * 8);
    if constexpr (MR == 8) gload_lds16(gA1 + ko, Sb + cA1 * 8);
    gload_lds16(gB0 + ko, Sb + BM * 32 + cB0 * 8);
    gload_lds16(gB1 + ko, Sb + BM * 32 + cB1 * 8);
  };
  auto WAITV = [&](int ahead) {
    if (ahead >= 2) {
      if constexpr (MR == 8) asm volatile("s_waitcnt vmcnt(8)" ::: "memory");
      else                   asm volatile("s_waitcnt vmcnt(6)" ::: "memory");
    } else if (ahead == 1) {
      if constexpr (MR == 8) asm volatile("s_waitcnt vmcnt(4)" ::: "memory");
      else                   asm volatile("s_waitcnt vmcnt(3)" ::: "memory");
    } else {
      asm volatile("s_waitcnt vmcnt(0)" ::: "memory");
    }
  };

  // ds_read lane constants: logical granule g at physical g^((fr>>1)&3)
  const int fr = lane & 15, g = lane >> 4;
  const int foff = fr * 32 + ((g ^ ((fr >> 1) & 3)) * 8);

  f32x4 acc[MR][4];
  #pragma unroll
  for (int m = 0; m < MR; m++)
    #pragma unroll
    for (int n = 0; n < 4; n++) acc[m][n] = f32x4{0.f, 0.f, 0.f, 0.f};

  for (int i = 0; i < 3 && i < NK; ++i) STAGE(i);
  WAITV(NK - 1 < 2 ? NK - 1 : 2);
  __builtin_amdgcn_s_barrier();
  __builtin_amdgcn_sched_barrier(0);

  for (int s = 0; s < NK; ++s) {
    const u16* As = &ring[(s & 3) * SLOT];
    const u16* Bs = As + BM * 32;

    bf16x8 bf[4];
    #pragma unroll
    for (int n = 0; n < 4; n++)
      bf[n] = *(const bf16x8*)(Bs + (wn * 64 + n * 16) * 32 + foff);
    bf16x8 af[MR];
    #pragma unroll
    for (int m = 0; m < MR; m++)
      af[m] = *(const bf16x8*)(As + (wm * (MR * 16) + m * 16) * 32 + foff);

    if (s + 3 < NK) STAGE(s + 3);

    // align all waves: reads + stage issued before any MFMA cluster starts
    __builtin_amdgcn_s_barrier();
    asm volatile("s_waitcnt lgkmcnt(0)" ::: "memory");
    __builtin_amdgcn_sched_barrier(0);

    __builtin_amdgcn_s_setprio(1);
    #pragma unroll
    for (int m = 0; m < MR; m++)
      #pragma unroll
      for (int n = 0; n < 4; n++)
        acc[m][n] = mfma_16x16x32(af[m], bf[n], acc[m][n]);
    __builtin_amdgcn_s_setprio(0);

    // RAW: slot s+1 fully staged (counted in steady state)
    {
      int im = (s + 3 < NK - 1) ? s + 3 : NK - 1;
      WAITV(im - (s + 1));
    }
    __builtin_amdgcn_sched_barrier(0);
    __builtin_amdgcn_s_barrier();
    __builtin_amdgcn_sched_barrier(0);
  }

  #pragma unroll
  for (int n = 0; n < 4; n++) {
    const int gcol = n0 + wn * 64 + n * 16 + fr;
    const float bv = bias ? bias[gcol] : 0.f;
    #pragma unroll
    for (int m = 0; m < MR; m++) {
      #pragma unroll
      for (int r = 0; r < 4; r++) {
        const int grow = m0 + wm * (MR * 16) + m * 16 + g * 4 + r;
        float v = acc[m][n][r] + bv;
        if (ACC) v += bf2f(((const u16*)Cout)[(size_t)grow * ldc + gcol]);
        if (RELU) v = fmaxf(v, 0.f);
        if (OUT_BF16) ((u16*)Cout)[(size_t)grow * ldc + gcol] = f2bf(v);
        else         ((float*)Cout)[(size_t)grow * ldc + gcol] = v;
      }
    }
  }
}

// ---------------------------------------------------------------------------
// Small GEMM (M=400 K/V projections): 128x128 tile, BK=32.
// TRANS=true: store C transposed into vtb[((b*16+h)*64+d)*128 + j]
// ---------------------------------------------------------------------------
template<bool TRANS>
__global__ __launch_bounds__(256, 2) void gemm_bt(
    const u16* __restrict__ A, int lda, const u16* __restrict__ Bt, int ldb,
    const float* __restrict__ bias, u16* Cout, int ldc,
    int M, int N, int K)
{
  __shared__ u16 ldsA[128 * 32];
  __shared__ u16 ldsB[128 * 32];

  const int tid = threadIdx.x;
  const int lane = tid & 63, wave = tid >> 6;
  const int wr = wave >> 1, wc = wave & 1;
  const int m0 = blockIdx.x * 128, n0 = blockIdx.y * 128;

  const int c0 = tid, c1 = tid + 256;
  const int ar0 = c0 >> 2, ak0 = (c0 & 3) * 8;
  const int ar1 = c1 >> 2, ak1 = (c1 & 3) * 8;

  const bool av0 = (m0 + ar0) < M;
  const bool av1 = (m0 + ar1) < M;
  const u16* Ag0 = A + (size_t)(m0 + ar0) * lda + ak0;
  const u16* Ag1 = A + (size_t)(m0 + ar1) * lda + ak1;
  const u16* Bg0 = Bt + (size_t)(n0 + ar0) * ldb + ak0;
  const u16* Bg1 = Bt + (size_t)(n0 + ar1) * ldb + ak1;

  f32x4 acc[4][4] = {};
  const int fr = lane & 15, fo = (lane >> 4) * 8;

  for (int k0 = 0; k0 < K; k0 += 32) {
    if (av0) gload_lds16(Ag0 + k0, &ldsA[c0 * 8]);
    if (av1) gload_lds16(Ag1 + k0, &ldsA[c1 * 8]);
    gload_lds16(Bg0 + k0, &ldsB[c0 * 8]);
    gload_lds16(Bg1 + k0, &ldsB[c1 * 8]);
    asm volatile("s_waitcnt vmcnt(0)" ::: "memory");
    __syncthreads();

    bf16x8 af[4], bfr[4];
    #pragma unroll
    for (int m = 0; m < 4; m++)
      af[m] = *(const bf16x8*)&ldsA[(wr * 64 + m * 16 + fr) * 32 + fo];
    #pragma unroll
    for (int n = 0; n < 4; n++)
      bfr[n] = *(const bf16x8*)&ldsB[(wc * 64 + n * 16 + fr) * 32 + fo];
    #pragma unroll
    for (int m = 0; m < 4; m++)
      #pragma unroll
      for (int n = 0; n < 4; n++)
        acc[m][n] = mfma_16x16x32(af[m], bfr[n], acc[m][n]);
    __syncthreads();
  }

  const int g = lane >> 4;
  #pragma unroll
  for (int m = 0; m < 4; m++) {
    #pragma unroll
    for (int n = 0; n < 4; n++) {
      const int gcol = n0 + wc * 64 + n * 16 + fr;
      const float bv = bias[gcol];
      #pragma unroll
      for (int r = 0; r < 4; r++) {
        const int grow = m0 + wr * 64 + m * 16 + g * 4 + r;
        if (grow < M) {
          float v = acc[m][n][r] + bv;
          if (TRANS) {
            int bb = grow / 100, jj = grow - bb * 100;
            int h = gcol >> 6, d = gcol & 63;
            Cout[(size_t)(((bb * 16 + h) * 64 + d)) * 128 + jj] = f2bf(v);
          } else {
            Cout[(size_t)grow * ldc + gcol] = f2bf(v);
          }
        }
      }
    }
  }
}

// ---------------------------------------------------------------------------
// Weight transpose+convert: src f32 [K][N] -> dst bf16 [N][K]
// ---------------------------------------------------------------------------
__global__ void wconv_t(const float* __restrict__ src, u16* __restrict__ dst,
                        int K, int N)
{
  __shared__ float tile[32][33];
  const int n0 = blockIdx.x * 32, k0 = blockIdx.y * 32;
  const int tx = threadIdx.x, ty = threadIdx.y;
  #pragma unroll
  for (int i = 0; i < 4; i++)
    tile[ty + i * 8][tx] = src[(size_t)(k0 + ty + i * 8) * N + n0 + tx];
  __syncthreads();
  #pragma unroll
  for (int i = 0; i < 4; i++)
    dst[(size_t)(n0 + ty + i * 8) * K + k0 + tx] = f2bf(tile[tx][ty + i * 8]);
}

// ---------------------------------------------------------------------------
// Positional encoding add -> bf16 only
// ---------------------------------------------------------------------------
__global__ __launch_bounds__(256) void pe_video_k(const float* __restrict__ video,
                                                  u16* __restrict__ vbf)
{
  const int r = blockIdx.x;
  const int s = r & 2047;
  const int d0 = threadIdx.x * 4;
  const size_t base = (size_t)r * 1024 + d0;
  float4 v = *(const float4*)&video[base];
  const float coef = -9.210340371976184f / 1024.f;
  float o[4];
  float in[4] = {v.x, v.y, v.z, v.w};
  #pragma unroll
  for (int i = 0; i < 4; i++) {
    int d = d0 + i;
    int j = d >> 1;
    float dv = expf((float)(2 * j) * coef);
    float arg = (float)s * dv;
    float pe = (d & 1) ? cosf(arg) : sinf(arg);
    o[i] = in[i] + pe;
  }
  uint2 pk;
  pk.x = (uint32_t)f2bf(o[0]) | ((uint32_t)f2bf(o[1]) << 16);
  pk.y = (uint32_t)f2bf(o[2]) | ((uint32_t)f2bf(o[3]) << 16);
  *(uint2*)&vbf[base] = pk;
}

__global__ __launch_bounds__(128) void pe_text_k(const float* __restrict__ text,
                                                 u16* __restrict__ tbf)
{
  const int r = blockIdx.x;
  const int s = r % 100;
  const int d0 = threadIdx.x * 4;
  const size_t base = (size_t)r * 512 + d0;
  float4 v = *(const float4*)&text[base];
  const float coef = -9.210340371976184f / 512.f;
  float o[4];
  float in[4] = {v.x, v.y, v.z, v.w};
  #pragma unroll
  for (int i = 0; i < 4; i++) {
    int d = d0 + i;
    int j = d >> 1;
    float dv = expf((float)(2 * j) * coef);
    float arg = (float)s * dv;
    float pe = (d & 1) ? cosf(arg) : sinf(arg);
    o[i] = in[i] + pe;
  }
  uint2 pk;
  pk.x = (uint32_t)f2bf(o[0]) | ((uint32_t)f2bf(o[1]) << 16);
  pk.y = (uint32_t)f2bf(o[2]) | ((uint32_t)f2bf(o[3]) << 16);
  *(uint2*)&tbf[base] = pk;
}

// ---------------------------------------------------------------------------
// LayerNorm, bf16 residual stream: x' = LN(x + delta)*g+b
// ---------------------------------------------------------------------------
template<bool LAST>
__global__ __launch_bounds__(256) void ln2(const u16* __restrict__ xin,
                                           const u16* __restrict__ delta,
                                           const float* __restrict__ gamma,
                                           const float* __restrict__ beta,
                                           u16* __restrict__ xbf,
                                           float* __restrict__ fout)
{
  const int row = blockIdx.x;
  const size_t base = (size_t)row * 1024;
  const int t = threadIdx.x;
  const int d0 = t * 4;
  uint2 xv = *(const uint2*)&xin[base + d0];
  uint2 dv = *(const uint2*)&delta[base + d0];
  float v0 = bf2f((u16)(xv.x & 0xFFFF)) + bf2f((u16)(dv.x & 0xFFFF));
  float v1 = bf2f((u16)(xv.x >> 16))    + bf2f((u16)(dv.x >> 16));
  float v2 = bf2f((u16)(xv.y & 0xFFFF)) + bf2f((u16)(dv.y & 0xFFFF));
  float v3 = bf2f((u16)(xv.y >> 16))    + bf2f((u16)(dv.y >> 16));
  float s = v0 + v1 + v2 + v3;
  float q = v0 * v0 + v1 * v1 + v2 * v2 + v3 * v3;
  #pragma unroll
  for (int d = 32; d >= 1; d >>= 1) { s += __shfl_xor(s, d); q += __shfl_xor(q, d); }
  __shared__ float red[8];
  const int lane = t & 63, w = t >> 6;
  if (lane == 0) { red[w] = s; red[4 + w] = q; }
  __syncthreads();
  float S = red[0] + red[1] + red[2] + red[3];
  float Qs = red[4] + red[5] + red[6] + red[7];
  const float mu = S * (1.f / 1024.f);
  const float var = Qs * (1.f / 1024.f) - mu * mu;
  const float rs = rsqrtf(var + 1e-5f);
  float4 gv = *(const float4*)&gamma[d0];
  float4 bv = *(const float4*)&beta[d0];
  float o0 = (v0 - mu) * rs * gv.x + bv.x;
  float o1 = (v1 - mu) * rs * gv.y + bv.y;
  float o2 = (v2 - mu) * rs * gv.z + bv.z;
  float o3 = (v3 - mu) * rs * gv.w + bv.w;
  if (LAST) {
    *(float4*)&fout[base + d0] = make_float4(o0, o1, o2, o3);
  } else {
    uint2 pk;
    pk.x = (uint32_t)f2bf(o0) | ((uint32_t)f2bf(o1) << 16);
    pk.y = (uint32_t)f2bf(o2) | ((uint32_t)f2bf(o3) << 16);
    *(uint2*)&xbf[base + d0] = pk;
  }
}

// ---------------------------------------------------------------------------
// Cross attention v2 (verified): K from global (L2), V pre-transposed,
// P via LDS intra-wave, zero barriers.
// ---------------------------------------------------------------------------
__global__ __launch_bounds__(256) void attn_v2(
    const u16* __restrict__ Q, const u16* __restrict__ Kb,
    const u16* __restrict__ Vtb, const int* __restrict__ mask,
    u16* __restrict__ Out)
{
  __shared__ u16 ldsP[64 * 136];

  const int tid = threadIdx.x, lane = tid & 63, w = tid >> 6;
  const int qb = blockIdx.x, bh = blockIdx.y;
  const int b = bh >> 4, h = bh & 15;
  const int fr = lane & 15, g = lane >> 4, fo = g * 8;

  const size_t qrow = (size_t)(b * 2048 + qb * 64 + w * 16 + fr) * 1024 + h * 64;
  bf16x8 qf0 = *(const bf16x8*)&Q[qrow + fo];
  bf16x8 qf1 = *(const bf16x8*)&Q[qrow + 32 + fo];

  float madd[7];
  #pragma unroll
  for (int t = 0; t < 7; t++) {
    int col = t * 16 + fr;
    int mv = (col < 100) ? mask[b * 100 + col] : 0;
    madd[t] = mv ? 0.f : -1e30f;
  }

  float sc[7][4];
  #pragma unroll
  for (int t = 0; t < 7; t++) {
    int col = t * 16 + fr;
    int jr = (col < 100) ? col : 99;
    const u16* kp = Kb + (size_t)(b * 100 + jr) * 1024 + h * 64;
    bf16x8 kf0 = *(const bf16x8*)&kp[fo];
    bf16x8 kf1 = *(const bf16x8*)&kp[32 + fo];
    f32x4 a = {};
    a = mfma_16x16x32(qf0, kf0, a);
    a = mfma_16x16x32(qf1, kf1, a);
    #pragma unroll
    for (int r = 0; r < 4; r++)
      sc[t][r] = a[r] * 0.125f + madd[t];
  }

  #pragma unroll
  for (int r = 0; r < 4; r++) {
    float m = sc[0][r];
    #pragma unroll
    for (int t = 1; t < 7; t++) m = fmaxf(m, sc[t][r]);
    #pragma unroll
    for (int d = 8; d >= 1; d >>= 1) m = fmaxf(m, __shfl_xor(m, d));
    float ssum = 0.f;
    #pragma unroll
    for (int t = 0; t < 7; t++) { float p = __expf(sc[t][r] - m); sc[t][r] = p; ssum += p; }
    #pragma unroll
    for (int d = 8; d >= 1; d >>= 1) ssum += __shfl_xor(ssum, d);
    float is = 1.f / ssum;
    #pragma unroll
    for (int t = 0; t < 7; t++)
      ldsP[(w * 16 + g * 4 + r) * 136 + t * 16 + fr] = f2bf(sc[t][r] * is);
  }
  {
    u16* zp = &ldsP[(w * 16 + fr) * 136 + 112 + g * 6];
    #pragma unroll
    for (int i = 0; i < 6; i++) zp[i] = 0;
  }

  bf16x8 pa[4];
  #pragma unroll
  for (int kk = 0; kk < 4; kk++)
    pa[kk] = *(const bf16x8*)&ldsP[(w * 16 + fr) * 136 + kk * 32 + fo];
  const u16* vtbase = Vtb + (size_t)bh * 64 * 128;
  #pragma unroll
  for (int nt = 0; nt < 4; nt++) {
    f32x4 a = {};
    #pragma unroll
    for (int kk = 0; kk < 4; kk++) {
      bf16x8 vf = *(const bf16x8*)&vtbase[(size_t)(nt * 16 + fr) * 128 + kk * 32 + fo];
      a = mfma_16x16x32(pa[kk], vf, a);
    }
    #pragma unroll
    for (int r = 0; r < 4; r++) {
      size_t orow = (size_t)(b * 2048 + qb * 64 + w * 16 + g * 4 + r) * 1024 + h * 64 + nt * 16 + fr;
      Out[orow] = f2bf(a[r]);
    }
  }
}

// ---------------------------------------------------------------------------
extern "C" void kernel_launch(void* const* d_in, const int* in_sizes, int n_in,
                              void* d_out, int out_size, void* d_ws, size_t ws_size,
                              hipStream_t stream) {
  const float* video = (const float*)d_in[0];
  const float* text  = (const float*)d_in[1];
  const int*   text_mask = (const int*)d_in[2];
  const float* Wq_w = (const float*)d_in[3];
  const float* Wq_b = (const float*)d_in[4];
  const float* Wk_w = (const float*)d_in[5];
  const float* Wk_b = (const float*)d_in[6];
  const float* Wv_w = (const float*)d_in[7];
  const float* Wv_b = (const float*)d_in[8];
  const float* Wo_w = (const float*)d_in[9];
  const float* Wo_b = (const float*)d_in[10];
  const float* fc1_w = (const float*)d_in[11];
  const float* fc1_b = (const float*)d_in[12];
  const float* fc2_w = (const float*)d_in[13];
  const float* fc2_b = (const float*)d_in[14];
  const float* n2_g = (const float*)d_in[15];
  const float* n2_b = (const float*)d_in[16];
  const float* n3_g = (const float*)d_in[17];
  const float* n3_b = (const float*)d_in[18];

  char* ws = (char*)d_ws;
  size_t off = 0;
  auto alloc = [&](size_t bytes) {
    char* p = ws + off;
    off += (bytes + 255) & ~(size_t)255;
    return p;
  };
  u16* vbf = (u16*)alloc((size_t)8192 * 1024 * 2);     // 16 MB residual (bf16)
  u16* tbf = (u16*)alloc((size_t)400 * 512 * 2);
  u16* wqT = (u16*)alloc((size_t)1024 * 1024 * 2);
  u16* wkT = (u16*)alloc((size_t)1024 * 512 * 2);
  u16* wvT = (u16*)alloc((size_t)1024 * 512 * 2);
  u16* woT = (u16*)alloc((size_t)1024 * 1024 * 2);
  u16* f1T = (u16*)alloc((size_t)4096 * 1024 * 2);
  u16* f2T = (u16*)alloc((size_t)1024 * 4096 * 2);
  char* S = alloc((size_t)35192832);                   // union scratch
  u16* qbf  = (u16*)S;
  u16* kbf  = (u16*)(S + 16777216);
  u16* abf  = (u16*)(S + 16777216 + 1638400);
  u16* h1c  = (u16*)S;
  u16* vtb  = (u16*)alloc((size_t)64 * 64 * 128 * 2);  // 2 MB V^T (not aliased)
  u16* dbf  = (u16*)alloc((size_t)8192 * 1024 * 2);
  float* fout = (float*)d_out;

  hipMemsetAsync(vtb, 0, (size_t)64 * 64 * 128 * 2, stream);

  pe_video_k<<<8192, 256, 0, stream>>>(video, vbf);
  pe_text_k<<<400, 128, 0, stream>>>(text, tbf);

  dim3 tb(32, 8, 1);
  for (int l = 0; l < 4; ++l) {
    wconv_t<<<dim3(32, 32), tb, 0, stream>>>(Wq_w + (size_t)l * 1024 * 1024, wqT, 1024, 1024);
    wconv_t<<<dim3(32, 16), tb, 0, stream>>>(Wk_w + (size_t)l * 512 * 1024, wkT, 512, 1024);
    wconv_t<<<dim3(32, 16), tb, 0, stream>>>(Wv_w + (size_t)l * 512 * 1024, wvT, 512, 1024);
    wconv_t<<<dim3(32, 32), tb, 0, stream>>>(Wo_w + (size_t)l * 1024 * 1024, woT, 1024, 1024);
    wconv_t<<<dim3(128, 32), tb, 0, stream>>>(fc1_w + (size_t)l * 1024 * 4096, f1T, 1024, 4096);
    wconv_t<<<dim3(32, 128), tb, 0, stream>>>(fc2_w + (size_t)l * 4096 * 1024, f2T, 4096, 1024);

    gemm_ring6<4, true, false, false><<<dim3(64, 4), 512, 0, stream>>>(
        vbf, 1024, wqT, 1024, Wq_b + l * 1024, qbf, 1024, 8192, 1024, 1024);
    gemm_bt<false><<<dim3(4, 8), 256, 0, stream>>>(
        tbf, 512, wkT, 512, Wk_b + l * 1024, kbf, 1024, 400, 1024, 512);
    gemm_bt<true><<<dim3(4, 8), 256, 0, stream>>>(
        tbf, 512, wvT, 512, Wv_b + l * 1024, vtb, 1024, 400, 1024, 512);
    attn_v2<<<dim3(32, 64), 256, 0, stream>>>(qbf, kbf, vtb, text_mask, abf);
    gemm_ring6<4, true, false, false><<<dim3(64, 4), 512, 0, stream>>>(
        abf, 1024, woT, 1024, Wo_b + l * 1024, dbf, 1024, 8192, 1024, 1024);
    ln2<false><<<8192, 256, 0, stream>>>(vbf, dbf, n2_g + l * 1024, n2_b + l * 1024, vbf, nullptr);

    for (int c = 0; c < 2; ++c) {
      gemm_ring6<8, true, true, false><<<dim3(32, 8), 512, 0, stream>>>(
          vbf, 1024, f1T + (size_t)c * 2048 * 1024, 1024,
          fc1_b + l * 4096 + c * 2048, h1c, 2048, 8192, 2048, 1024);
      if (c == 0)
        gemm_ring6<4, true, false, false><<<dim3(64, 4), 512, 0, stream>>>(
            h1c, 2048, f2T + (size_t)c * 2048, 4096,
            fc2_b + l * 1024, dbf, 1024, 8192, 1024, 2048);
      else
        gemm_ring6<4, true, false, true><<<dim3(64, 4), 512, 0, stream>>>(
            h1c, 2048, f2T + (size_t)c * 2048, 4096,
            nullptr, dbf, 1024, 8192, 1024, 2048);
    }
    if (l == 3)
      ln2<true><<<8192, 256, 0, stream>>>(vbf, dbf, n3_g + l * 1024, n3_b + l * 1024, nullptr, fout);
    else
      ln2<false><<<8192, 256, 0, stream>>>(vbf, dbf, n3_g + l * 1024, n3_b + l * 1024, vbf, nullptr);
  }
}

// Round 9
// 1335.877 us; speedup vs baseline: 1.0453x; 1.0144x over previous
//
#include <hip/hip_runtime.h>
#include <cstdint>
#include <cstddef>

typedef unsigned short u16;
typedef __attribute__((ext_vector_type(8))) __bf16 bf16x8;
typedef __attribute__((ext_vector_type(4))) float f32x4;

__device__ __forceinline__ f32x4 mfma_16x16x32(bf16x8 a, bf16x8 b, f32x4 c) {
  return __builtin_amdgcn_mfma_f32_16x16x32_bf16(a, b, c, 0, 0, 0);
}

__device__ __forceinline__ u16 f2bf(float f) {
  union { float f; uint32_t u; } c; c.f = f;
  uint32_t u = c.u + 0x7FFFu + ((c.u >> 16) & 1u);
  return (u16)(u >> 16);
}

__device__ __forceinline__ float bf2f(u16 x) {
  union { uint32_t u; float f; } c; c.u = ((uint32_t)x) << 16;
  return c.f;
}

__device__ __forceinline__ void gload_lds16(const void* g, void* l) {
  __builtin_amdgcn_global_load_lds(
      (__attribute__((address_space(1))) void*)(uintptr_t)g,
      (__attribute__((address_space(3))) void*)l, 16, 0, 0);
}

// ===========================================================================
// 8-phase GEMM (m201-style port).  C[M,N] = A[M,K] @ Bt[N,K]^T (+bias)(+C)(ReLU)
// BM=256, BN=128, BK=64. 512 threads = 8 waves (4M x 2N), wave tile 64x64.
// 3-buffer LDS (144 KB), prefetch dist 2.  Per K-tile: 4 phases, each
// {ds_read subtile ; 2 global_load_lds ; barrier ; lgkmcnt(0) ; setprio(1)
//  8 MFMA ; setprio(0) ; barrier}; vmcnt(6) ONLY at phase 3 (never 0 in
// steady state).  Swizzle: k-octet ^= (row&7) on 16B granules, applied on
// BOTH the pre-swizzled global source and the ds_read offset -> 2-way (free).
// M % 256 == 0, N % 128 == 0, K % 64 == 0 assumed (true for all call sites).
// ===========================================================================
template<bool OUT_BF16, bool RELU, bool ACC>
__global__ __launch_bounds__(512, 2) void gemm8p(
    const u16* __restrict__ A, int lda, const u16* __restrict__ Bt, int ldb,
    const float* __restrict__ bias, void* Cout, int ldc,
    int M, int N, int K)
{
  constexpr int BM = 256, BN = 128, BK = 64;
  constexpr int TILE = (BM + BN) * BK;        // 24576 elems = 48 KB
  __shared__ u16 lds[3 * TILE];               // 144 KB

  const int tid = threadIdx.x;
  const int lane = tid & 63, wave = tid >> 6;
  const int wm = wave >> 1, wn = wave & 1;    // 4 x 2 waves
  const int m0 = blockIdx.x * BM, n0 = blockIdx.y * BN;

  // pre-swizzled global sources. chunk c: row r=c>>3, granule q=c&7 holds
  // logical k-octet q^(r&7).
  const u16* gA[4];
  const u16* gB[2];
  #pragma unroll
  for (int i = 0; i < 4; i++) {
    int c = tid + i * 512, r = c >> 3, q = c & 7;
    gA[i] = A + (size_t)(m0 + r) * lda + ((q ^ (r & 7)) * 8);
  }
  #pragma unroll
  for (int i = 0; i < 2; i++) {
    int c = tid + i * 512, r = c >> 3, q = c & 7;
    gB[i] = Bt + (size_t)(n0 + r) * ldb + ((q ^ (r & 7)) * 8);
  }

  const int NT = K >> 6;

  // stage one third of tile t's data (pieces 0,1: A halves; 2: B)
  auto STAGE = [&](int t, int buf, int piece) {
    u16* Sb = &lds[buf * TILE];
    const int ko = t * 64;
    if (piece == 0) {
      gload_lds16(gA[0] + ko, Sb + tid * 8);
      gload_lds16(gA[1] + ko, Sb + (tid + 512) * 8);
    } else if (piece == 1) {
      gload_lds16(gA[2] + ko, Sb + (tid + 1024) * 8);
      gload_lds16(gA[3] + ko, Sb + (tid + 1536) * 8);
    } else {
      gload_lds16(gB[0] + ko, Sb + BM * 64 + tid * 8);
      gload_lds16(gB[1] + ko, Sb + BM * 64 + (tid + 512) * 8);
    }
  };

  const int fr = lane & 15, g = lane >> 4;
  // lds elem offset for a fragment: row*64 + ((oct)^(fr&7))*8  (row&7==fr&7)
  const int sx = fr & 7;

  f32x4 acc[4][4];
  #pragma unroll
  for (int m = 0; m < 4; m++)
    #pragma unroll
    for (int n = 0; n < 4; n++) acc[m][n] = f32x4{0.f, 0.f, 0.f, 0.f};

  // prologue: stage tiles 0 and 1 fully (12 loads), wait tile 0 (vmcnt(6))
  STAGE(0, 0, 0); STAGE(0, 0, 1); STAGE(0, 0, 2);
  STAGE(1, 1, 0); STAGE(1, 1, 1); STAGE(1, 1, 2);
  asm volatile("s_waitcnt vmcnt(6)" ::: "memory");
  __builtin_amdgcn_s_barrier();
  __builtin_amdgcn_sched_barrier(0);

  int cur = 0;
  for (int t = 0; t < NT; ++t) {
    const u16* As = &lds[cur * TILE];
    const u16* Bs = As + BM * 64;
    const bool st = (t + 2 < NT);
    int sbuf = cur + 2; if (sbuf >= 3) sbuf -= 3;

    bf16x8 bf[4], afA[2], afB[2];
    const int arow0 = wm * 64 + fr;          // + mf*16
    const int brow0 = wn * 64 + fr;          // + nf*16

    // ---- phase 0: B(ks0) + A rows 0-31 (ks0) ----
    #pragma unroll
    for (int nf = 0; nf < 4; nf++)
      bf[nf] = *(const bf16x8*)(Bs + (brow0 + nf * 16) * 64 + ((g ^ sx) * 8));
    #pragma unroll
    for (int mf = 0; mf < 2; mf++)
      afA[mf] = *(const bf16x8*)(As + (arow0 + mf * 16) * 64 + ((g ^ sx) * 8));
    if (st) STAGE(t + 2, sbuf, 0);
    __builtin_amdgcn_s_barrier();
    asm volatile("s_waitcnt lgkmcnt(0)" ::: "memory");
    __builtin_amdgcn_sched_barrier(0);
    __builtin_amdgcn_s_setprio(1);
    #pragma unroll
    for (int mf = 0; mf < 2; mf++)
      #pragma unroll
      for (int nf = 0; nf < 4; nf++)
        acc[mf][nf] = mfma_16x16x32(afA[mf], bf[nf], acc[mf][nf]);
    __builtin_amdgcn_s_setprio(0);
    __builtin_amdgcn_s_barrier();

    // ---- phase 1: A rows 32-63 (ks0) ----
    #pragma unroll
    for (int mf = 0; mf < 2; mf++)
      afB[mf] = *(const bf16x8*)(As + (arow0 + (mf + 2) * 16) * 64 + ((g ^ sx) * 8));
    if (st) STAGE(t + 2, sbuf, 1);
    __builtin_amdgcn_s_barrier();
    asm volatile("s_waitcnt lgkmcnt(0)" ::: "memory");
    __builtin_amdgcn_sched_barrier(0);
    __builtin_amdgcn_s_setprio(1);
    #pragma unroll
    for (int mf = 0; mf < 2; mf++)
      #pragma unroll
      for (int nf = 0; nf < 4; nf++)
        acc[mf + 2][nf] = mfma_16x16x32(afB[mf], bf[nf], acc[mf + 2][nf]);
    __builtin_amdgcn_s_setprio(0);
    __builtin_amdgcn_s_barrier();

    // ---- phase 2: B(ks1) + A rows 0-31 (ks1) ----
    #pragma unroll
    for (int nf = 0; nf < 4; nf++)
      bf[nf] = *(const bf16x8*)(Bs + (brow0 + nf * 16) * 64 + (((4 + g) ^ sx) * 8));
    #pragma unroll
    for (int mf = 0; mf < 2; mf++)
      afA[mf] = *(const bf16x8*)(As + (arow0 + mf * 16) * 64 + (((4 + g) ^ sx) * 8));
    if (st) STAGE(t + 2, sbuf, 2);
    __builtin_amdgcn_s_barrier();
    asm volatile("s_waitcnt lgkmcnt(0)" ::: "memory");
    __builtin_amdgcn_sched_barrier(0);
    __builtin_amdgcn_s_setprio(1);
    #pragma unroll
    for (int mf = 0; mf < 2; mf++)
      #pragma unroll
      for (int nf = 0; nf < 4; nf++)
        acc[mf][nf] = mfma_16x16x32(afA[mf], bf[nf], acc[mf][nf]);
    __builtin_amdgcn_s_setprio(0);
    __builtin_amdgcn_s_barrier();

    // ---- phase 3: A rows 32-63 (ks1); counted vmcnt; buffer switch ----
    #pragma unroll
    for (int mf = 0; mf < 2; mf++)
      afB[mf] = *(const bf16x8*)(As + (arow0 + (mf + 2) * 16) * 64 + (((4 + g) ^ sx) * 8));
    __builtin_amdgcn_s_barrier();
    asm volatile("s_waitcnt lgkmcnt(0)" ::: "memory");
    __builtin_amdgcn_sched_barrier(0);
    __builtin_amdgcn_s_setprio(1);
    #pragma unroll
    for (int mf = 0; mf < 2; mf++)
      #pragma unroll
      for (int nf = 0; nf < 4; nf++)
        acc[mf + 2][nf] = mfma_16x16x32(afB[mf], bf[nf], acc[mf + 2][nf]);
    __builtin_amdgcn_s_setprio(0);
    if (st) asm volatile("s_waitcnt vmcnt(6)" ::: "memory");
    else    asm volatile("s_waitcnt vmcnt(0)" ::: "memory");
    __builtin_amdgcn_sched_barrier(0);
    __builtin_amdgcn_s_barrier();
    __builtin_amdgcn_sched_barrier(0);

    cur = cur + 1 == 3 ? 0 : cur + 1;
  }

  // ---- epilogue ----
  #pragma unroll
  for (int nf = 0; nf < 4; nf++) {
    const int gcol = n0 + wn * 64 + nf * 16 + fr;
    const float bv = bias ? bias[gcol] : 0.f;
    #pragma unroll
    for (int mf = 0; mf < 4; mf++) {
      #pragma unroll
      for (int r = 0; r < 4; r++) {
        const int grow = m0 + wm * 64 + mf * 16 + g * 4 + r;
        float v = acc[mf][nf][r] + bv;
        if (ACC) v += bf2f(((const u16*)Cout)[(size_t)grow * ldc + gcol]);
        if (RELU) v = fmaxf(v, 0.f);
        if (OUT_BF16) ((u16*)Cout)[(size_t)grow * ldc + gcol] = f2bf(v);
        else         ((float*)Cout)[(size_t)grow * ldc + gcol] = v;
      }
    }
  }
}

// ---------------------------------------------------------------------------
// Small GEMM (M=400 K/V projections): 128x128 tile, BK=32.
// TRANS=true: store C transposed into vtb[((b*16+h)*64+d)*128 + j]
// ---------------------------------------------------------------------------
template<bool TRANS>
__global__ __launch_bounds__(256, 2) void gemm_bt(
    const u16* __restrict__ A, int lda, const u16* __restrict__ Bt, int ldb,
    const float* __restrict__ bias, u16* Cout, int ldc,
    int M, int N, int K)
{
  __shared__ u16 ldsA[128 * 32];
  __shared__ u16 ldsB[128 * 32];

  const int tid = threadIdx.x;
  const int lane = tid & 63, wave = tid >> 6;
  const int wr = wave >> 1, wc = wave & 1;
  const int m0 = blockIdx.x * 128, n0 = blockIdx.y * 128;

  const int c0 = tid, c1 = tid + 256;
  const int ar0 = c0 >> 2, ak0 = (c0 & 3) * 8;
  const int ar1 = c1 >> 2, ak1 = (c1 & 3) * 8;

  const bool av0 = (m0 + ar0) < M;
  const bool av1 = (m0 + ar1) < M;
  const u16* Ag0 = A + (size_t)(m0 + ar0) * lda + ak0;
  const u16* Ag1 = A + (size_t)(m0 + ar1) * lda + ak1;
  const u16* Bg0 = Bt + (size_t)(n0 + ar0) * ldb + ak0;
  const u16* Bg1 = Bt + (size_t)(n0 + ar1) * ldb + ak1;

  f32x4 acc[4][4] = {};
  const int fr = lane & 15, fo = (lane >> 4) * 8;

  for (int k0 = 0; k0 < K; k0 += 32) {
    if (av0) gload_lds16(Ag0 + k0, &ldsA[c0 * 8]);
    if (av1) gload_lds16(Ag1 + k0, &ldsA[c1 * 8]);
    gload_lds16(Bg0 + k0, &ldsB[c0 * 8]);
    gload_lds16(Bg1 + k0, &ldsB[c1 * 8]);
    asm volatile("s_waitcnt vmcnt(0)" ::: "memory");
    __syncthreads();

    bf16x8 af[4], bfr[4];
    #pragma unroll
    for (int m = 0; m < 4; m++)
      af[m] = *(const bf16x8*)&ldsA[(wr * 64 + m * 16 + fr) * 32 + fo];
    #pragma unroll
    for (int n = 0; n < 4; n++)
      bfr[n] = *(const bf16x8*)&ldsB[(wc * 64 + n * 16 + fr) * 32 + fo];
    #pragma unroll
    for (int m = 0; m < 4; m++)
      #pragma unroll
      for (int n = 0; n < 4; n++)
        acc[m][n] = mfma_16x16x32(af[m], bfr[n], acc[m][n]);
    __syncthreads();
  }

  const int g = lane >> 4;
  #pragma unroll
  for (int m = 0; m < 4; m++) {
    #pragma unroll
    for (int n = 0; n < 4; n++) {
      const int gcol = n0 + wc * 64 + n * 16 + fr;
      const float bv = bias[gcol];
      #pragma unroll
      for (int r = 0; r < 4; r++) {
        const int grow = m0 + wr * 64 + m * 16 + g * 4 + r;
        if (grow < M) {
          float v = acc[m][n][r] + bv;
          if (TRANS) {
            int bb = grow / 100, jj = grow - bb * 100;
            int h = gcol >> 6, d = gcol & 63;
            Cout[(size_t)(((bb * 16 + h) * 64 + d)) * 128 + jj] = f2bf(v);
          } else {
            Cout[(size_t)grow * ldc + gcol] = f2bf(v);
          }
        }
      }
    }
  }
}

// ---------------------------------------------------------------------------
// Weight transpose+convert: src f32 [K][N] -> dst bf16 [N][K]
// ---------------------------------------------------------------------------
__global__ void wconv_t(const float* __restrict__ src, u16* __restrict__ dst,
                        int K, int N)
{
  __shared__ float tile[32][33];
  const int n0 = blockIdx.x * 32, k0 = blockIdx.y * 32;
  const int tx = threadIdx.x, ty = threadIdx.y;
  #pragma unroll
  for (int i = 0; i < 4; i++)
    tile[ty + i * 8][tx] = src[(size_t)(k0 + ty + i * 8) * N + n0 + tx];
  __syncthreads();
  #pragma unroll
  for (int i = 0; i < 4; i++)
    dst[(size_t)(n0 + ty + i * 8) * K + k0 + tx] = f2bf(tile[tx][ty + i * 8]);
}

// ---------------------------------------------------------------------------
// Positional encoding add -> bf16 only
// ---------------------------------------------------------------------------
__global__ __launch_bounds__(256) void pe_video_k(const float* __restrict__ video,
                                                  u16* __restrict__ vbf)
{
  const int r = blockIdx.x;
  const int s = r & 2047;
  const int d0 = threadIdx.x * 4;
  const size_t base = (size_t)r * 1024 + d0;
  float4 v = *(const float4*)&video[base];
  const float coef = -9.210340371976184f / 1024.f;
  float o[4];
  float in[4] = {v.x, v.y, v.z, v.w};
  #pragma unroll
  for (int i = 0; i < 4; i++) {
    int d = d0 + i;
    int j = d >> 1;
    float dv = expf((float)(2 * j) * coef);
    float arg = (float)s * dv;
    float pe = (d & 1) ? cosf(arg) : sinf(arg);
    o[i] = in[i] + pe;
  }
  uint2 pk;
  pk.x = (uint32_t)f2bf(o[0]) | ((uint32_t)f2bf(o[1]) << 16);
  pk.y = (uint32_t)f2bf(o[2]) | ((uint32_t)f2bf(o[3]) << 16);
  *(uint2*)&vbf[base] = pk;
}

__global__ __launch_bounds__(128) void pe_text_k(const float* __restrict__ text,
                                                 u16* __restrict__ tbf)
{
  const int r = blockIdx.x;
  const int s = r % 100;
  const int d0 = threadIdx.x * 4;
  const size_t base = (size_t)r * 512 + d0;
  float4 v = *(const float4*)&text[base];
  const float coef = -9.210340371976184f / 512.f;
  float o[4];
  float in[4] = {v.x, v.y, v.z, v.w};
  #pragma unroll
  for (int i = 0; i < 4; i++) {
    int d = d0 + i;
    int j = d >> 1;
    float dv = expf((float)(2 * j) * coef);
    float arg = (float)s * dv;
    float pe = (d & 1) ? cosf(arg) : sinf(arg);
    o[i] = in[i] + pe;
  }
  uint2 pk;
  pk.x = (uint32_t)f2bf(o[0]) | ((uint32_t)f2bf(o[1]) << 16);
  pk.y = (uint32_t)f2bf(o[2]) | ((uint32_t)f2bf(o[3]) << 16);
  *(uint2*)&tbf[base] = pk;
}

// ---------------------------------------------------------------------------
// LayerNorm, bf16 residual stream: x' = LN(x + delta)*g+b
// ---------------------------------------------------------------------------
template<bool LAST>
__global__ __launch_bounds__(256) void ln2(const u16* __restrict__ xin,
                                           const u16* __restrict__ delta,
                                           const float* __restrict__ gamma,
                                           const float* __restrict__ beta,
                                           u16* __restrict__ xbf,
                                           float* __restrict__ fout)
{
  const int row = blockIdx.x;
  const size_t base = (size_t)row * 1024;
  const int t = threadIdx.x;
  const int d0 = t * 4;
  uint2 xv = *(const uint2*)&xin[base + d0];
  uint2 dv = *(const uint2*)&delta[base + d0];
  float v0 = bf2f((u16)(xv.x & 0xFFFF)) + bf2f((u16)(dv.x & 0xFFFF));
  float v1 = bf2f((u16)(xv.x >> 16))    + bf2f((u16)(dv.x >> 16));
  float v2 = bf2f((u16)(xv.y & 0xFFFF)) + bf2f((u16)(dv.y & 0xFFFF));
  float v3 = bf2f((u16)(xv.y >> 16))    + bf2f((u16)(dv.y >> 16));
  float s = v0 + v1 + v2 + v3;
  float q = v0 * v0 + v1 * v1 + v2 * v2 + v3 * v3;
  #pragma unroll
  for (int d = 32; d >= 1; d >>= 1) { s += __shfl_xor(s, d); q += __shfl_xor(q, d); }
  __shared__ float red[8];
  const int lane = t & 63, w = t >> 6;
  if (lane == 0) { red[w] = s; red[4 + w] = q; }
  __syncthreads();
  float S = red[0] + red[1] + red[2] + red[3];
  float Qs = red[4] + red[5] + red[6] + red[7];
  const float mu = S * (1.f / 1024.f);
  const float var = Qs * (1.f / 1024.f) - mu * mu;
  const float rs = rsqrtf(var + 1e-5f);
  float4 gv = *(const float4*)&gamma[d0];
  float4 bv = *(const float4*)&beta[d0];
  float o0 = (v0 - mu) * rs * gv.x + bv.x;
  float o1 = (v1 - mu) * rs * gv.y + bv.y;
  float o2 = (v2 - mu) * rs * gv.z + bv.z;
  float o3 = (v3 - mu) * rs * gv.w + bv.w;
  if (LAST) {
    *(float4*)&fout[base + d0] = make_float4(o0, o1, o2, o3);
  } else {
    uint2 pk;
    pk.x = (uint32_t)f2bf(o0) | ((uint32_t)f2bf(o1) << 16);
    pk.y = (uint32_t)f2bf(o2) | ((uint32_t)f2bf(o3) << 16);
    *(uint2*)&xbf[base + d0] = pk;
  }
}

// ---------------------------------------------------------------------------
// Cross attention v2 (verified): K from global (L2), V pre-transposed,
// P via LDS intra-wave, zero barriers.
// ---------------------------------------------------------------------------
__global__ __launch_bounds__(256) void attn_v2(
    const u16* __restrict__ Q, const u16* __restrict__ Kb,
    const u16* __restrict__ Vtb, const int* __restrict__ mask,
    u16* __restrict__ Out)
{
  __shared__ u16 ldsP[64 * 136];

  const int tid = threadIdx.x, lane = tid & 63, w = tid >> 6;
  const int qb = blockIdx.x, bh = blockIdx.y;
  const int b = bh >> 4, h = bh & 15;
  const int fr = lane & 15, g = lane >> 4, fo = g * 8;

  const size_t qrow = (size_t)(b * 2048 + qb * 64 + w * 16 + fr) * 1024 + h * 64;
  bf16x8 qf0 = *(const bf16x8*)&Q[qrow + fo];
  bf16x8 qf1 = *(const bf16x8*)&Q[qrow + 32 + fo];

  float madd[7];
  #pragma unroll
  for (int t = 0; t < 7; t++) {
    int col = t * 16 + fr;
    int mv = (col < 100) ? mask[b * 100 + col] : 0;
    madd[t] = mv ? 0.f : -1e30f;
  }

  float sc[7][4];
  #pragma unroll
  for (int t = 0; t < 7; t++) {
    int col = t * 16 + fr;
    int jr = (col < 100) ? col : 99;
    const u16* kp = Kb + (size_t)(b * 100 + jr) * 1024 + h * 64;
    bf16x8 kf0 = *(const bf16x8*)&kp[fo];
    bf16x8 kf1 = *(const bf16x8*)&kp[32 + fo];
    f32x4 a = {};
    a = mfma_16x16x32(qf0, kf0, a);
    a = mfma_16x16x32(qf1, kf1, a);
    #pragma unroll
    for (int r = 0; r < 4; r++)
      sc[t][r] = a[r] * 0.125f + madd[t];
  }

  #pragma unroll
  for (int r = 0; r < 4; r++) {
    float m = sc[0][r];
    #pragma unroll
    for (int t = 1; t < 7; t++) m = fmaxf(m, sc[t][r]);
    #pragma unroll
    for (int d = 8; d >= 1; d >>= 1) m = fmaxf(m, __shfl_xor(m, d));
    float ssum = 0.f;
    #pragma unroll
    for (int t = 0; t < 7; t++) { float p = __expf(sc[t][r] - m); sc[t][r] = p; ssum += p; }
    #pragma unroll
    for (int d = 8; d >= 1; d >>= 1) ssum += __shfl_xor(ssum, d);
    float is = 1.f / ssum;
    #pragma unroll
    for (int t = 0; t < 7; t++)
      ldsP[(w * 16 + g * 4 + r) * 136 + t * 16 + fr] = f2bf(sc[t][r] * is);
  }
  {
    u16* zp = &ldsP[(w * 16 + fr) * 136 + 112 + g * 6];
    #pragma unroll
    for (int i = 0; i < 6; i++) zp[i] = 0;
  }

  bf16x8 pa[4];
  #pragma unroll
  for (int kk = 0; kk < 4; kk++)
    pa[kk] = *(const bf16x8*)&ldsP[(w * 16 + fr) * 136 + kk * 32 + fo];
  const u16* vtbase = Vtb + (size_t)bh * 64 * 128;
  #pragma unroll
  for (int nt = 0; nt < 4; nt++) {
    f32x4 a = {};
    #pragma unroll
    for (int kk = 0; kk < 4; kk++) {
      bf16x8 vf = *(const bf16x8*)&vtbase[(size_t)(nt * 16 + fr) * 128 + kk * 32 + fo];
      a = mfma_16x16x32(pa[kk], vf, a);
    }
    #pragma unroll
    for (int r = 0; r < 4; r++) {
      size_t orow = (size_t)(b * 2048 + qb * 64 + w * 16 + g * 4 + r) * 1024 + h * 64 + nt * 16 + fr;
      Out[orow] = f2bf(a[r]);
    }
  }
}

// ---------------------------------------------------------------------------
extern "C" void kernel_launch(void* const* d_in, const int* in_sizes, int n_in,
                              void* d_out, int out_size, void* d_ws, size_t ws_size,
                              hipStream_t stream) {
  const float* video = (const float*)d_in[0];
  const float* text  = (const float*)d_in[1];
  const int*   text_mask = (const int*)d_in[2];
  const float* Wq_w = (const float*)d_in[3];
  const float* Wq_b = (const float*)d_in[4];
  const float* Wk_w = (const float*)d_in[5];
  const float* Wk_b = (const float*)d_in[6];
  const float* Wv_w = (const float*)d_in[7];
  const float* Wv_b = (const float*)d_in[8];
  const float* Wo_w = (const float*)d_in[9];
  const float* Wo_b = (const float*)d_in[10];
  const float* fc1_w = (const float*)d_in[11];
  const float* fc1_b = (const float*)d_in[12];
  const float* fc2_w = (const float*)d_in[13];
  const float* fc2_b = (const float*)d_in[14];
  const float* n2_g = (const float*)d_in[15];
  const float* n2_b = (const float*)d_in[16];
  const float* n3_g = (const float*)d_in[17];
  const float* n3_b = (const float*)d_in[18];

  char* ws = (char*)d_ws;
  size_t off = 0;
  auto alloc = [&](size_t bytes) {
    char* p = ws + off;
    off += (bytes + 255) & ~(size_t)255;
    return p;
  };
  u16* vbf = (u16*)alloc((size_t)8192 * 1024 * 2);     // 16 MB residual (bf16)
  u16* tbf = (u16*)alloc((size_t)400 * 512 * 2);
  u16* wqT = (u16*)alloc((size_t)1024 * 1024 * 2);
  u16* wkT = (u16*)alloc((size_t)1024 * 512 * 2);
  u16* wvT = (u16*)alloc((size_t)1024 * 512 * 2);
  u16* woT = (u16*)alloc((size_t)1024 * 1024 * 2);
  u16* f1T = (u16*)alloc((size_t)4096 * 1024 * 2);
  u16* f2T = (u16*)alloc((size_t)1024 * 4096 * 2);
  char* S = alloc((size_t)35192832);                   // union scratch
  u16* qbf  = (u16*)S;
  u16* kbf  = (u16*)(S + 16777216);
  u16* abf  = (u16*)(S + 16777216 + 1638400);
  u16* h1c  = (u16*)S;
  u16* vtb  = (u16*)alloc((size_t)64 * 64 * 128 * 2);  // 2 MB V^T (not aliased)
  u16* dbf  = (u16*)alloc((size_t)8192 * 1024 * 2);
  float* fout = (float*)d_out;

  hipMemsetAsync(vtb, 0, (size_t)64 * 64 * 128 * 2, stream);

  pe_video_k<<<8192, 256, 0, stream>>>(video, vbf);
  pe_text_k<<<400, 128, 0, stream>>>(text, tbf);

  dim3 tb(32, 8, 1);
  for (int l = 0; l < 4; ++l) {
    wconv_t<<<dim3(32, 32), tb, 0, stream>>>(Wq_w + (size_t)l * 1024 * 1024, wqT, 1024, 1024);
    wconv_t<<<dim3(32, 16), tb, 0, stream>>>(Wk_w + (size_t)l * 512 * 1024, wkT, 512, 1024);
    wconv_t<<<dim3(32, 16), tb, 0, stream>>>(Wv_w + (size_t)l * 512 * 1024, wvT, 512, 1024);
    wconv_t<<<dim3(32, 32), tb, 0, stream>>>(Wo_w + (size_t)l * 1024 * 1024, woT, 1024, 1024);
    wconv_t<<<dim3(128, 32), tb, 0, stream>>>(fc1_w + (size_t)l * 1024 * 4096, f1T, 1024, 4096);
    wconv_t<<<dim3(32, 128), tb, 0, stream>>>(fc2_w + (size_t)l * 4096 * 1024, f2T, 4096, 1024);

    gemm8p<true, false, false><<<dim3(32, 8), 512, 0, stream>>>(
        vbf, 1024, wqT, 1024, Wq_b + l * 1024, qbf, 1024, 8192, 1024, 1024);
    gemm_bt<false><<<dim3(4, 8), 256, 0, stream>>>(
        tbf, 512, wkT, 512, Wk_b + l * 1024, kbf, 1024, 400, 1024, 512);
    gemm_bt<true><<<dim3(4, 8), 256, 0, stream>>>(
        tbf, 512, wvT, 512, Wv_b + l * 1024, vtb, 1024, 400, 1024, 512);
    attn_v2<<<dim3(32, 64), 256, 0, stream>>>(qbf, kbf, vtb, text_mask, abf);
    gemm8p<true, false, false><<<dim3(32, 8), 512, 0, stream>>>(
        abf, 1024, woT, 1024, Wo_b + l * 1024, dbf, 1024, 8192, 1024, 1024);
    ln2<false><<<8192, 256, 0, stream>>>(vbf, dbf, n2_g + l * 1024, n2_b + l * 1024, vbf, nullptr);

    for (int c = 0; c < 2; ++c) {
      gemm8p<true, true, false><<<dim3(32, 16), 512, 0, stream>>>(
          vbf, 1024, f1T + (size_t)c * 2048 * 1024, 1024,
          fc1_b + l * 4096 + c * 2048, h1c, 2048, 8192, 2048, 1024);
      if (c == 0)
        gemm8p<true, false, false><<<dim3(32, 8), 512, 0, stream>>>(
            h1c, 2048, f2T + (size_t)c * 2048, 4096,
            fc2_b + l * 1024, dbf, 1024, 8192, 1024, 2048);
      else
        gemm8p<true, false, true><<<dim3(32, 8), 512, 0, stream>>>(
            h1c, 2048, f2T + (size_t)c * 2048, 4096,
            nullptr, dbf, 1024, 8192, 1024, 2048);
    }
    if (l == 3)
      ln2<true><<<8192, 256, 0, stream>>>(vbf, dbf, n3_g + l * 1024, n3_b + l * 1024, nullptr, fout);
    else
      ln2<false><<<8192, 256, 0, stream>>>(vbf, dbf, n3_g + l * 1024, n3_b + l * 1024, vbf, nullptr);
  }
}

// Round 10
// 1331.137 us; speedup vs baseline: 1.0490x; 1.0036x over previous
//
#include <hip/hip_runtime.h>
#include <cstdint>
#include <cstddef>

typedef unsigned short u16;
typedef __attribute__((ext_vector_type(8))) __bf16 bf16x8;
typedef __attribute__((ext_vector_type(4))) float f32x4;

__device__ __forceinline__ f32x4 mfma_16x16x32(bf16x8 a, bf16x8 b, f32x4 c) {
  return __builtin_amdgcn_mfma_f32_16x16x32_bf16(a, b, c, 0, 0, 0);
}

__device__ __forceinline__ u16 f2bf(float f) {
  union { float f; uint32_t u; } c; c.f = f;
  uint32_t u = c.u + 0x7FFFu + ((c.u >> 16) & 1u);
  return (u16)(u >> 16);
}

__device__ __forceinline__ float bf2f(u16 x) {
  union { uint32_t u; float f; } c; c.u = ((uint32_t)x) << 16;
  return c.f;
}

__device__ __forceinline__ void gload_lds16(const void* g, void* l) {
  __builtin_amdgcn_global_load_lds(
      (__attribute__((address_space(1))) void*)(uintptr_t)g,
      (__attribute__((address_space(3))) void*)l, 16, 0, 0);
}

// ===========================================================================
// gemm256: true 256x256-tile 4-phase kernel (m201-geometry).
// BM=BN=256, BK=64. 512 threads = 8 waves (2M x 4N), wave tile 128x64,
// acc[8][4].  2-buffer LDS (128 KB).  Per K-tile 4 phases:
//   ph0: read B(ks0)+A(m0-3,ks0); stage P0{A0,A2,B0,B1}; bar; lgk; 16 MFMA;
//        vmcnt(4) [gates A1,A3]; bar
//   ph1: read A(m4-7,ks0); stage P1{B2,B3,A1,A3}; bar; lgk; 16 MFMA; bar
//   ph2: read B(ks1)+A(m0-3,ks1); bar; lgk; 16 MFMA; bar
//   ph3: read A(m4-7,ks1); bar; lgk; 16 MFMA; vmcnt(2) boundary; bar
// Counted vmcnt never drains to 0 in steady state (in-order accounting:
// boundary leaves A1,A3 in flight; ph0's vmcnt(4) completes them with
// ~1.5 phases of cover).  Octet swizzle q^=row&7 on BOTH global source and
// ds_read offset (structure measured conflict-free rounds 5-9).
// Requires M%256==0, N%256==0, K%64==0.
// ===========================================================================
template<bool OUT_BF16, bool RELU>
__global__ __launch_bounds__(512, 2) void gemm256(
    const u16* __restrict__ A, int lda, const u16* __restrict__ Bt, int ldb,
    const float* __restrict__ bias, void* Cout, int ldc,
    int M, int N, int K)
{
  constexpr int BM = 256, BK = 64;
  constexpr int TILE = 512 * BK;              // 32768 elems = 64 KB
  __shared__ u16 lds[2 * TILE];               // 128 KB

  const int tid = threadIdx.x;
  const int lane = tid & 63, wave = tid >> 6;
  const int wm = wave >> 2, wn = wave & 3;    // 2M x 4N
  const int m0 = blockIdx.x * 256, n0 = blockIdx.y * 256;

  // pre-swizzled global sources: chunk c = tid + i*512, row r=c>>3,
  // granule q=c&7 receives logical octet q^(r&7)
  const u16* gA[4];
  const u16* gB[4];
  #pragma unroll
  for (int i = 0; i < 4; i++) {
    int c = tid + i * 512, r = c >> 3, q = c & 7;
    gA[i] = A + (size_t)(m0 + r) * lda + ((q ^ (r & 7)) * 8);
    gB[i] = Bt + (size_t)(n0 + r) * ldb + ((q ^ (r & 7)) * 8);
  }

  const int NT = K >> 6;

  // piece P0: A loads {0,2} + B loads {0,1}
  auto STAGE_P0 = [&](int t, int buf) {
    u16* Sb = &lds[buf * TILE];
    const int ko = t * 64;
    gload_lds16(gA[0] + ko, Sb + (tid) * 8);
    gload_lds16(gA[2] + ko, Sb + (tid + 1024) * 8);
    gload_lds16(gB[0] + ko, Sb + BM * 64 + (tid) * 8);
    gload_lds16(gB[1] + ko, Sb + BM * 64 + (tid + 512) * 8);
  };
  // piece P1: B loads {2,3} first, then A loads {1,3} LAST (boundary leaves
  // only A1,A3 outstanding)
  auto STAGE_P1 = [&](int t, int buf) {
    u16* Sb = &lds[buf * TILE];
    const int ko = t * 64;
    gload_lds16(gB[2] + ko, Sb + BM * 64 + (tid + 1024) * 8);
    gload_lds16(gB[3] + ko, Sb + BM * 64 + (tid + 1536) * 8);
    gload_lds16(gA[1] + ko, Sb + (tid + 512) * 8);
    gload_lds16(gA[3] + ko, Sb + (tid + 1536) * 8);
  };

  const int fr = lane & 15, g = lane >> 4;
  const int sx = fr & 7;

  f32x4 acc[8][4];
  #pragma unroll
  for (int m = 0; m < 8; m++)
    #pragma unroll
    for (int n = 0; n < 4; n++) acc[m][n] = f32x4{0.f, 0.f, 0.f, 0.f};

  // prologue: tile 0 fully staged, A1/A3 last; wait all but those 2
  STAGE_P0(0, 0);
  STAGE_P1(0, 0);
  asm volatile("s_waitcnt vmcnt(2)" ::: "memory");
  __builtin_amdgcn_s_barrier();
  __builtin_amdgcn_sched_barrier(0);

  int cur = 0;
  for (int t = 0; t < NT; ++t) {
    const u16* As = &lds[cur * TILE];
    const u16* Bs = As + BM * 64;
    const bool stg = (t + 1 < NT);
    const int nxt = cur ^ 1;

    const int arow0 = wm * 128 + fr;
    const int brow0 = wn * 64 + fr;
    bf16x8 bf[4], af[4];

    // ---------------- phase 0 ----------------
    #pragma unroll
    for (int nf = 0; nf < 4; nf++)
      bf[nf] = *(const bf16x8*)(Bs + (brow0 + nf * 16) * 64 + ((g ^ sx) * 8));
    #pragma unroll
    for (int mf = 0; mf < 4; mf++)
      af[mf] = *(const bf16x8*)(As + (arow0 + mf * 16) * 64 + ((g ^ sx) * 8));
    if (stg) STAGE_P0(t + 1, nxt);
    __builtin_amdgcn_s_barrier();
    asm volatile("s_waitcnt lgkmcnt(0)" ::: "memory");
    __builtin_amdgcn_sched_barrier(0);
    __builtin_amdgcn_s_setprio(1);
    #pragma unroll
    for (int mf = 0; mf < 4; mf++)
      #pragma unroll
      for (int nf = 0; nf < 4; nf++)
        acc[mf][nf] = mfma_16x16x32(af[mf], bf[nf], acc[mf][nf]);
    __builtin_amdgcn_s_setprio(0);
    if (stg) asm volatile("s_waitcnt vmcnt(4)" ::: "memory");
    else     asm volatile("s_waitcnt vmcnt(0)" ::: "memory");
    __builtin_amdgcn_sched_barrier(0);
    __builtin_amdgcn_s_barrier();

    // ---------------- phase 1 ----------------
    #pragma unroll
    for (int mf = 0; mf < 4; mf++)
      af[mf] = *(const bf16x8*)(As + (arow0 + (mf + 4) * 16) * 64 + ((g ^ sx) * 8));
    if (stg) STAGE_P1(t + 1, nxt);
    __builtin_amdgcn_s_barrier();
    asm volatile("s_waitcnt lgkmcnt(0)" ::: "memory");
    __builtin_amdgcn_sched_barrier(0);
    __builtin_amdgcn_s_setprio(1);
    #pragma unroll
    for (int mf = 0; mf < 4; mf++)
      #pragma unroll
      for (int nf = 0; nf < 4; nf++)
        acc[mf + 4][nf] = mfma_16x16x32(af[mf], bf[nf], acc[mf + 4][nf]);
    __builtin_amdgcn_s_setprio(0);
    __builtin_amdgcn_s_barrier();

    // ---------------- phase 2 ----------------
    #pragma unroll
    for (int nf = 0; nf < 4; nf++)
      bf[nf] = *(const bf16x8*)(Bs + (brow0 + nf * 16) * 64 + (((4 + g) ^ sx) * 8));
    #pragma unroll
    for (int mf = 0; mf < 4; mf++)
      af[mf] = *(const bf16x8*)(As + (arow0 + mf * 16) * 64 + (((4 + g) ^ sx) * 8));
    __builtin_amdgcn_s_barrier();
    asm volatile("s_waitcnt lgkmcnt(0)" ::: "memory");
    __builtin_amdgcn_sched_barrier(0);
    __builtin_amdgcn_s_setprio(1);
    #pragma unroll
    for (int mf = 0; mf < 4; mf++)
      #pragma unroll
      for (int nf = 0; nf < 4; nf++)
        acc[mf][nf] = mfma_16x16x32(af[mf], bf[nf], acc[mf][nf]);
    __builtin_amdgcn_s_setprio(0);
    __builtin_amdgcn_s_barrier();

    // ---------------- phase 3 ----------------
    #pragma unroll
    for (int mf = 0; mf < 4; mf++)
      af[mf] = *(const bf16x8*)(As + (arow0 + (mf + 4) * 16) * 64 + (((4 + g) ^ sx) * 8));
    __builtin_amdgcn_s_barrier();
    asm volatile("s_waitcnt lgkmcnt(0)" ::: "memory");
    __builtin_amdgcn_sched_barrier(0);
    __builtin_amdgcn_s_setprio(1);
    #pragma unroll
    for (int mf = 0; mf < 4; mf++)
      #pragma unroll
      for (int nf = 0; nf < 4; nf++)
        acc[mf + 4][nf] = mfma_16x16x32(af[mf], bf[nf], acc[mf + 4][nf]);
    __builtin_amdgcn_s_setprio(0);
    if (stg) asm volatile("s_waitcnt vmcnt(2)" ::: "memory");
    __builtin_amdgcn_sched_barrier(0);
    __builtin_amdgcn_s_barrier();
    __builtin_amdgcn_sched_barrier(0);

    cur = nxt;
  }

  // ---- epilogue ----
  #pragma unroll
  for (int nf = 0; nf < 4; nf++) {
    const int gcol = n0 + wn * 64 + nf * 16 + fr;
    const float bv = bias ? bias[gcol] : 0.f;
    #pragma unroll
    for (int mf = 0; mf < 8; mf++) {
      #pragma unroll
      for (int r = 0; r < 4; r++) {
        const int grow = m0 + wm * 128 + mf * 16 + g * 4 + r;
        float v = acc[mf][nf][r] + bv;
        if (RELU) v = fmaxf(v, 0.f);
        if (OUT_BF16) ((u16*)Cout)[(size_t)grow * ldc + gcol] = f2bf(v);
        else         ((float*)Cout)[(size_t)grow * ldc + gcol] = v;
      }
    }
  }
}

// ===========================================================================
// gemm8p (round-9, unchanged): BM=256 BN=128 BK=64, 8 waves, 3-buffer ring.
// ===========================================================================
template<bool OUT_BF16, bool RELU, bool ACC>
__global__ __launch_bounds__(512, 2) void gemm8p(
    const u16* __restrict__ A, int lda, const u16* __restrict__ Bt, int ldb,
    const float* __restrict__ bias, void* Cout, int ldc,
    int M, int N, int K)
{
  constexpr int BM = 256, BN = 128, BK = 64;
  constexpr int TILE = (BM + BN) * BK;
  __shared__ u16 lds[3 * TILE];

  const int tid = threadIdx.x;
  const int lane = tid & 63, wave = tid >> 6;
  const int wm = wave >> 1, wn = wave & 1;
  const int m0 = blockIdx.x * BM, n0 = blockIdx.y * BN;

  const u16* gA[4];
  const u16* gB[2];
  #pragma unroll
  for (int i = 0; i < 4; i++) {
    int c = tid + i * 512, r = c >> 3, q = c & 7;
    gA[i] = A + (size_t)(m0 + r) * lda + ((q ^ (r & 7)) * 8);
  }
  #pragma unroll
  for (int i = 0; i < 2; i++) {
    int c = tid + i * 512, r = c >> 3, q = c & 7;
    gB[i] = Bt + (size_t)(n0 + r) * ldb + ((q ^ (r & 7)) * 8);
  }

  const int NT = K >> 6;

  auto STAGE = [&](int t, int buf, int piece) {
    u16* Sb = &lds[buf * TILE];
    const int ko = t * 64;
    if (piece == 0) {
      gload_lds16(gA[0] + ko, Sb + tid * 8);
      gload_lds16(gA[1] + ko, Sb + (tid + 512) * 8);
    } else if (piece == 1) {
      gload_lds16(gA[2] + ko, Sb + (tid + 1024) * 8);
      gload_lds16(gA[3] + ko, Sb + (tid + 1536) * 8);
    } else {
      gload_lds16(gB[0] + ko, Sb + BM * 64 + tid * 8);
      gload_lds16(gB[1] + ko, Sb + BM * 64 + (tid + 512) * 8);
    }
  };

  const int fr = lane & 15, g = lane >> 4;
  const int sx = fr & 7;

  f32x4 acc[4][4];
  #pragma unroll
  for (int m = 0; m < 4; m++)
    #pragma unroll
    for (int n = 0; n < 4; n++) acc[m][n] = f32x4{0.f, 0.f, 0.f, 0.f};

  STAGE(0, 0, 0); STAGE(0, 0, 1); STAGE(0, 0, 2);
  STAGE(1, 1, 0); STAGE(1, 1, 1); STAGE(1, 1, 2);
  asm volatile("s_waitcnt vmcnt(6)" ::: "memory");
  __builtin_amdgcn_s_barrier();
  __builtin_amdgcn_sched_barrier(0);

  int cur = 0;
  for (int t = 0; t < NT; ++t) {
    const u16* As = &lds[cur * TILE];
    const u16* Bs = As + BM * 64;
    const bool st = (t + 2 < NT);
    int sbuf = cur + 2; if (sbuf >= 3) sbuf -= 3;

    bf16x8 bf[4], afA[2], afB[2];
    const int arow0 = wm * 64 + fr;
    const int brow0 = wn * 64 + fr;

    #pragma unroll
    for (int nf = 0; nf < 4; nf++)
      bf[nf] = *(const bf16x8*)(Bs + (brow0 + nf * 16) * 64 + ((g ^ sx) * 8));
    #pragma unroll
    for (int mf = 0; mf < 2; mf++)
      afA[mf] = *(const bf16x8*)(As + (arow0 + mf * 16) * 64 + ((g ^ sx) * 8));
    if (st) STAGE(t + 2, sbuf, 0);
    __builtin_amdgcn_s_barrier();
    asm volatile("s_waitcnt lgkmcnt(0)" ::: "memory");
    __builtin_amdgcn_sched_barrier(0);
    __builtin_amdgcn_s_setprio(1);
    #pragma unroll
    for (int mf = 0; mf < 2; mf++)
      #pragma unroll
      for (int nf = 0; nf < 4; nf++)
        acc[mf][nf] = mfma_16x16x32(afA[mf], bf[nf], acc[mf][nf]);
    __builtin_amdgcn_s_setprio(0);
    __builtin_amdgcn_s_barrier();

    #pragma unroll
    for (int mf = 0; mf < 2; mf++)
      afB[mf] = *(const bf16x8*)(As + (arow0 + (mf + 2) * 16) * 64 + ((g ^ sx) * 8));
    if (st) STAGE(t + 2, sbuf, 1);
    __builtin_amdgcn_s_barrier();
    asm volatile("s_waitcnt lgkmcnt(0)" ::: "memory");
    __builtin_amdgcn_sched_barrier(0);
    __builtin_amdgcn_s_setprio(1);
    #pragma unroll
    for (int mf = 0; mf < 2; mf++)
      #pragma unroll
      for (int nf = 0; nf < 4; nf++)
        acc[mf + 2][nf] = mfma_16x16x32(afB[mf], bf[nf], acc[mf + 2][nf]);
    __builtin_amdgcn_s_setprio(0);
    __builtin_amdgcn_s_barrier();

    #pragma unroll
    for (int nf = 0; nf < 4; nf++)
      bf[nf] = *(const bf16x8*)(Bs + (brow0 + nf * 16) * 64 + (((4 + g) ^ sx) * 8));
    #pragma unroll
    for (int mf = 0; mf < 2; mf++)
      afA[mf] = *(const bf16x8*)(As + (arow0 + mf * 16) * 64 + (((4 + g) ^ sx) * 8));
    if (st) STAGE(t + 2, sbuf, 2);
    __builtin_amdgcn_s_barrier();
    asm volatile("s_waitcnt lgkmcnt(0)" ::: "memory");
    __builtin_amdgcn_sched_barrier(0);
    __builtin_amdgcn_s_setprio(1);
    #pragma unroll
    for (int mf = 0; mf < 2; mf++)
      #pragma unroll
      for (int nf = 0; nf < 4; nf++)
        acc[mf][nf] = mfma_16x16x32(afA[mf], bf[nf], acc[mf][nf]);
    __builtin_amdgcn_s_setprio(0);
    __builtin_amdgcn_s_barrier();

    #pragma unroll
    for (int mf = 0; mf < 2; mf++)
      afB[mf] = *(const bf16x8*)(As + (arow0 + (mf + 2) * 16) * 64 + (((4 + g) ^ sx) * 8));
    __builtin_amdgcn_s_barrier();
    asm volatile("s_waitcnt lgkmcnt(0)" ::: "memory");
    __builtin_amdgcn_sched_barrier(0);
    __builtin_amdgcn_s_setprio(1);
    #pragma unroll
    for (int mf = 0; mf < 2; mf++)
      #pragma unroll
      for (int nf = 0; nf < 4; nf++)
        acc[mf + 2][nf] = mfma_16x16x32(afB[mf], bf[nf], acc[mf + 2][nf]);
    __builtin_amdgcn_s_setprio(0);
    if (st) asm volatile("s_waitcnt vmcnt(6)" ::: "memory");
    else    asm volatile("s_waitcnt vmcnt(0)" ::: "memory");
    __builtin_amdgcn_sched_barrier(0);
    __builtin_amdgcn_s_barrier();
    __builtin_amdgcn_sched_barrier(0);

    cur = cur + 1 == 3 ? 0 : cur + 1;
  }

  #pragma unroll
  for (int nf = 0; nf < 4; nf++) {
    const int gcol = n0 + wn * 64 + nf * 16 + fr;
    const float bv = bias ? bias[gcol] : 0.f;
    #pragma unroll
    for (int mf = 0; mf < 4; mf++) {
      #pragma unroll
      for (int r = 0; r < 4; r++) {
        const int grow = m0 + wm * 64 + mf * 16 + g * 4 + r;
        float v = acc[mf][nf][r] + bv;
        if (ACC) v += bf2f(((const u16*)Cout)[(size_t)grow * ldc + gcol]);
        if (RELU) v = fmaxf(v, 0.f);
        if (OUT_BF16) ((u16*)Cout)[(size_t)grow * ldc + gcol] = f2bf(v);
        else         ((float*)Cout)[(size_t)grow * ldc + gcol] = v;
      }
    }
  }
}

// ---------------------------------------------------------------------------
// Small GEMM (M=400 K/V projections): 128x128 tile, BK=32.
// TRANS=true: store C transposed into vtb[((b*16+h)*64+d)*128 + j]
// ---------------------------------------------------------------------------
template<bool TRANS>
__global__ __launch_bounds__(256, 2) void gemm_bt(
    const u16* __restrict__ A, int lda, const u16* __restrict__ Bt, int ldb,
    const float* __restrict__ bias, u16* Cout, int ldc,
    int M, int N, int K)
{
  __shared__ u16 ldsA[128 * 32];
  __shared__ u16 ldsB[128 * 32];

  const int tid = threadIdx.x;
  const int lane = tid & 63, wave = tid >> 6;
  const int wr = wave >> 1, wc = wave & 1;
  const int m0 = blockIdx.x * 128, n0 = blockIdx.y * 128;

  const int c0 = tid, c1 = tid + 256;
  const int ar0 = c0 >> 2, ak0 = (c0 & 3) * 8;
  const int ar1 = c1 >> 2, ak1 = (c1 & 3) * 8;

  const bool av0 = (m0 + ar0) < M;
  const bool av1 = (m0 + ar1) < M;
  const u16* Ag0 = A + (size_t)(m0 + ar0) * lda + ak0;
  const u16* Ag1 = A + (size_t)(m0 + ar1) * lda + ak1;
  const u16* Bg0 = Bt + (size_t)(n0 + ar0) * ldb + ak0;
  const u16* Bg1 = Bt + (size_t)(n0 + ar1) * ldb + ak1;

  f32x4 acc[4][4] = {};
  const int fr = lane & 15, fo = (lane >> 4) * 8;

  for (int k0 = 0; k0 < K; k0 += 32) {
    if (av0) gload_lds16(Ag0 + k0, &ldsA[c0 * 8]);
    if (av1) gload_lds16(Ag1 + k0, &ldsA[c1 * 8]);
    gload_lds16(Bg0 + k0, &ldsB[c0 * 8]);
    gload_lds16(Bg1 + k0, &ldsB[c1 * 8]);
    asm volatile("s_waitcnt vmcnt(0)" ::: "memory");
    __syncthreads();

    bf16x8 af[4], bfr[4];
    #pragma unroll
    for (int m = 0; m < 4; m++)
      af[m] = *(const bf16x8*)&ldsA[(wr * 64 + m * 16 + fr) * 32 + fo];
    #pragma unroll
    for (int n = 0; n < 4; n++)
      bfr[n] = *(const bf16x8*)&ldsB[(wc * 64 + n * 16 + fr) * 32 + fo];
    #pragma unroll
    for (int m = 0; m < 4; m++)
      #pragma unroll
      for (int n = 0; n < 4; n++)
        acc[m][n] = mfma_16x16x32(af[m], bfr[n], acc[m][n]);
    __syncthreads();
  }

  const int g = lane >> 4;
  #pragma unroll
  for (int m = 0; m < 4; m++) {
    #pragma unroll
    for (int n = 0; n < 4; n++) {
      const int gcol = n0 + wc * 64 + n * 16 + fr;
      const float bv = bias[gcol];
      #pragma unroll
      for (int r = 0; r < 4; r++) {
        const int grow = m0 + wr * 64 + m * 16 + g * 4 + r;
        if (grow < M) {
          float v = acc[m][n][r] + bv;
          if (TRANS) {
            int bb = grow / 100, jj = grow - bb * 100;
            int h = gcol >> 6, d = gcol & 63;
            Cout[(size_t)(((bb * 16 + h) * 64 + d)) * 128 + jj] = f2bf(v);
          } else {
            Cout[(size_t)grow * ldc + gcol] = f2bf(v);
          }
        }
      }
    }
  }
}

// ---------------------------------------------------------------------------
// Weight transpose+convert: src f32 [K][N] -> dst bf16 [N][K]
// ---------------------------------------------------------------------------
__global__ void wconv_t(const float* __restrict__ src, u16* __restrict__ dst,
                        int K, int N)
{
  __shared__ float tile[32][33];
  const int n0 = blockIdx.x * 32, k0 = blockIdx.y * 32;
  const int tx = threadIdx.x, ty = threadIdx.y;
  #pragma unroll
  for (int i = 0; i < 4; i++)
    tile[ty + i * 8][tx] = src[(size_t)(k0 + ty + i * 8) * N + n0 + tx];
  __syncthreads();
  #pragma unroll
  for (int i = 0; i < 4; i++)
    dst[(size_t)(n0 + ty + i * 8) * K + k0 + tx] = f2bf(tile[tx][ty + i * 8]);
}

// ---------------------------------------------------------------------------
// Positional encoding add -> bf16 only
// ---------------------------------------------------------------------------
__global__ __launch_bounds__(256) void pe_video_k(const float* __restrict__ video,
                                                  u16* __restrict__ vbf)
{
  const int r = blockIdx.x;
  const int s = r & 2047;
  const int d0 = threadIdx.x * 4;
  const size_t base = (size_t)r * 1024 + d0;
  float4 v = *(const float4*)&video[base];
  const float coef = -9.210340371976184f / 1024.f;
  float o[4];
  float in[4] = {v.x, v.y, v.z, v.w};
  #pragma unroll
  for (int i = 0; i < 4; i++) {
    int d = d0 + i;
    int j = d >> 1;
    float dv = expf((float)(2 * j) * coef);
    float arg = (float)s * dv;
    float pe = (d & 1) ? cosf(arg) : sinf(arg);
    o[i] = in[i] + pe;
  }
  uint2 pk;
  pk.x = (uint32_t)f2bf(o[0]) | ((uint32_t)f2bf(o[1]) << 16);
  pk.y = (uint32_t)f2bf(o[2]) | ((uint32_t)f2bf(o[3]) << 16);
  *(uint2*)&vbf[base] = pk;
}

__global__ __launch_bounds__(128) void pe_text_k(const float* __restrict__ text,
                                                 u16* __restrict__ tbf)
{
  const int r = blockIdx.x;
  const int s = r % 100;
  const int d0 = threadIdx.x * 4;
  const size_t base = (size_t)r * 512 + d0;
  float4 v = *(const float4*)&text[base];
  const float coef = -9.210340371976184f / 512.f;
  float o[4];
  float in[4] = {v.x, v.y, v.z, v.w};
  #pragma unroll
  for (int i = 0; i < 4; i++) {
    int d = d0 + i;
    int j = d >> 1;
    float dv = expf((float)(2 * j) * coef);
    float arg = (float)s * dv;
    float pe = (d & 1) ? cosf(arg) : sinf(arg);
    o[i] = in[i] + pe;
  }
  uint2 pk;
  pk.x = (uint32_t)f2bf(o[0]) | ((uint32_t)f2bf(o[1]) << 16);
  pk.y = (uint32_t)f2bf(o[2]) | ((uint32_t)f2bf(o[3]) << 16);
  *(uint2*)&tbf[base] = pk;
}

// ---------------------------------------------------------------------------
// LayerNorm, bf16 residual stream: x' = LN(x + delta)*g+b
// ---------------------------------------------------------------------------
template<bool LAST>
__global__ __launch_bounds__(256) void ln2(const u16* __restrict__ xin,
                                           const u16* __restrict__ delta,
                                           const float* __restrict__ gamma,
                                           const float* __restrict__ beta,
                                           u16* __restrict__ xbf,
                                           float* __restrict__ fout)
{
  const int row = blockIdx.x;
  const size_t base = (size_t)row * 1024;
  const int t = threadIdx.x;
  const int d0 = t * 4;
  uint2 xv = *(const uint2*)&xin[base + d0];
  uint2 dv = *(const uint2*)&delta[base + d0];
  float v0 = bf2f((u16)(xv.x & 0xFFFF)) + bf2f((u16)(dv.x & 0xFFFF));
  float v1 = bf2f((u16)(xv.x >> 16))    + bf2f((u16)(dv.x >> 16));
  float v2 = bf2f((u16)(xv.y & 0xFFFF)) + bf2f((u16)(dv.y & 0xFFFF));
  float v3 = bf2f((u16)(xv.y >> 16))    + bf2f((u16)(dv.y >> 16));
  float s = v0 + v1 + v2 + v3;
  float q = v0 * v0 + v1 * v1 + v2 * v2 + v3 * v3;
  #pragma unroll
  for (int d = 32; d >= 1; d >>= 1) { s += __shfl_xor(s, d); q += __shfl_xor(q, d); }
  __shared__ float red[8];
  const int lane = t & 63, w = t >> 6;
  if (lane == 0) { red[w] = s; red[4 + w] = q; }
  __syncthreads();
  float S = red[0] + red[1] + red[2] + red[3];
  float Qs = red[4] + red[5] + red[6] + red[7];
  const float mu = S * (1.f / 1024.f);
  const float var = Qs * (1.f / 1024.f) - mu * mu;
  const float rs = rsqrtf(var + 1e-5f);
  float4 gv = *(const float4*)&gamma[d0];
  float4 bv = *(const float4*)&beta[d0];
  float o0 = (v0 - mu) * rs * gv.x + bv.x;
  float o1 = (v1 - mu) * rs * gv.y + bv.y;
  float o2 = (v2 - mu) * rs * gv.z + bv.z;
  float o3 = (v3 - mu) * rs * gv.w + bv.w;
  if (LAST) {
    *(float4*)&fout[base + d0] = make_float4(o0, o1, o2, o3);
  } else {
    uint2 pk;
    pk.x = (uint32_t)f2bf(o0) | ((uint32_t)f2bf(o1) << 16);
    pk.y = (uint32_t)f2bf(o2) | ((uint32_t)f2bf(o3) << 16);
    *(uint2*)&xbf[base + d0] = pk;
  }
}

// ---------------------------------------------------------------------------
// Cross attention v2 (verified): K from global (L2), V pre-transposed,
// P via LDS intra-wave, zero barriers.
// ---------------------------------------------------------------------------
__global__ __launch_bounds__(256) void attn_v2(
    const u16* __restrict__ Q, const u16* __restrict__ Kb,
    const u16* __restrict__ Vtb, const int* __restrict__ mask,
    u16* __restrict__ Out)
{
  __shared__ u16 ldsP[64 * 136];

  const int tid = threadIdx.x, lane = tid & 63, w = tid >> 6;
  const int qb = blockIdx.x, bh = blockIdx.y;
  const int b = bh >> 4, h = bh & 15;
  const int fr = lane & 15, g = lane >> 4, fo = g * 8;

  const size_t qrow = (size_t)(b * 2048 + qb * 64 + w * 16 + fr) * 1024 + h * 64;
  bf16x8 qf0 = *(const bf16x8*)&Q[qrow + fo];
  bf16x8 qf1 = *(const bf16x8*)&Q[qrow + 32 + fo];

  float madd[7];
  #pragma unroll
  for (int t = 0; t < 7; t++) {
    int col = t * 16 + fr;
    int mv = (col < 100) ? mask[b * 100 + col] : 0;
    madd[t] = mv ? 0.f : -1e30f;
  }

  float sc[7][4];
  #pragma unroll
  for (int t = 0; t < 7; t++) {
    int col = t * 16 + fr;
    int jr = (col < 100) ? col : 99;
    const u16* kp = Kb + (size_t)(b * 100 + jr) * 1024 + h * 64;
    bf16x8 kf0 = *(const bf16x8*)&kp[fo];
    bf16x8 kf1 = *(const bf16x8*)&kp[32 + fo];
    f32x4 a = {};
    a = mfma_16x16x32(qf0, kf0, a);
    a = mfma_16x16x32(qf1, kf1, a);
    #pragma unroll
    for (int r = 0; r < 4; r++)
      sc[t][r] = a[r] * 0.125f + madd[t];
  }

  #pragma unroll
  for (int r = 0; r < 4; r++) {
    float m = sc[0][r];
    #pragma unroll
    for (int t = 1; t < 7; t++) m = fmaxf(m, sc[t][r]);
    #pragma unroll
    for (int d = 8; d >= 1; d >>= 1) m = fmaxf(m, __shfl_xor(m, d));
    float ssum = 0.f;
    #pragma unroll
    for (int t = 0; t < 7; t++) { float p = __expf(sc[t][r] - m); sc[t][r] = p; ssum += p; }
    #pragma unroll
    for (int d = 8; d >= 1; d >>= 1) ssum += __shfl_xor(ssum, d);
    float is = 1.f / ssum;
    #pragma unroll
    for (int t = 0; t < 7; t++)
      ldsP[(w * 16 + g * 4 + r) * 136 + t * 16 + fr] = f2bf(sc[t][r] * is);
  }
  {
    u16* zp = &ldsP[(w * 16 + fr) * 136 + 112 + g * 6];
    #pragma unroll
    for (int i = 0; i < 6; i++) zp[i] = 0;
  }

  bf16x8 pa[4];
  #pragma unroll
  for (int kk = 0; kk < 4; kk++)
    pa[kk] = *(const bf16x8*)&ldsP[(w * 16 + fr) * 136 + kk * 32 + fo];
  const u16* vtbase = Vtb + (size_t)bh * 64 * 128;
  #pragma unroll
  for (int nt = 0; nt < 4; nt++) {
    f32x4 a = {};
    #pragma unroll
    for (int kk = 0; kk < 4; kk++) {
      bf16x8 vf = *(const bf16x8*)&vtbase[(size_t)(nt * 16 + fr) * 128 + kk * 32 + fo];
      a = mfma_16x16x32(pa[kk], vf, a);
    }
    #pragma unroll
    for (int r = 0; r < 4; r++) {
      size_t orow = (size_t)(b * 2048 + qb * 64 + w * 16 + g * 4 + r) * 1024 + h * 64 + nt * 16 + fr;
      Out[orow] = f2bf(a[r]);
    }
  }
}

// ---------------------------------------------------------------------------
extern "C" void kernel_launch(void* const* d_in, const int* in_sizes, int n_in,
                              void* d_out, int out_size, void* d_ws, size_t ws_size,
                              hipStream_t stream) {
  const float* video = (const float*)d_in[0];
  const float* text  = (const float*)d_in[1];
  const int*   text_mask = (const int*)d_in[2];
  const float* Wq_w = (const float*)d_in[3];
  const float* Wq_b = (const float*)d_in[4];
  const float* Wk_w = (const float*)d_in[5];
  const float* Wk_b = (const float*)d_in[6];
  const float* Wv_w = (const float*)d_in[7];
  const float* Wv_b = (const float*)d_in[8];
  const float* Wo_w = (const float*)d_in[9];
  const float* Wo_b = (const float*)d_in[10];
  const float* fc1_w = (const float*)d_in[11];
  const float* fc1_b = (const float*)d_in[12];
  const float* fc2_w = (const float*)d_in[13];
  const float* fc2_b = (const float*)d_in[14];
  const float* n2_g = (const float*)d_in[15];
  const float* n2_b = (const float*)d_in[16];
  const float* n3_g = (const float*)d_in[17];
  const float* n3_b = (const float*)d_in[18];

  char* ws = (char*)d_ws;
  size_t off = 0;
  auto alloc = [&](size_t bytes) {
    char* p = ws + off;
    off += (bytes + 255) & ~(size_t)255;
    return p;
  };
  u16* vbf = (u16*)alloc((size_t)8192 * 1024 * 2);     // 16 MB residual (bf16)
  u16* tbf = (u16*)alloc((size_t)400 * 512 * 2);
  u16* wqT = (u16*)alloc((size_t)1024 * 1024 * 2);
  u16* wkT = (u16*)alloc((size_t)1024 * 512 * 2);
  u16* wvT = (u16*)alloc((size_t)1024 * 512 * 2);
  u16* woT = (u16*)alloc((size_t)1024 * 1024 * 2);
  u16* f1T = (u16*)alloc((size_t)4096 * 1024 * 2);
  u16* f2T = (u16*)alloc((size_t)1024 * 4096 * 2);
  char* S = alloc((size_t)35192832);                   // union scratch
  u16* qbf  = (u16*)S;
  u16* kbf  = (u16*)(S + 16777216);
  u16* abf  = (u16*)(S + 16777216 + 1638400);
  u16* h1c  = (u16*)S;
  u16* vtb  = (u16*)alloc((size_t)64 * 64 * 128 * 2);  // 2 MB V^T (not aliased)
  u16* dbf  = (u16*)alloc((size_t)8192 * 1024 * 2);
  float* fout = (float*)d_out;

  hipMemsetAsync(vtb, 0, (size_t)64 * 64 * 128 * 2, stream);

  pe_video_k<<<8192, 256, 0, stream>>>(video, vbf);
  pe_text_k<<<400, 128, 0, stream>>>(text, tbf);

  dim3 tb(32, 8, 1);
  for (int l = 0; l < 4; ++l) {
    wconv_t<<<dim3(32, 32), tb, 0, stream>>>(Wq_w + (size_t)l * 1024 * 1024, wqT, 1024, 1024);
    wconv_t<<<dim3(32, 16), tb, 0, stream>>>(Wk_w + (size_t)l * 512 * 1024, wkT, 512, 1024);
    wconv_t<<<dim3(32, 16), tb, 0, stream>>>(Wv_w + (size_t)l * 512 * 1024, wvT, 512, 1024);
    wconv_t<<<dim3(32, 32), tb, 0, stream>>>(Wo_w + (size_t)l * 1024 * 1024, woT, 1024, 1024);
    wconv_t<<<dim3(128, 32), tb, 0, stream>>>(fc1_w + (size_t)l * 1024 * 4096, f1T, 1024, 4096);
    wconv_t<<<dim3(32, 128), tb, 0, stream>>>(fc2_w + (size_t)l * 4096 * 1024, f2T, 4096, 1024);

    gemm8p<true, false, false><<<dim3(32, 8), 512, 0, stream>>>(
        vbf, 1024, wqT, 1024, Wq_b + l * 1024, qbf, 1024, 8192, 1024, 1024);
    gemm_bt<false><<<dim3(4, 8), 256, 0, stream>>>(
        tbf, 512, wkT, 512, Wk_b + l * 1024, kbf, 1024, 400, 1024, 512);
    gemm_bt<true><<<dim3(4, 8), 256, 0, stream>>>(
        tbf, 512, wvT, 512, Wv_b + l * 1024, vtb, 1024, 400, 1024, 512);
    attn_v2<<<dim3(32, 64), 256, 0, stream>>>(qbf, kbf, vtb, text_mask, abf);
    gemm8p<true, false, false><<<dim3(32, 8), 512, 0, stream>>>(
        abf, 1024, woT, 1024, Wo_b + l * 1024, dbf, 1024, 8192, 1024, 1024);
    ln2<false><<<8192, 256, 0, stream>>>(vbf, dbf, n2_g + l * 1024, n2_b + l * 1024, vbf, nullptr);

    for (int c = 0; c < 2; ++c) {
      // FF1 chunk: true 256x256 8-phase kernel, grid 32x8 = 256 = 1 block/CU
      gemm256<true, true><<<dim3(32, 8), 512, 0, stream>>>(
          vbf, 1024, f1T + (size_t)c * 2048 * 1024, 1024,
          fc1_b + l * 4096 + c * 2048, h1c, 2048, 8192, 2048, 1024);
      if (c == 0)
        gemm8p<true, false, false><<<dim3(32, 8), 512, 0, stream>>>(
            h1c, 2048, f2T + (size_t)c * 2048, 4096,
            fc2_b + l * 1024, dbf, 1024, 8192, 1024, 2048);
      else
        gemm8p<true, false, true><<<dim3(32, 8), 512, 0, stream>>>(
            h1c, 2048, f2T + (size_t)c * 2048, 4096,
            nullptr, dbf, 1024, 8192, 1024, 2048);
    }
    if (l == 3)
      ln2<true><<<8192, 256, 0, stream>>>(vbf, dbf, n3_g + l * 1024, n3_b + l * 1024, nullptr, fout);
    else
      ln2<false><<<8192, 256, 0, stream>>>(vbf, dbf, n3_g + l * 1024, n3_b + l * 1024, vbf, nullptr);
  }
}

// Round 11
// 1307.183 us; speedup vs baseline: 1.0682x; 1.0183x over previous
//
#include <hip/hip_runtime.h>
#include <cstdint>
#include <cstddef>

typedef unsigned short u16;
typedef __attribute__((ext_vector_type(8))) __bf16 bf16x8;
typedef __attribute__((ext_vector_type(4))) float f32x4;

__device__ __forceinline__ f32x4 mfma_16x16x32(bf16x8 a, bf16x8 b, f32x4 c) {
  return __builtin_amdgcn_mfma_f32_16x16x32_bf16(a, b, c, 0, 0, 0);
}

__device__ __forceinline__ u16 f2bf(float f) {
  union { float f; uint32_t u; } c; c.f = f;
  uint32_t u = c.u + 0x7FFFu + ((c.u >> 16) & 1u);
  return (u16)(u >> 16);
}

__device__ __forceinline__ float bf2f(u16 x) {
  union { uint32_t u; float f; } c; c.u = ((uint32_t)x) << 16;
  return c.f;
}

__device__ __forceinline__ void gload_lds16(const void* g, void* l) {
  __builtin_amdgcn_global_load_lds(
      (__attribute__((address_space(1))) void*)(uintptr_t)g,
      (__attribute__((address_space(3))) void*)l, 16, 0, 0);
}

// ===========================================================================
// Ring GEMM (round-5 exact revert — best measured: FF2 49.5us, total 1314).
// MR=8: BM=256, MR=4: BM=128. BN=256. 512 threads = 8 waves (2x4).
// BK=32/step; 4-slot LDS ring; prefetch dist 3; counted vmcnt; ONE barrier
// per K-step (WAR closed by lgkmcnt(0) before it, RAW by counted vmcnt).
// Swizzle sigma(r)=(r>>1)&3 on 16B granules: consecutive 8 lanes hit 8
// distinct bank granules. Applied to BOTH the pre-swizzled global source of
// global_load_lds and the ds_read offset (verified conflict-free r5-r10).
// ===========================================================================
template<int MR, bool OUT_BF16, bool RELU, bool ACC>
__global__ __launch_bounds__(512, 2) void gemm_ring(
    const u16* __restrict__ A, int lda, const u16* __restrict__ Bt, int ldb,
    const float* __restrict__ bias, void* Cout, int ldc,
    int M, int N, int K)
{
  constexpr int BM = MR * 32;
  constexpr int SLOT = (BM + 256) * 32;
  __shared__ u16 ring[4 * SLOT];

  const int tid = threadIdx.x;
  const int lane = tid & 63, wave = tid >> 6;
  const int wm = wave >> 2, wn = wave & 3;
  const int m0 = blockIdx.x * BM, n0 = blockIdx.y * 256;

  const int cA0 = tid, rA0 = cA0 >> 2;
  const u16* gA0 = A + (size_t)(m0 + rA0) * lda + (((cA0 & 3) ^ ((rA0 >> 1) & 3)) * 8);
  const int cA1 = tid + 512, rA1 = cA1 >> 2;
  const u16* gA1 = A + (size_t)(m0 + (MR == 8 ? rA1 : 0)) * lda + (((cA1 & 3) ^ ((rA1 >> 1) & 3)) * 8);
  const int cB0 = tid, rB0 = cB0 >> 2;
  const int cB1 = tid + 512, rB1 = cB1 >> 2;
  const u16* gB0 = Bt + (size_t)(n0 + rB0) * ldb + (((cB0 & 3) ^ ((rB0 >> 1) & 3)) * 8);
  const u16* gB1 = Bt + (size_t)(n0 + rB1) * ldb + (((cB1 & 3) ^ ((rB1 >> 1) & 3)) * 8);

  const int NK = K >> 5;

  auto STAGE = [&](int s) {
    u16* Sb = &ring[(s & 3) * SLOT];
    const int ko = s * 32;
    gload_lds16(gA0 + ko, Sb + cA0 * 8);
    if constexpr (MR == 8) gload_lds16(gA1 + ko, Sb + cA1 * 8);
    gload_lds16(gB0 + ko, Sb + BM * 32 + cB0 * 8);
    gload_lds16(gB1 + ko, Sb + BM * 32 + cB1 * 8);
  };
  auto WAITV = [&](int ahead) {
    if (ahead >= 2) {
      if constexpr (MR == 8) asm volatile("s_waitcnt vmcnt(8)" ::: "memory");
      else                   asm volatile("s_waitcnt vmcnt(6)" ::: "memory");
    } else if (ahead == 1) {
      if constexpr (MR == 8) asm volatile("s_waitcnt vmcnt(4)" ::: "memory");
      else                   asm volatile("s_waitcnt vmcnt(3)" ::: "memory");
    } else {
      asm volatile("s_waitcnt vmcnt(0)" ::: "memory");
    }
  };

  const int fr = lane & 15, g = lane >> 4;
  const int foff = fr * 32 + ((g ^ ((fr >> 1) & 3)) * 8);

  f32x4 acc[MR][4];
  #pragma unroll
  for (int m = 0; m < MR; m++)
    #pragma unroll
    for (int n = 0; n < 4; n++) acc[m][n] = f32x4{0.f, 0.f, 0.f, 0.f};

  for (int i = 0; i < 3 && i < NK; ++i) STAGE(i);
  WAITV(NK - 1 < 2 ? NK - 1 : 2);
  __builtin_amdgcn_s_barrier();
  __builtin_amdgcn_sched_barrier(0);

  for (int s = 0; s < NK; ++s) {
    const u16* As = &ring[(s & 3) * SLOT];
    const u16* Bs = As + BM * 32;

    bf16x8 bf[4];
    #pragma unroll
    for (int n = 0; n < 4; n++)
      bf[n] = *(const bf16x8*)(Bs + (wn * 64 + n * 16) * 32 + foff);
    bf16x8 af[4];
    #pragma unroll
    for (int m = 0; m < 4; m++)
      af[m] = *(const bf16x8*)(As + (wm * (MR * 16) + m * 16) * 32 + foff);

    if (s + 3 < NK) STAGE(s + 3);

    __builtin_amdgcn_s_setprio(1);
    #pragma unroll
    for (int m = 0; m < 4; m++)
      #pragma unroll
      for (int n = 0; n < 4; n++)
        acc[m][n] = mfma_16x16x32(af[m], bf[n], acc[m][n]);
    __builtin_amdgcn_s_setprio(0);

    if constexpr (MR == 8) {
      bf16x8 af2[4];
      #pragma unroll
      for (int m = 0; m < 4; m++)
        af2[m] = *(const bf16x8*)(As + (wm * 128 + (m + 4) * 16) * 32 + foff);
      __builtin_amdgcn_s_setprio(1);
      #pragma unroll
      for (int m = 0; m < 4; m++)
        #pragma unroll
        for (int n = 0; n < 4; n++)
          acc[m + 4][n] = mfma_16x16x32(af2[m], bf[n], acc[m + 4][n]);
      __builtin_amdgcn_s_setprio(0);
    }

    {
      int im = (s + 3 < NK - 1) ? s + 3 : NK - 1;
      WAITV(im - (s + 1));
    }
    asm volatile("s_waitcnt lgkmcnt(0)" ::: "memory");
    __builtin_amdgcn_sched_barrier(0);
    __builtin_amdgcn_s_barrier();
    __builtin_amdgcn_sched_barrier(0);
  }

  #pragma unroll
  for (int n = 0; n < 4; n++) {
    const int gcol = n0 + wn * 64 + n * 16 + fr;
    const float bv = bias ? bias[gcol] : 0.f;
    #pragma unroll
    for (int m = 0; m < MR; m++) {
      #pragma unroll
      for (int r = 0; r < 4; r++) {
        const int grow = m0 + wm * (MR * 16) + m * 16 + g * 4 + r;
        float v = acc[m][n][r] + bv;
        if (ACC) v += bf2f(((const u16*)Cout)[(size_t)grow * ldc + gcol]);
        if (RELU) v = fmaxf(v, 0.f);
        if (OUT_BF16) ((u16*)Cout)[(size_t)grow * ldc + gcol] = f2bf(v);
        else         ((float*)Cout)[(size_t)grow * ldc + gcol] = v;
      }
    }
  }
}

// ---------------------------------------------------------------------------
// Small GEMM (M=400 K/V projections): 128x128 tile, BK=32.
// TRANS=true: store C transposed into vtb[((b*16+h)*64+d)*128 + j]
// ---------------------------------------------------------------------------
template<bool TRANS>
__global__ __launch_bounds__(256, 2) void gemm_bt(
    const u16* __restrict__ A, int lda, const u16* __restrict__ Bt, int ldb,
    const float* __restrict__ bias, u16* Cout, int ldc,
    int M, int N, int K)
{
  __shared__ u16 ldsA[128 * 32];
  __shared__ u16 ldsB[128 * 32];

  const int tid = threadIdx.x;
  const int lane = tid & 63, wave = tid >> 6;
  const int wr = wave >> 1, wc = wave & 1;
  const int m0 = blockIdx.x * 128, n0 = blockIdx.y * 128;

  const int c0 = tid, c1 = tid + 256;
  const int ar0 = c0 >> 2, ak0 = (c0 & 3) * 8;
  const int ar1 = c1 >> 2, ak1 = (c1 & 3) * 8;

  const bool av0 = (m0 + ar0) < M;
  const bool av1 = (m0 + ar1) < M;
  const u16* Ag0 = A + (size_t)(m0 + ar0) * lda + ak0;
  const u16* Ag1 = A + (size_t)(m0 + ar1) * lda + ak1;
  const u16* Bg0 = Bt + (size_t)(n0 + ar0) * ldb + ak0;
  const u16* Bg1 = Bt + (size_t)(n0 + ar1) * ldb + ak1;

  f32x4 acc[4][4] = {};
  const int fr = lane & 15, fo = (lane >> 4) * 8;

  for (int k0 = 0; k0 < K; k0 += 32) {
    if (av0) gload_lds16(Ag0 + k0, &ldsA[c0 * 8]);
    if (av1) gload_lds16(Ag1 + k0, &ldsA[c1 * 8]);
    gload_lds16(Bg0 + k0, &ldsB[c0 * 8]);
    gload_lds16(Bg1 + k0, &ldsB[c1 * 8]);
    asm volatile("s_waitcnt vmcnt(0)" ::: "memory");
    __syncthreads();

    bf16x8 af[4], bfr[4];
    #pragma unroll
    for (int m = 0; m < 4; m++)
      af[m] = *(const bf16x8*)&ldsA[(wr * 64 + m * 16 + fr) * 32 + fo];
    #pragma unroll
    for (int n = 0; n < 4; n++)
      bfr[n] = *(const bf16x8*)&ldsB[(wc * 64 + n * 16 + fr) * 32 + fo];
    #pragma unroll
    for (int m = 0; m < 4; m++)
      #pragma unroll
      for (int n = 0; n < 4; n++)
        acc[m][n] = mfma_16x16x32(af[m], bfr[n], acc[m][n]);
    __syncthreads();
  }

  const int g = lane >> 4;
  #pragma unroll
  for (int m = 0; m < 4; m++) {
    #pragma unroll
    for (int n = 0; n < 4; n++) {
      const int gcol = n0 + wc * 64 + n * 16 + fr;
      const float bv = bias[gcol];
      #pragma unroll
      for (int r = 0; r < 4; r++) {
        const int grow = m0 + wr * 64 + m * 16 + g * 4 + r;
        if (grow < M) {
          float v = acc[m][n][r] + bv;
          if (TRANS) {
            int bb = grow / 100, jj = grow - bb * 100;
            int h = gcol >> 6, d = gcol & 63;
            Cout[(size_t)(((bb * 16 + h) * 64 + d)) * 128 + jj] = f2bf(v);
          } else {
            Cout[(size_t)grow * ldc + gcol] = f2bf(v);
          }
        }
      }
    }
  }
}

// ---------------------------------------------------------------------------
// Weight transpose+convert v2: src f32 [K][N] -> dst bf16 [N][K]
// 64(k) x 32(n) tile; f32 loads 128B/row coalesced; packed u32 (2xbf16)
// writes 128B/row fully coalesced (old version wrote 64B/wave scattered u16).
// tile padded to 33 -> column reads are 2-way bank aliases (free, m136).
// ---------------------------------------------------------------------------
__global__ __launch_bounds__(256) void wconv2(const float* __restrict__ src,
                                              u16* __restrict__ dst,
                                              int K, int N)
{
  __shared__ float tile[64][33];
  const int n0 = blockIdx.x * 32, k0 = blockIdx.y * 64;
  const int tx = threadIdx.x & 31, ty = threadIdx.x >> 5;   // 32 x 8
  #pragma unroll
  for (int i = 0; i < 8; i++)
    tile[ty + i * 8][tx] = src[(size_t)(k0 + ty + i * 8) * N + n0 + tx];
  __syncthreads();
  #pragma unroll
  for (int j = 0; j < 4; j++) {
    int n = ty + j * 8;
    uint32_t lo = f2bf(tile[2 * tx][n]);
    uint32_t hi = f2bf(tile[2 * tx + 1][n]);
    *(uint32_t*)&dst[(size_t)(n0 + n) * K + k0 + 2 * tx] = lo | (hi << 16);
  }
}

// ---------------------------------------------------------------------------
// Positional encoding add -> bf16 only
// ---------------------------------------------------------------------------
__global__ __launch_bounds__(256) void pe_video_k(const float* __restrict__ video,
                                                  u16* __restrict__ vbf)
{
  const int r = blockIdx.x;
  const int s = r & 2047;
  const int d0 = threadIdx.x * 4;
  const size_t base = (size_t)r * 1024 + d0;
  float4 v = *(const float4*)&video[base];
  const float coef = -9.210340371976184f / 1024.f;
  float o[4];
  float in[4] = {v.x, v.y, v.z, v.w};
  #pragma unroll
  for (int i = 0; i < 4; i++) {
    int d = d0 + i;
    int j = d >> 1;
    float dv = expf((float)(2 * j) * coef);
    float arg = (float)s * dv;
    float pe = (d & 1) ? cosf(arg) : sinf(arg);
    o[i] = in[i] + pe;
  }
  uint2 pk;
  pk.x = (uint32_t)f2bf(o[0]) | ((uint32_t)f2bf(o[1]) << 16);
  pk.y = (uint32_t)f2bf(o[2]) | ((uint32_t)f2bf(o[3]) << 16);
  *(uint2*)&vbf[base] = pk;
}

__global__ __launch_bounds__(128) void pe_text_k(const float* __restrict__ text,
                                                 u16* __restrict__ tbf)
{
  const int r = blockIdx.x;
  const int s = r % 100;
  const int d0 = threadIdx.x * 4;
  const size_t base = (size_t)r * 512 + d0;
  float4 v = *(const float4*)&text[base];
  const float coef = -9.210340371976184f / 512.f;
  float o[4];
  float in[4] = {v.x, v.y, v.z, v.w};
  #pragma unroll
  for (int i = 0; i < 4; i++) {
    int d = d0 + i;
    int j = d >> 1;
    float dv = expf((float)(2 * j) * coef);
    float arg = (float)s * dv;
    float pe = (d & 1) ? cosf(arg) : sinf(arg);
    o[i] = in[i] + pe;
  }
  uint2 pk;
  pk.x = (uint32_t)f2bf(o[0]) | ((uint32_t)f2bf(o[1]) << 16);
  pk.y = (uint32_t)f2bf(o[2]) | ((uint32_t)f2bf(o[3]) << 16);
  *(uint2*)&tbf[base] = pk;
}

// ---------------------------------------------------------------------------
// LayerNorm, bf16 residual stream: x' = LN(x + delta)*g+b
// ---------------------------------------------------------------------------
template<bool LAST>
__global__ __launch_bounds__(256) void ln2(const u16* __restrict__ xin,
                                           const u16* __restrict__ delta,
                                           const float* __restrict__ gamma,
                                           const float* __restrict__ beta,
                                           u16* __restrict__ xbf,
                                           float* __restrict__ fout)
{
  const int row = blockIdx.x;
  const size_t base = (size_t)row * 1024;
  const int t = threadIdx.x;
  const int d0 = t * 4;
  uint2 xv = *(const uint2*)&xin[base + d0];
  uint2 dv = *(const uint2*)&delta[base + d0];
  float v0 = bf2f((u16)(xv.x & 0xFFFF)) + bf2f((u16)(dv.x & 0xFFFF));
  float v1 = bf2f((u16)(xv.x >> 16))    + bf2f((u16)(dv.x >> 16));
  float v2 = bf2f((u16)(xv.y & 0xFFFF)) + bf2f((u16)(dv.y & 0xFFFF));
  float v3 = bf2f((u16)(xv.y >> 16))    + bf2f((u16)(dv.y >> 16));
  float s = v0 + v1 + v2 + v3;
  float q = v0 * v0 + v1 * v1 + v2 * v2 + v3 * v3;
  #pragma unroll
  for (int d = 32; d >= 1; d >>= 1) { s += __shfl_xor(s, d); q += __shfl_xor(q, d); }
  __shared__ float red[8];
  const int lane = t & 63, w = t >> 6;
  if (lane == 0) { red[w] = s; red[4 + w] = q; }
  __syncthreads();
  float S = red[0] + red[1] + red[2] + red[3];
  float Qs = red[4] + red[5] + red[6] + red[7];
  const float mu = S * (1.f / 1024.f);
  const float var = Qs * (1.f / 1024.f) - mu * mu;
  const float rs = rsqrtf(var + 1e-5f);
  float4 gv = *(const float4*)&gamma[d0];
  float4 bv = *(const float4*)&beta[d0];
  float o0 = (v0 - mu) * rs * gv.x + bv.x;
  float o1 = (v1 - mu) * rs * gv.y + bv.y;
  float o2 = (v2 - mu) * rs * gv.z + bv.z;
  float o3 = (v3 - mu) * rs * gv.w + bv.w;
  if (LAST) {
    *(float4*)&fout[base + d0] = make_float4(o0, o1, o2, o3);
  } else {
    uint2 pk;
    pk.x = (uint32_t)f2bf(o0) | ((uint32_t)f2bf(o1) << 16);
    pk.y = (uint32_t)f2bf(o2) | ((uint32_t)f2bf(o3) << 16);
    *(uint2*)&xbf[base + d0] = pk;
  }
}

// ---------------------------------------------------------------------------
// Cross attention v2 (verified): K from global (L2), V pre-transposed,
// P via LDS intra-wave, zero barriers.
// ---------------------------------------------------------------------------
__global__ __launch_bounds__(256) void attn_v2(
    const u16* __restrict__ Q, const u16* __restrict__ Kb,
    const u16* __restrict__ Vtb, const int* __restrict__ mask,
    u16* __restrict__ Out)
{
  __shared__ u16 ldsP[64 * 136];

  const int tid = threadIdx.x, lane = tid & 63, w = tid >> 6;
  const int qb = blockIdx.x, bh = blockIdx.y;
  const int b = bh >> 4, h = bh & 15;
  const int fr = lane & 15, g = lane >> 4, fo = g * 8;

  const size_t qrow = (size_t)(b * 2048 + qb * 64 + w * 16 + fr) * 1024 + h * 64;
  bf16x8 qf0 = *(const bf16x8*)&Q[qrow + fo];
  bf16x8 qf1 = *(const bf16x8*)&Q[qrow + 32 + fo];

  float madd[7];
  #pragma unroll
  for (int t = 0; t < 7; t++) {
    int col = t * 16 + fr;
    int mv = (col < 100) ? mask[b * 100 + col] : 0;
    madd[t] = mv ? 0.f : -1e30f;
  }

  float sc[7][4];
  #pragma unroll
  for (int t = 0; t < 7; t++) {
    int col = t * 16 + fr;
    int jr = (col < 100) ? col : 99;
    const u16* kp = Kb + (size_t)(b * 100 + jr) * 1024 + h * 64;
    bf16x8 kf0 = *(const bf16x8*)&kp[fo];
    bf16x8 kf1 = *(const bf16x8*)&kp[32 + fo];
    f32x4 a = {};
    a = mfma_16x16x32(qf0, kf0, a);
    a = mfma_16x16x32(qf1, kf1, a);
    #pragma unroll
    for (int r = 0; r < 4; r++)
      sc[t][r] = a[r] * 0.125f + madd[t];
  }

  #pragma unroll
  for (int r = 0; r < 4; r++) {
    float m = sc[0][r];
    #pragma unroll
    for (int t = 1; t < 7; t++) m = fmaxf(m, sc[t][r]);
    #pragma unroll
    for (int d = 8; d >= 1; d >>= 1) m = fmaxf(m, __shfl_xor(m, d));
    float ssum = 0.f;
    #pragma unroll
    for (int t = 0; t < 7; t++) { float p = __expf(sc[t][r] - m); sc[t][r] = p; ssum += p; }
    #pragma unroll
    for (int d = 8; d >= 1; d >>= 1) ssum += __shfl_xor(ssum, d);
    float is = 1.f / ssum;
    #pragma unroll
    for (int t = 0; t < 7; t++)
      ldsP[(w * 16 + g * 4 + r) * 136 + t * 16 + fr] = f2bf(sc[t][r] * is);
  }
  {
    u16* zp = &ldsP[(w * 16 + fr) * 136 + 112 + g * 6];
    #pragma unroll
    for (int i = 0; i < 6; i++) zp[i] = 0;
  }

  bf16x8 pa[4];
  #pragma unroll
  for (int kk = 0; kk < 4; kk++)
    pa[kk] = *(const bf16x8*)&ldsP[(w * 16 + fr) * 136 + kk * 32 + fo];
  const u16* vtbase = Vtb + (size_t)bh * 64 * 128;
  #pragma unroll
  for (int nt = 0; nt < 4; nt++) {
    f32x4 a = {};
    #pragma unroll
    for (int kk = 0; kk < 4; kk++) {
      bf16x8 vf = *(const bf16x8*)&vtbase[(size_t)(nt * 16 + fr) * 128 + kk * 32 + fo];
      a = mfma_16x16x32(pa[kk], vf, a);
    }
    #pragma unroll
    for (int r = 0; r < 4; r++) {
      size_t orow = (size_t)(b * 2048 + qb * 64 + w * 16 + g * 4 + r) * 1024 + h * 64 + nt * 16 + fr;
      Out[orow] = f2bf(a[r]);
    }
  }
}

// ---------------------------------------------------------------------------
extern "C" void kernel_launch(void* const* d_in, const int* in_sizes, int n_in,
                              void* d_out, int out_size, void* d_ws, size_t ws_size,
                              hipStream_t stream) {
  const float* video = (const float*)d_in[0];
  const float* text  = (const float*)d_in[1];
  const int*   text_mask = (const int*)d_in[2];
  const float* Wq_w = (const float*)d_in[3];
  const float* Wq_b = (const float*)d_in[4];
  const float* Wk_w = (const float*)d_in[5];
  const float* Wk_b = (const float*)d_in[6];
  const float* Wv_w = (const float*)d_in[7];
  const float* Wv_b = (const float*)d_in[8];
  const float* Wo_w = (const float*)d_in[9];
  const float* Wo_b = (const float*)d_in[10];
  const float* fc1_w = (const float*)d_in[11];
  const float* fc1_b = (const float*)d_in[12];
  const float* fc2_w = (const float*)d_in[13];
  const float* fc2_b = (const float*)d_in[14];
  const float* n2_g = (const float*)d_in[15];
  const float* n2_b = (const float*)d_in[16];
  const float* n3_g = (const float*)d_in[17];
  const float* n3_b = (const float*)d_in[18];

  char* ws = (char*)d_ws;
  size_t off = 0;
  auto alloc = [&](size_t bytes) {
    char* p = ws + off;
    off += (bytes + 255) & ~(size_t)255;
    return p;
  };
  u16* vbf = (u16*)alloc((size_t)8192 * 1024 * 2);     // 16 MB residual (bf16)
  u16* tbf = (u16*)alloc((size_t)400 * 512 * 2);
  u16* wqT = (u16*)alloc((size_t)1024 * 1024 * 2);
  u16* wkT = (u16*)alloc((size_t)1024 * 512 * 2);
  u16* wvT = (u16*)alloc((size_t)1024 * 512 * 2);
  u16* woT = (u16*)alloc((size_t)1024 * 1024 * 2);
  u16* f1T = (u16*)alloc((size_t)4096 * 1024 * 2);
  u16* f2T = (u16*)alloc((size_t)1024 * 4096 * 2);
  char* S = alloc((size_t)35192832);                   // union scratch
  u16* qbf  = (u16*)S;
  u16* kbf  = (u16*)(S + 16777216);
  u16* abf  = (u16*)(S + 16777216 + 1638400);
  u16* h1c  = (u16*)S;
  u16* vtb  = (u16*)alloc((size_t)64 * 64 * 128 * 2);  // 2 MB V^T (not aliased)
  u16* dbf  = (u16*)alloc((size_t)8192 * 1024 * 2);
  float* fout = (float*)d_out;

  hipMemsetAsync(vtb, 0, (size_t)64 * 64 * 128 * 2, stream);

  pe_video_k<<<8192, 256, 0, stream>>>(video, vbf);
  pe_text_k<<<400, 128, 0, stream>>>(text, tbf);

  for (int l = 0; l < 4; ++l) {
    wconv2<<<dim3(32, 16), 256, 0, stream>>>(Wq_w + (size_t)l * 1024 * 1024, wqT, 1024, 1024);
    wconv2<<<dim3(32, 8), 256, 0, stream>>>(Wk_w + (size_t)l * 512 * 1024, wkT, 512, 1024);
    wconv2<<<dim3(32, 8), 256, 0, stream>>>(Wv_w + (size_t)l * 512 * 1024, wvT, 512, 1024);
    wconv2<<<dim3(32, 16), 256, 0, stream>>>(Wo_w + (size_t)l * 1024 * 1024, woT, 1024, 1024);
    wconv2<<<dim3(128, 16), 256, 0, stream>>>(fc1_w + (size_t)l * 1024 * 4096, f1T, 1024, 4096);
    wconv2<<<dim3(32, 64), 256, 0, stream>>>(fc2_w + (size_t)l * 4096 * 1024, f2T, 4096, 1024);

    gemm_ring<4, true, false, false><<<dim3(64, 4), 512, 0, stream>>>(
        vbf, 1024, wqT, 1024, Wq_b + l * 1024, qbf, 1024, 8192, 1024, 1024);
    gemm_bt<false><<<dim3(4, 8), 256, 0, stream>>>(
        tbf, 512, wkT, 512, Wk_b + l * 1024, kbf, 1024, 400, 1024, 512);
    gemm_bt<true><<<dim3(4, 8), 256, 0, stream>>>(
        tbf, 512, wvT, 512, Wv_b + l * 1024, vtb, 1024, 400, 1024, 512);
    attn_v2<<<dim3(32, 64), 256, 0, stream>>>(qbf, kbf, vtb, text_mask, abf);
    gemm_ring<4, true, false, false><<<dim3(64, 4), 512, 0, stream>>>(
        abf, 1024, woT, 1024, Wo_b + l * 1024, dbf, 1024, 8192, 1024, 1024);
    ln2<false><<<8192, 256, 0, stream>>>(vbf, dbf, n2_g + l * 1024, n2_b + l * 1024, vbf, nullptr);

    for (int c = 0; c < 2; ++c) {
      gemm_ring<8, true, true, false><<<dim3(32, 8), 512, 0, stream>>>(
          vbf, 1024, f1T + (size_t)c * 2048 * 1024, 1024,
          fc1_b + l * 4096 + c * 2048, h1c, 2048, 8192, 2048, 1024);
      if (c == 0)
        gemm_ring<4, true, false, false><<<dim3(64, 4), 512, 0, stream>>>(
            h1c, 2048, f2T + (size_t)c * 2048, 4096,
            fc2_b + l * 1024, dbf, 1024, 8192, 1024, 2048);
      else
        gemm_ring<4, true, false, true><<<dim3(64, 4), 512, 0, stream>>>(
            h1c, 2048, f2T + (size_t)c * 2048, 4096,
            nullptr, dbf, 1024, 8192, 1024, 2048);
    }
    if (l == 3)
      ln2<true><<<8192, 256, 0, stream>>>(vbf, dbf, n3_g + l * 1024, n3_b + l * 1024, nullptr, fout);
    else
      ln2<false><<<8192, 256, 0, stream>>>(vbf, dbf, n3_g + l * 1024, n3_b + l * 1024, vbf, nullptr);
  }
}

// Round 12
// 1259.430 us; speedup vs baseline: 1.1087x; 1.0379x over previous
//
#include <hip/hip_runtime.h>
#include <cstdint>
#include <cstddef>

typedef unsigned short u16;
typedef __attribute__((ext_vector_type(8))) __bf16 bf16x8;
typedef __attribute__((ext_vector_type(4))) float f32x4;

__device__ __forceinline__ f32x4 mfma_16x16x32(bf16x8 a, bf16x8 b, f32x4 c) {
  return __builtin_amdgcn_mfma_f32_16x16x32_bf16(a, b, c, 0, 0, 0);
}

__device__ __forceinline__ u16 f2bf(float f) {
  union { float f; uint32_t u; } c; c.f = f;
  uint32_t u = c.u + 0x7FFFu + ((c.u >> 16) & 1u);
  return (u16)(u >> 16);
}

__device__ __forceinline__ float bf2f(u16 x) {
  union { uint32_t u; float f; } c; c.u = ((uint32_t)x) << 16;
  return c.f;
}

__device__ __forceinline__ void gload_lds16(const void* g, void* l) {
  __builtin_amdgcn_global_load_lds(
      (__attribute__((address_space(1))) void*)(uintptr_t)g,
      (__attribute__((address_space(3))) void*)l, 16, 0, 0);
}

// ===========================================================================
// Ring GEMM (round-5/11 best: FF2 ~50us, conflicts 0 — unchanged).
// MR=8: BM=256, MR=4: BM=128. BN=256. 512 threads = 8 waves (2x4).
// BK=32/step; 4-slot LDS ring; prefetch dist 3; counted vmcnt; ONE barrier
// per K-step. Swizzle sigma(r)=(r>>1)&3 on 16B granules on BOTH sides.
// ===========================================================================
template<int MR, bool OUT_BF16, bool RELU, bool ACC>
__global__ __launch_bounds__(512, 2) void gemm_ring(
    const u16* __restrict__ A, int lda, const u16* __restrict__ Bt, int ldb,
    const float* __restrict__ bias, void* Cout, int ldc,
    int M, int N, int K)
{
  constexpr int BM = MR * 32;
  constexpr int SLOT = (BM + 256) * 32;
  __shared__ u16 ring[4 * SLOT];

  const int tid = threadIdx.x;
  const int lane = tid & 63, wave = tid >> 6;
  const int wm = wave >> 2, wn = wave & 3;
  const int m0 = blockIdx.x * BM, n0 = blockIdx.y * 256;

  const int cA0 = tid, rA0 = cA0 >> 2;
  const u16* gA0 = A + (size_t)(m0 + rA0) * lda + (((cA0 & 3) ^ ((rA0 >> 1) & 3)) * 8);
  const int cA1 = tid + 512, rA1 = cA1 >> 2;
  const u16* gA1 = A + (size_t)(m0 + (MR == 8 ? rA1 : 0)) * lda + (((cA1 & 3) ^ ((rA1 >> 1) & 3)) * 8);
  const int cB0 = tid, rB0 = cB0 >> 2;
  const int cB1 = tid + 512, rB1 = cB1 >> 2;
  const u16* gB0 = Bt + (size_t)(n0 + rB0) * ldb + (((cB0 & 3) ^ ((rB0 >> 1) & 3)) * 8);
  const u16* gB1 = Bt + (size_t)(n0 + rB1) * ldb + (((cB1 & 3) ^ ((rB1 >> 1) & 3)) * 8);

  const int NK = K >> 5;

  auto STAGE = [&](int s) {
    u16* Sb = &ring[(s & 3) * SLOT];
    const int ko = s * 32;
    gload_lds16(gA0 + ko, Sb + cA0 * 8);
    if constexpr (MR == 8) gload_lds16(gA1 + ko, Sb + cA1 * 8);
    gload_lds16(gB0 + ko, Sb + BM * 32 + cB0 * 8);
    gload_lds16(gB1 + ko, Sb + BM * 32 + cB1 * 8);
  };
  auto WAITV = [&](int ahead) {
    if (ahead >= 2) {
      if constexpr (MR == 8) asm volatile("s_waitcnt vmcnt(8)" ::: "memory");
      else                   asm volatile("s_waitcnt vmcnt(6)" ::: "memory");
    } else if (ahead == 1) {
      if constexpr (MR == 8) asm volatile("s_waitcnt vmcnt(4)" ::: "memory");
      else                   asm volatile("s_waitcnt vmcnt(3)" ::: "memory");
    } else {
      asm volatile("s_waitcnt vmcnt(0)" ::: "memory");
    }
  };

  const int fr = lane & 15, g = lane >> 4;
  const int foff = fr * 32 + ((g ^ ((fr >> 1) & 3)) * 8);

  f32x4 acc[MR][4];
  #pragma unroll
  for (int m = 0; m < MR; m++)
    #pragma unroll
    for (int n = 0; n < 4; n++) acc[m][n] = f32x4{0.f, 0.f, 0.f, 0.f};

  for (int i = 0; i < 3 && i < NK; ++i) STAGE(i);
  WAITV(NK - 1 < 2 ? NK - 1 : 2);
  __builtin_amdgcn_s_barrier();
  __builtin_amdgcn_sched_barrier(0);

  for (int s = 0; s < NK; ++s) {
    const u16* As = &ring[(s & 3) * SLOT];
    const u16* Bs = As + BM * 32;

    bf16x8 bf[4];
    #pragma unroll
    for (int n = 0; n < 4; n++)
      bf[n] = *(const bf16x8*)(Bs + (wn * 64 + n * 16) * 32 + foff);
    bf16x8 af[4];
    #pragma unroll
    for (int m = 0; m < 4; m++)
      af[m] = *(const bf16x8*)(As + (wm * (MR * 16) + m * 16) * 32 + foff);

    if (s + 3 < NK) STAGE(s + 3);

    __builtin_amdgcn_s_setprio(1);
    #pragma unroll
    for (int m = 0; m < 4; m++)
      #pragma unroll
      for (int n = 0; n < 4; n++)
        acc[m][n] = mfma_16x16x32(af[m], bf[n], acc[m][n]);
    __builtin_amdgcn_s_setprio(0);

    if constexpr (MR == 8) {
      bf16x8 af2[4];
      #pragma unroll
      for (int m = 0; m < 4; m++)
        af2[m] = *(const bf16x8*)(As + (wm * 128 + (m + 4) * 16) * 32 + foff);
      __builtin_amdgcn_s_setprio(1);
      #pragma unroll
      for (int m = 0; m < 4; m++)
        #pragma unroll
        for (int n = 0; n < 4; n++)
          acc[m + 4][n] = mfma_16x16x32(af2[m], bf[n], acc[m + 4][n]);
      __builtin_amdgcn_s_setprio(0);
    }

    {
      int im = (s + 3 < NK - 1) ? s + 3 : NK - 1;
      WAITV(im - (s + 1));
    }
    asm volatile("s_waitcnt lgkmcnt(0)" ::: "memory");
    __builtin_amdgcn_sched_barrier(0);
    __builtin_amdgcn_s_barrier();
    __builtin_amdgcn_sched_barrier(0);
  }

  #pragma unroll
  for (int n = 0; n < 4; n++) {
    const int gcol = n0 + wn * 64 + n * 16 + fr;
    const float bv = bias ? bias[gcol] : 0.f;
    #pragma unroll
    for (int m = 0; m < MR; m++) {
      #pragma unroll
      for (int r = 0; r < 4; r++) {
        const int grow = m0 + wm * (MR * 16) + m * 16 + g * 4 + r;
        float v = acc[m][n][r] + bv;
        if (ACC) v += bf2f(((const u16*)Cout)[(size_t)grow * ldc + gcol]);
        if (RELU) v = fmaxf(v, 0.f);
        if (OUT_BF16) ((u16*)Cout)[(size_t)grow * ldc + gcol] = f2bf(v);
        else         ((float*)Cout)[(size_t)grow * ldc + gcol] = v;
      }
    }
  }
}

// ---------------------------------------------------------------------------
// Merged K+V projection GEMM: A=tbf [400x512], Bt = wkT||wvT [2048x512].
// gcol<1024 -> K proj -> kbf[grow*1024+gcol] (+biasK)
// gcol>=1024 -> V proj -> vtb transposed [((b*16+h)*64+d)*128 + j] (+biasV)
// grid (4,16), 128x128 tile, BK=32.
// ---------------------------------------------------------------------------
__global__ __launch_bounds__(256, 2) void gemm_kv(
    const u16* __restrict__ A, const u16* __restrict__ Bt,
    const float* __restrict__ biasK, const float* __restrict__ biasV,
    u16* __restrict__ kbf, u16* __restrict__ vtb, int M, int K)
{
  __shared__ u16 ldsA[128 * 32];
  __shared__ u16 ldsB[128 * 32];

  const int tid = threadIdx.x;
  const int lane = tid & 63, wave = tid >> 6;
  const int wr = wave >> 1, wc = wave & 1;
  const int m0 = blockIdx.x * 128, n0 = blockIdx.y * 128;

  const int c0 = tid, c1 = tid + 256;
  const int ar0 = c0 >> 2, ak0 = (c0 & 3) * 8;
  const int ar1 = c1 >> 2, ak1 = (c1 & 3) * 8;

  const bool av0 = (m0 + ar0) < M;
  const bool av1 = (m0 + ar1) < M;
  const u16* Ag0 = A + (size_t)(m0 + ar0) * K + ak0;
  const u16* Ag1 = A + (size_t)(m0 + ar1) * K + ak1;
  const u16* Bg0 = Bt + (size_t)(n0 + ar0) * K + ak0;
  const u16* Bg1 = Bt + (size_t)(n0 + ar1) * K + ak1;

  f32x4 acc[4][4] = {};
  const int fr = lane & 15, fo = (lane >> 4) * 8;

  for (int k0 = 0; k0 < K; k0 += 32) {
    if (av0) gload_lds16(Ag0 + k0, &ldsA[c0 * 8]);
    if (av1) gload_lds16(Ag1 + k0, &ldsA[c1 * 8]);
    gload_lds16(Bg0 + k0, &ldsB[c0 * 8]);
    gload_lds16(Bg1 + k0, &ldsB[c1 * 8]);
    asm volatile("s_waitcnt vmcnt(0)" ::: "memory");
    __syncthreads();

    bf16x8 af[4], bfr[4];
    #pragma unroll
    for (int m = 0; m < 4; m++)
      af[m] = *(const bf16x8*)&ldsA[(wr * 64 + m * 16 + fr) * 32 + fo];
    #pragma unroll
    for (int n = 0; n < 4; n++)
      bfr[n] = *(const bf16x8*)&ldsB[(wc * 64 + n * 16 + fr) * 32 + fo];
    #pragma unroll
    for (int m = 0; m < 4; m++)
      #pragma unroll
      for (int n = 0; n < 4; n++)
        acc[m][n] = mfma_16x16x32(af[m], bfr[n], acc[m][n]);
    __syncthreads();
  }

  const int g = lane >> 4;
  #pragma unroll
  for (int m = 0; m < 4; m++) {
    #pragma unroll
    for (int n = 0; n < 4; n++) {
      const int gcol = n0 + wc * 64 + n * 16 + fr;
      const bool isK = gcol < 1024;
      const int vc = isK ? gcol : gcol - 1024;
      const float bv = isK ? biasK[vc] : biasV[vc];
      #pragma unroll
      for (int r = 0; r < 4; r++) {
        const int grow = m0 + wr * 64 + m * 16 + g * 4 + r;
        if (grow < M) {
          float v = acc[m][n][r] + bv;
          if (isK) {
            kbf[(size_t)grow * 1024 + vc] = f2bf(v);
          } else {
            int bb = grow / 100, jj = grow - bb * 100;
            int h = vc >> 6, d = vc & 63;
            vtb[(size_t)(((bb * 16 + h) * 64 + d)) * 128 + jj] = f2bf(v);
          }
        }
      }
    }
  }
}

// ---------------------------------------------------------------------------
// Weight transpose+convert v2: src f32 [K][N] -> dst bf16 [N][K]
// ---------------------------------------------------------------------------
__global__ __launch_bounds__(256) void wconv2(const float* __restrict__ src,
                                              u16* __restrict__ dst,
                                              int K, int N)
{
  __shared__ float tile[64][33];
  const int n0 = blockIdx.x * 32, k0 = blockIdx.y * 64;
  const int tx = threadIdx.x & 31, ty = threadIdx.x >> 5;   // 32 x 8
  #pragma unroll
  for (int i = 0; i < 8; i++)
    tile[ty + i * 8][tx] = src[(size_t)(k0 + ty + i * 8) * N + n0 + tx];
  __syncthreads();
  #pragma unroll
  for (int j = 0; j < 4; j++) {
    int n = ty + j * 8;
    uint32_t lo = f2bf(tile[2 * tx][n]);
    uint32_t hi = f2bf(tile[2 * tx + 1][n]);
    *(uint32_t*)&dst[(size_t)(n0 + n) * K + k0 + 2 * tx] = lo | (hi << 16);
  }
}

// ---------------------------------------------------------------------------
// Positional encoding add -> bf16 only (fast-math trig; err ~1e-5 << bf16 ulp)
// ---------------------------------------------------------------------------
__global__ __launch_bounds__(256) void pe_video_k(const float* __restrict__ video,
                                                  u16* __restrict__ vbf)
{
  const int r = blockIdx.x;
  const int s = r & 2047;
  const int d0 = threadIdx.x * 4;
  const size_t base = (size_t)r * 1024 + d0;
  float4 v = *(const float4*)&video[base];
  const float coef = -9.210340371976184f / 1024.f;
  float o[4];
  float in[4] = {v.x, v.y, v.z, v.w};
  #pragma unroll
  for (int i = 0; i < 4; i++) {
    int d = d0 + i;
    int j = d >> 1;
    float dv = __expf((float)(2 * j) * coef);
    float arg = (float)s * dv;
    float pe = (d & 1) ? __cosf(arg) : __sinf(arg);
    o[i] = in[i] + pe;
  }
  uint2 pk;
  pk.x = (uint32_t)f2bf(o[0]) | ((uint32_t)f2bf(o[1]) << 16);
  pk.y = (uint32_t)f2bf(o[2]) | ((uint32_t)f2bf(o[3]) << 16);
  *(uint2*)&vbf[base] = pk;
}

__global__ __launch_bounds__(128) void pe_text_k(const float* __restrict__ text,
                                                 u16* __restrict__ tbf)
{
  const int r = blockIdx.x;
  const int s = r % 100;
  const int d0 = threadIdx.x * 4;
  const size_t base = (size_t)r * 512 + d0;
  float4 v = *(const float4*)&text[base];
  const float coef = -9.210340371976184f / 512.f;
  float o[4];
  float in[4] = {v.x, v.y, v.z, v.w};
  #pragma unroll
  for (int i = 0; i < 4; i++) {
    int d = d0 + i;
    int j = d >> 1;
    float dv = __expf((float)(2 * j) * coef);
    float arg = (float)s * dv;
    float pe = (d & 1) ? __cosf(arg) : __sinf(arg);
    o[i] = in[i] + pe;
  }
  uint2 pk;
  pk.x = (uint32_t)f2bf(o[0]) | ((uint32_t)f2bf(o[1]) << 16);
  pk.y = (uint32_t)f2bf(o[2]) | ((uint32_t)f2bf(o[3]) << 16);
  *(uint2*)&tbf[base] = pk;
}

// ---------------------------------------------------------------------------
// LayerNorm, bf16 residual stream: x' = LN(x + delta)*g+b
// ---------------------------------------------------------------------------
template<bool LAST>
__global__ __launch_bounds__(256) void ln2(const u16* __restrict__ xin,
                                           const u16* __restrict__ delta,
                                           const float* __restrict__ gamma,
                                           const float* __restrict__ beta,
                                           u16* __restrict__ xbf,
                                           float* __restrict__ fout)
{
  const int row = blockIdx.x;
  const size_t base = (size_t)row * 1024;
  const int t = threadIdx.x;
  const int d0 = t * 4;
  uint2 xv = *(const uint2*)&xin[base + d0];
  uint2 dv = *(const uint2*)&delta[base + d0];
  float v0 = bf2f((u16)(xv.x & 0xFFFF)) + bf2f((u16)(dv.x & 0xFFFF));
  float v1 = bf2f((u16)(xv.x >> 16))    + bf2f((u16)(dv.x >> 16));
  float v2 = bf2f((u16)(xv.y & 0xFFFF)) + bf2f((u16)(dv.y & 0xFFFF));
  float v3 = bf2f((u16)(xv.y >> 16))    + bf2f((u16)(dv.y >> 16));
  float s = v0 + v1 + v2 + v3;
  float q = v0 * v0 + v1 * v1 + v2 * v2 + v3 * v3;
  #pragma unroll
  for (int d = 32; d >= 1; d >>= 1) { s += __shfl_xor(s, d); q += __shfl_xor(q, d); }
  __shared__ float red[8];
  const int lane = t & 63, w = t >> 6;
  if (lane == 0) { red[w] = s; red[4 + w] = q; }
  __syncthreads();
  float S = red[0] + red[1] + red[2] + red[3];
  float Qs = red[4] + red[5] + red[6] + red[7];
  const float mu = S * (1.f / 1024.f);
  const float var = Qs * (1.f / 1024.f) - mu * mu;
  const float rs = rsqrtf(var + 1e-5f);
  float4 gv = *(const float4*)&gamma[d0];
  float4 bv = *(const float4*)&beta[d0];
  float o0 = (v0 - mu) * rs * gv.x + bv.x;
  float o1 = (v1 - mu) * rs * gv.y + bv.y;
  float o2 = (v2 - mu) * rs * gv.z + bv.z;
  float o3 = (v3 - mu) * rs * gv.w + bv.w;
  if (LAST) {
    *(float4*)&fout[base + d0] = make_float4(o0, o1, o2, o3);
  } else {
    uint2 pk;
    pk.x = (uint32_t)f2bf(o0) | ((uint32_t)f2bf(o1) << 16);
    pk.y = (uint32_t)f2bf(o2) | ((uint32_t)f2bf(o3) << 16);
    *(uint2*)&xbf[base + d0] = pk;
  }
}

// ---------------------------------------------------------------------------
// Cross attention v2 (verified): K from global (L2), V pre-transposed,
// P via LDS intra-wave, zero barriers.
// ---------------------------------------------------------------------------
__global__ __launch_bounds__(256) void attn_v2(
    const u16* __restrict__ Q, const u16* __restrict__ Kb,
    const u16* __restrict__ Vtb, const int* __restrict__ mask,
    u16* __restrict__ Out)
{
  __shared__ u16 ldsP[64 * 136];

  const int tid = threadIdx.x, lane = tid & 63, w = tid >> 6;
  const int qb = blockIdx.x, bh = blockIdx.y;
  const int b = bh >> 4, h = bh & 15;
  const int fr = lane & 15, g = lane >> 4, fo = g * 8;

  const size_t qrow = (size_t)(b * 2048 + qb * 64 + w * 16 + fr) * 1024 + h * 64;
  bf16x8 qf0 = *(const bf16x8*)&Q[qrow + fo];
  bf16x8 qf1 = *(const bf16x8*)&Q[qrow + 32 + fo];

  float madd[7];
  #pragma unroll
  for (int t = 0; t < 7; t++) {
    int col = t * 16 + fr;
    int mv = (col < 100) ? mask[b * 100 + col] : 0;
    madd[t] = mv ? 0.f : -1e30f;
  }

  float sc[7][4];
  #pragma unroll
  for (int t = 0; t < 7; t++) {
    int col = t * 16 + fr;
    int jr = (col < 100) ? col : 99;
    const u16* kp = Kb + (size_t)(b * 100 + jr) * 1024 + h * 64;
    bf16x8 kf0 = *(const bf16x8*)&kp[fo];
    bf16x8 kf1 = *(const bf16x8*)&kp[32 + fo];
    f32x4 a = {};
    a = mfma_16x16x32(qf0, kf0, a);
    a = mfma_16x16x32(qf1, kf1, a);
    #pragma unroll
    for (int r = 0; r < 4; r++)
      sc[t][r] = a[r] * 0.125f + madd[t];
  }

  #pragma unroll
  for (int r = 0; r < 4; r++) {
    float m = sc[0][r];
    #pragma unroll
    for (int t = 1; t < 7; t++) m = fmaxf(m, sc[t][r]);
    #pragma unroll
    for (int d = 8; d >= 1; d >>= 1) m = fmaxf(m, __shfl_xor(m, d));
    float ssum = 0.f;
    #pragma unroll
    for (int t = 0; t < 7; t++) { float p = __expf(sc[t][r] - m); sc[t][r] = p; ssum += p; }
    #pragma unroll
    for (int d = 8; d >= 1; d >>= 1) ssum += __shfl_xor(ssum, d);
    float is = 1.f / ssum;
    #pragma unroll
    for (int t = 0; t < 7; t++)
      ldsP[(w * 16 + g * 4 + r) * 136 + t * 16 + fr] = f2bf(sc[t][r] * is);
  }
  {
    u16* zp = &ldsP[(w * 16 + fr) * 136 + 112 + g * 6];
    #pragma unroll
    for (int i = 0; i < 6; i++) zp[i] = 0;
  }

  bf16x8 pa[4];
  #pragma unroll
  for (int kk = 0; kk < 4; kk++)
    pa[kk] = *(const bf16x8*)&ldsP[(w * 16 + fr) * 136 + kk * 32 + fo];
  const u16* vtbase = Vtb + (size_t)bh * 64 * 128;
  #pragma unroll
  for (int nt = 0; nt < 4; nt++) {
    f32x4 a = {};
    #pragma unroll
    for (int kk = 0; kk < 4; kk++) {
      bf16x8 vf = *(const bf16x8*)&vtbase[(size_t)(nt * 16 + fr) * 128 + kk * 32 + fo];
      a = mfma_16x16x32(pa[kk], vf, a);
    }
    #pragma unroll
    for (int r = 0; r < 4; r++) {
      size_t orow = (size_t)(b * 2048 + qb * 64 + w * 16 + g * 4 + r) * 1024 + h * 64 + nt * 16 + fr;
      Out[orow] = f2bf(a[r]);
    }
  }
}

// ---------------------------------------------------------------------------
extern "C" void kernel_launch(void* const* d_in, const int* in_sizes, int n_in,
                              void* d_out, int out_size, void* d_ws, size_t ws_size,
                              hipStream_t stream) {
  const float* video = (const float*)d_in[0];
  const float* text  = (const float*)d_in[1];
  const int*   text_mask = (const int*)d_in[2];
  const float* Wq_w = (const float*)d_in[3];
  const float* Wq_b = (const float*)d_in[4];
  const float* Wk_w = (const float*)d_in[5];
  const float* Wk_b = (const float*)d_in[6];
  const float* Wv_w = (const float*)d_in[7];
  const float* Wv_b = (const float*)d_in[8];
  const float* Wo_w = (const float*)d_in[9];
  const float* Wo_b = (const float*)d_in[10];
  const float* fc1_w = (const float*)d_in[11];
  const float* fc1_b = (const float*)d_in[12];
  const float* fc2_w = (const float*)d_in[13];
  const float* fc2_b = (const float*)d_in[14];
  const float* n2_g = (const float*)d_in[15];
  const float* n2_b = (const float*)d_in[16];
  const float* n3_g = (const float*)d_in[17];
  const float* n3_b = (const float*)d_in[18];

  char* ws = (char*)d_ws;
  size_t off = 0;
  auto alloc = [&](size_t bytes) {
    char* p = ws + off;
    off += (bytes + 255) & ~(size_t)255;
    return p;
  };
  u16* vbf = (u16*)alloc((size_t)8192 * 1024 * 2);     // 16 MB residual (bf16)
  u16* tbf = (u16*)alloc((size_t)400 * 512 * 2);
  u16* wqT = (u16*)alloc((size_t)1024 * 1024 * 2);
  u16* wkT = (u16*)alloc((size_t)1024 * 512 * 2);      // contiguous with wvT
  u16* wvT = (u16*)alloc((size_t)1024 * 512 * 2);
  u16* woT = (u16*)alloc((size_t)1024 * 1024 * 2);
  u16* f1T = (u16*)alloc((size_t)4096 * 1024 * 2);
  u16* f2T = (u16*)alloc((size_t)1024 * 4096 * 2);
  char* S = alloc((size_t)35192832);                   // union scratch
  u16* qbf  = (u16*)S;
  u16* kbf  = (u16*)(S + 16777216);
  u16* abf  = (u16*)(S + 16777216 + 1638400);
  u16* h1c  = (u16*)S;
  u16* vtb  = (u16*)alloc((size_t)64 * 64 * 128 * 2);  // 2 MB V^T (not aliased)
  u16* dbf  = (u16*)alloc((size_t)8192 * 1024 * 2);
  float* fout = (float*)d_out;

  hipMemsetAsync(vtb, 0, (size_t)64 * 64 * 128 * 2, stream);

  pe_video_k<<<8192, 256, 0, stream>>>(video, vbf);
  pe_text_k<<<400, 128, 0, stream>>>(text, tbf);

  for (int l = 0; l < 4; ++l) {
    wconv2<<<dim3(32, 16), 256, 0, stream>>>(Wq_w + (size_t)l * 1024 * 1024, wqT, 1024, 1024);
    wconv2<<<dim3(32, 8), 256, 0, stream>>>(Wk_w + (size_t)l * 512 * 1024, wkT, 512, 1024);
    wconv2<<<dim3(32, 8), 256, 0, stream>>>(Wv_w + (size_t)l * 512 * 1024, wvT, 512, 1024);
    wconv2<<<dim3(32, 16), 256, 0, stream>>>(Wo_w + (size_t)l * 1024 * 1024, woT, 1024, 1024);
    wconv2<<<dim3(128, 16), 256, 0, stream>>>(fc1_w + (size_t)l * 1024 * 4096, f1T, 1024, 4096);
    wconv2<<<dim3(32, 64), 256, 0, stream>>>(fc2_w + (size_t)l * 4096 * 1024, f2T, 4096, 1024);

    gemm_ring<4, true, false, false><<<dim3(64, 4), 512, 0, stream>>>(
        vbf, 1024, wqT, 1024, Wq_b + l * 1024, qbf, 1024, 8192, 1024, 1024);
    gemm_kv<<<dim3(4, 16), 256, 0, stream>>>(
        tbf, wkT, Wk_b + l * 1024, Wv_b + l * 1024, kbf, vtb, 400, 512);
    attn_v2<<<dim3(32, 64), 256, 0, stream>>>(qbf, kbf, vtb, text_mask, abf);
    gemm_ring<4, true, false, false><<<dim3(64, 4), 512, 0, stream>>>(
        abf, 1024, woT, 1024, Wo_b + l * 1024, dbf, 1024, 8192, 1024, 1024);
    ln2<false><<<8192, 256, 0, stream>>>(vbf, dbf, n2_g + l * 1024, n2_b + l * 1024, vbf, nullptr);

    for (int c = 0; c < 2; ++c) {
      gemm_ring<8, true, true, false><<<dim3(32, 8), 512, 0, stream>>>(
          vbf, 1024, f1T + (size_t)c * 2048 * 1024, 1024,
          fc1_b + l * 4096 + c * 2048, h1c, 2048, 8192, 2048, 1024);
      if (c == 0)
        gemm_ring<4, true, false, false><<<dim3(64, 4), 512, 0, stream>>>(
            h1c, 2048, f2T + (size_t)c * 2048, 4096,
            fc2_b + l * 1024, dbf, 1024, 8192, 1024, 2048);
      else
        gemm_ring<4, true, false, true><<<dim3(64, 4), 512, 0, stream>>>(
            h1c, 2048, f2T + (size_t)c * 2048, 4096,
            nullptr, dbf, 1024, 8192, 1024, 2048);
    }
    if (l == 3)
      ln2<true><<<8192, 256, 0, stream>>>(vbf, dbf, n3_g + l * 1024, n3_b + l * 1024, nullptr, fout);
    else
      ln2<false><<<8192, 256, 0, stream>>>(vbf, dbf, n3_g + l * 1024, n3_b + l * 1024, vbf, nullptr);
  }
}

// Round 13
// 1191.828 us; speedup vs baseline: 1.1716x; 1.0567x over previous
//
#include <hip/hip_runtime.h>
#include <cstdint>
#include <cstddef>

typedef unsigned short u16;
typedef __attribute__((ext_vector_type(8))) __bf16 bf16x8;
typedef __attribute__((ext_vector_type(4))) float f32x4;

__device__ __forceinline__ f32x4 mfma_16x16x32(bf16x8 a, bf16x8 b, f32x4 c) {
  return __builtin_amdgcn_mfma_f32_16x16x32_bf16(a, b, c, 0, 0, 0);
}

__device__ __forceinline__ u16 f2bf(float f) {
  union { float f; uint32_t u; } c; c.f = f;
  uint32_t u = c.u + 0x7FFFu + ((c.u >> 16) & 1u);
  return (u16)(u >> 16);
}

__device__ __forceinline__ float bf2f(u16 x) {
  union { uint32_t u; float f; } c; c.u = ((uint32_t)x) << 16;
  return c.f;
}

__device__ __forceinline__ void gload_lds16(const void* g, void* l) {
  __builtin_amdgcn_global_load_lds(
      (__attribute__((address_space(1))) void*)(uintptr_t)g,
      (__attribute__((address_space(3))) void*)l, 16, 0, 0);
}

// ===========================================================================
// Ring GEMM (round-5/11 best: FF2 ~50us, conflicts 0 — unchanged).
// MR=8: BM=256, MR=4: BM=128. BN=256. 512 threads = 8 waves (2x4).
// BK=32/step; 4-slot LDS ring; prefetch dist 3; counted vmcnt; ONE barrier
// per K-step. Swizzle sigma(r)=(r>>1)&3 on 16B granules on BOTH sides.
// ===========================================================================
template<int MR, bool OUT_BF16, bool RELU, bool ACC>
__global__ __launch_bounds__(512, 2) void gemm_ring(
    const u16* __restrict__ A, int lda, const u16* __restrict__ Bt, int ldb,
    const float* __restrict__ bias, void* Cout, int ldc,
    int M, int N, int K)
{
  constexpr int BM = MR * 32;
  constexpr int SLOT = (BM + 256) * 32;
  __shared__ u16 ring[4 * SLOT];

  const int tid = threadIdx.x;
  const int lane = tid & 63, wave = tid >> 6;
  const int wm = wave >> 2, wn = wave & 3;
  const int m0 = blockIdx.x * BM, n0 = blockIdx.y * 256;

  const int cA0 = tid, rA0 = cA0 >> 2;
  const u16* gA0 = A + (size_t)(m0 + rA0) * lda + (((cA0 & 3) ^ ((rA0 >> 1) & 3)) * 8);
  const int cA1 = tid + 512, rA1 = cA1 >> 2;
  const u16* gA1 = A + (size_t)(m0 + (MR == 8 ? rA1 : 0)) * lda + (((cA1 & 3) ^ ((rA1 >> 1) & 3)) * 8);
  const int cB0 = tid, rB0 = cB0 >> 2;
  const int cB1 = tid + 512, rB1 = cB1 >> 2;
  const u16* gB0 = Bt + (size_t)(n0 + rB0) * ldb + (((cB0 & 3) ^ ((rB0 >> 1) & 3)) * 8);
  const u16* gB1 = Bt + (size_t)(n0 + rB1) * ldb + (((cB1 & 3) ^ ((rB1 >> 1) & 3)) * 8);

  const int NK = K >> 5;

  auto STAGE = [&](int s) {
    u16* Sb = &ring[(s & 3) * SLOT];
    const int ko = s * 32;
    gload_lds16(gA0 + ko, Sb + cA0 * 8);
    if constexpr (MR == 8) gload_lds16(gA1 + ko, Sb + cA1 * 8);
    gload_lds16(gB0 + ko, Sb + BM * 32 + cB0 * 8);
    gload_lds16(gB1 + ko, Sb + BM * 32 + cB1 * 8);
  };
  auto WAITV = [&](int ahead) {
    if (ahead >= 2) {
      if constexpr (MR == 8) asm volatile("s_waitcnt vmcnt(8)" ::: "memory");
      else                   asm volatile("s_waitcnt vmcnt(6)" ::: "memory");
    } else if (ahead == 1) {
      if constexpr (MR == 8) asm volatile("s_waitcnt vmcnt(4)" ::: "memory");
      else                   asm volatile("s_waitcnt vmcnt(3)" ::: "memory");
    } else {
      asm volatile("s_waitcnt vmcnt(0)" ::: "memory");
    }
  };

  const int fr = lane & 15, g = lane >> 4;
  const int foff = fr * 32 + ((g ^ ((fr >> 1) & 3)) * 8);

  f32x4 acc[MR][4];
  #pragma unroll
  for (int m = 0; m < MR; m++)
    #pragma unroll
    for (int n = 0; n < 4; n++) acc[m][n] = f32x4{0.f, 0.f, 0.f, 0.f};

  for (int i = 0; i < 3 && i < NK; ++i) STAGE(i);
  WAITV(NK - 1 < 2 ? NK - 1 : 2);
  __builtin_amdgcn_s_barrier();
  __builtin_amdgcn_sched_barrier(0);

  for (int s = 0; s < NK; ++s) {
    const u16* As = &ring[(s & 3) * SLOT];
    const u16* Bs = As + BM * 32;

    bf16x8 bf[4];
    #pragma unroll
    for (int n = 0; n < 4; n++)
      bf[n] = *(const bf16x8*)(Bs + (wn * 64 + n * 16) * 32 + foff);
    bf16x8 af[4];
    #pragma unroll
    for (int m = 0; m < 4; m++)
      af[m] = *(const bf16x8*)(As + (wm * (MR * 16) + m * 16) * 32 + foff);

    if (s + 3 < NK) STAGE(s + 3);

    __builtin_amdgcn_s_setprio(1);
    #pragma unroll
    for (int m = 0; m < 4; m++)
      #pragma unroll
      for (int n = 0; n < 4; n++)
        acc[m][n] = mfma_16x16x32(af[m], bf[n], acc[m][n]);
    __builtin_amdgcn_s_setprio(0);

    if constexpr (MR == 8) {
      bf16x8 af2[4];
      #pragma unroll
      for (int m = 0; m < 4; m++)
        af2[m] = *(const bf16x8*)(As + (wm * 128 + (m + 4) * 16) * 32 + foff);
      __builtin_amdgcn_s_setprio(1);
      #pragma unroll
      for (int m = 0; m < 4; m++)
        #pragma unroll
        for (int n = 0; n < 4; n++)
          acc[m + 4][n] = mfma_16x16x32(af2[m], bf[n], acc[m + 4][n]);
      __builtin_amdgcn_s_setprio(0);
    }

    {
      int im = (s + 3 < NK - 1) ? s + 3 : NK - 1;
      WAITV(im - (s + 1));
    }
    asm volatile("s_waitcnt lgkmcnt(0)" ::: "memory");
    __builtin_amdgcn_sched_barrier(0);
    __builtin_amdgcn_s_barrier();
    __builtin_amdgcn_sched_barrier(0);
  }

  #pragma unroll
  for (int n = 0; n < 4; n++) {
    const int gcol = n0 + wn * 64 + n * 16 + fr;
    const float bv = bias ? bias[gcol] : 0.f;
    #pragma unroll
    for (int m = 0; m < MR; m++) {
      #pragma unroll
      for (int r = 0; r < 4; r++) {
        const int grow = m0 + wm * (MR * 16) + m * 16 + g * 4 + r;
        float v = acc[m][n][r] + bv;
        if (ACC) v += bf2f(((const u16*)Cout)[(size_t)grow * ldc + gcol]);
        if (RELU) v = fmaxf(v, 0.f);
        if (OUT_BF16) ((u16*)Cout)[(size_t)grow * ldc + gcol] = f2bf(v);
        else         ((float*)Cout)[(size_t)grow * ldc + gcol] = v;
      }
    }
  }
}

// ---------------------------------------------------------------------------
// Merged K+V projection GEMM (round-11, verified).
// ---------------------------------------------------------------------------
__global__ __launch_bounds__(256, 2) void gemm_kv(
    const u16* __restrict__ A, const u16* __restrict__ Bt,
    const float* __restrict__ biasK, const float* __restrict__ biasV,
    u16* __restrict__ kbf, u16* __restrict__ vtb, int M, int K)
{
  __shared__ u16 ldsA[128 * 32];
  __shared__ u16 ldsB[128 * 32];

  const int tid = threadIdx.x;
  const int lane = tid & 63, wave = tid >> 6;
  const int wr = wave >> 1, wc = wave & 1;
  const int m0 = blockIdx.x * 128, n0 = blockIdx.y * 128;

  const int c0 = tid, c1 = tid + 256;
  const int ar0 = c0 >> 2, ak0 = (c0 & 3) * 8;
  const int ar1 = c1 >> 2, ak1 = (c1 & 3) * 8;

  const bool av0 = (m0 + ar0) < M;
  const bool av1 = (m0 + ar1) < M;
  const u16* Ag0 = A + (size_t)(m0 + ar0) * K + ak0;
  const u16* Ag1 = A + (size_t)(m0 + ar1) * K + ak1;
  const u16* Bg0 = Bt + (size_t)(n0 + ar0) * K + ak0;
  const u16* Bg1 = Bt + (size_t)(n0 + ar1) * K + ak1;

  f32x4 acc[4][4] = {};
  const int fr = lane & 15, fo = (lane >> 4) * 8;

  for (int k0 = 0; k0 < K; k0 += 32) {
    if (av0) gload_lds16(Ag0 + k0, &ldsA[c0 * 8]);
    if (av1) gload_lds16(Ag1 + k0, &ldsA[c1 * 8]);
    gload_lds16(Bg0 + k0, &ldsB[c0 * 8]);
    gload_lds16(Bg1 + k0, &ldsB[c1 * 8]);
    asm volatile("s_waitcnt vmcnt(0)" ::: "memory");
    __syncthreads();

    bf16x8 af[4], bfr[4];
    #pragma unroll
    for (int m = 0; m < 4; m++)
      af[m] = *(const bf16x8*)&ldsA[(wr * 64 + m * 16 + fr) * 32 + fo];
    #pragma unroll
    for (int n = 0; n < 4; n++)
      bfr[n] = *(const bf16x8*)&ldsB[(wc * 64 + n * 16 + fr) * 32 + fo];
    #pragma unroll
    for (int m = 0; m < 4; m++)
      #pragma unroll
      for (int n = 0; n < 4; n++)
        acc[m][n] = mfma_16x16x32(af[m], bfr[n], acc[m][n]);
    __syncthreads();
  }

  const int g = lane >> 4;
  #pragma unroll
  for (int m = 0; m < 4; m++) {
    #pragma unroll
    for (int n = 0; n < 4; n++) {
      const int gcol = n0 + wc * 64 + n * 16 + fr;
      const bool isK = gcol < 1024;
      const int vc = isK ? gcol : gcol - 1024;
      const float bv = isK ? biasK[vc] : biasV[vc];
      #pragma unroll
      for (int r = 0; r < 4; r++) {
        const int grow = m0 + wr * 64 + m * 16 + g * 4 + r;
        if (grow < M) {
          float v = acc[m][n][r] + bv;
          if (isK) {
            kbf[(size_t)grow * 1024 + vc] = f2bf(v);
          } else {
            int bb = grow / 100, jj = grow - bb * 100;
            int h = vc >> 6, d = vc & 63;
            vtb[(size_t)(((bb * 16 + h) * 64 + d)) * 128 + jj] = f2bf(v);
          }
        }
      }
    }
  }
}

// ---------------------------------------------------------------------------
// Weight transpose+convert v2: src f32 [K][N] -> dst bf16 [N][K]
// ---------------------------------------------------------------------------
__global__ __launch_bounds__(256) void wconv2(const float* __restrict__ src,
                                              u16* __restrict__ dst,
                                              int K, int N)
{
  __shared__ float tile[64][33];
  const int n0 = blockIdx.x * 32, k0 = blockIdx.y * 64;
  const int tx = threadIdx.x & 31, ty = threadIdx.x >> 5;   // 32 x 8
  #pragma unroll
  for (int i = 0; i < 8; i++)
    tile[ty + i * 8][tx] = src[(size_t)(k0 + ty + i * 8) * N + n0 + tx];
  __syncthreads();
  #pragma unroll
  for (int j = 0; j < 4; j++) {
    int n = ty + j * 8;
    uint32_t lo = f2bf(tile[2 * tx][n]);
    uint32_t hi = f2bf(tile[2 * tx + 1][n]);
    *(uint32_t*)&dst[(size_t)(n0 + n) * K + k0 + 2 * tx] = lo | (hi << 16);
  }
}

// ---------------------------------------------------------------------------
// Positional encoding add -> bf16 only (fast-math trig)
// ---------------------------------------------------------------------------
__global__ __launch_bounds__(256) void pe_video_k(const float* __restrict__ video,
                                                  u16* __restrict__ vbf)
{
  const int r = blockIdx.x;
  const int s = r & 2047;
  const int d0 = threadIdx.x * 4;
  const size_t base = (size_t)r * 1024 + d0;
  float4 v = *(const float4*)&video[base];
  const float coef = -9.210340371976184f / 1024.f;
  float o[4];
  float in[4] = {v.x, v.y, v.z, v.w};
  #pragma unroll
  for (int i = 0; i < 4; i++) {
    int d = d0 + i;
    int j = d >> 1;
    float dv = __expf((float)(2 * j) * coef);
    float arg = (float)s * dv;
    float pe = (d & 1) ? __cosf(arg) : __sinf(arg);
    o[i] = in[i] + pe;
  }
  uint2 pk;
  pk.x = (uint32_t)f2bf(o[0]) | ((uint32_t)f2bf(o[1]) << 16);
  pk.y = (uint32_t)f2bf(o[2]) | ((uint32_t)f2bf(o[3]) << 16);
  *(uint2*)&vbf[base] = pk;
}

__global__ __launch_bounds__(128) void pe_text_k(const float* __restrict__ text,
                                                 u16* __restrict__ tbf)
{
  const int r = blockIdx.x;
  const int s = r % 100;
  const int d0 = threadIdx.x * 4;
  const size_t base = (size_t)r * 512 + d0;
  float4 v = *(const float4*)&text[base];
  const float coef = -9.210340371976184f / 512.f;
  float o[4];
  float in[4] = {v.x, v.y, v.z, v.w};
  #pragma unroll
  for (int i = 0; i < 4; i++) {
    int d = d0 + i;
    int j = d >> 1;
    float dv = __expf((float)(2 * j) * coef);
    float arg = (float)s * dv;
    float pe = (d & 1) ? __cosf(arg) : __sinf(arg);
    o[i] = in[i] + pe;
  }
  uint2 pk;
  pk.x = (uint32_t)f2bf(o[0]) | ((uint32_t)f2bf(o[1]) << 16);
  pk.y = (uint32_t)f2bf(o[2]) | ((uint32_t)f2bf(o[3]) << 16);
  *(uint2*)&tbf[base] = pk;
}

// ---------------------------------------------------------------------------
// LayerNorm, bf16 residual stream: x' = LN(x + delta)*g+b
// ---------------------------------------------------------------------------
template<bool LAST>
__global__ __launch_bounds__(256) void ln2(const u16* __restrict__ xin,
                                           const u16* __restrict__ delta,
                                           const float* __restrict__ gamma,
                                           const float* __restrict__ beta,
                                           u16* __restrict__ xbf,
                                           float* __restrict__ fout)
{
  const int row = blockIdx.x;
  const size_t base = (size_t)row * 1024;
  const int t = threadIdx.x;
  const int d0 = t * 4;
  uint2 xv = *(const uint2*)&xin[base + d0];
  uint2 dv = *(const uint2*)&delta[base + d0];
  float v0 = bf2f((u16)(xv.x & 0xFFFF)) + bf2f((u16)(dv.x & 0xFFFF));
  float v1 = bf2f((u16)(xv.x >> 16))    + bf2f((u16)(dv.x >> 16));
  float v2 = bf2f((u16)(xv.y & 0xFFFF)) + bf2f((u16)(dv.y & 0xFFFF));
  float v3 = bf2f((u16)(xv.y >> 16))    + bf2f((u16)(dv.y >> 16));
  float s = v0 + v1 + v2 + v3;
  float q = v0 * v0 + v1 * v1 + v2 * v2 + v3 * v3;
  #pragma unroll
  for (int d = 32; d >= 1; d >>= 1) { s += __shfl_xor(s, d); q += __shfl_xor(q, d); }
  __shared__ float red[8];
  const int lane = t & 63, w = t >> 6;
  if (lane == 0) { red[w] = s; red[4 + w] = q; }
  __syncthreads();
  float S = red[0] + red[1] + red[2] + red[3];
  float Qs = red[4] + red[5] + red[6] + red[7];
  const float mu = S * (1.f / 1024.f);
  const float var = Qs * (1.f / 1024.f) - mu * mu;
  const float rs = rsqrtf(var + 1e-5f);
  float4 gv = *(const float4*)&gamma[d0];
  float4 bv = *(const float4*)&beta[d0];
  float o0 = (v0 - mu) * rs * gv.x + bv.x;
  float o1 = (v1 - mu) * rs * gv.y + bv.y;
  float o2 = (v2 - mu) * rs * gv.z + bv.z;
  float o3 = (v3 - mu) * rs * gv.w + bv.w;
  if (LAST) {
    *(float4*)&fout[base + d0] = make_float4(o0, o1, o2, o3);
  } else {
    uint2 pk;
    pk.x = (uint32_t)f2bf(o0) | ((uint32_t)f2bf(o1) << 16);
    pk.y = (uint32_t)f2bf(o2) | ((uint32_t)f2bf(o3) << 16);
    *(uint2*)&xbf[base + d0] = pk;
  }
}

// ---------------------------------------------------------------------------
// Cross attention v2 (verified).
// ---------------------------------------------------------------------------
__global__ __launch_bounds__(256) void attn_v2(
    const u16* __restrict__ Q, const u16* __restrict__ Kb,
    const u16* __restrict__ Vtb, const int* __restrict__ mask,
    u16* __restrict__ Out)
{
  __shared__ u16 ldsP[64 * 136];

  const int tid = threadIdx.x, lane = tid & 63, w = tid >> 6;
  const int qb = blockIdx.x, bh = blockIdx.y;
  const int b = bh >> 4, h = bh & 15;
  const int fr = lane & 15, g = lane >> 4, fo = g * 8;

  const size_t qrow = (size_t)(b * 2048 + qb * 64 + w * 16 + fr) * 1024 + h * 64;
  bf16x8 qf0 = *(const bf16x8*)&Q[qrow + fo];
  bf16x8 qf1 = *(const bf16x8*)&Q[qrow + 32 + fo];

  float madd[7];
  #pragma unroll
  for (int t = 0; t < 7; t++) {
    int col = t * 16 + fr;
    int mv = (col < 100) ? mask[b * 100 + col] : 0;
    madd[t] = mv ? 0.f : -1e30f;
  }

  float sc[7][4];
  #pragma unroll
  for (int t = 0; t < 7; t++) {
    int col = t * 16 + fr;
    int jr = (col < 100) ? col : 99;
    const u16* kp = Kb + (size_t)(b * 100 + jr) * 1024 + h * 64;
    bf16x8 kf0 = *(const bf16x8*)&kp[fo];
    bf16x8 kf1 = *(const bf16x8*)&kp[32 + fo];
    f32x4 a = {};
    a = mfma_16x16x32(qf0, kf0, a);
    a = mfma_16x16x32(qf1, kf1, a);
    #pragma unroll
    for (int r = 0; r < 4; r++)
      sc[t][r] = a[r] * 0.125f + madd[t];
  }

  #pragma unroll
  for (int r = 0; r < 4; r++) {
    float m = sc[0][r];
    #pragma unroll
    for (int t = 1; t < 7; t++) m = fmaxf(m, sc[t][r]);
    #pragma unroll
    for (int d = 8; d >= 1; d >>= 1) m = fmaxf(m, __shfl_xor(m, d));
    float ssum = 0.f;
    #pragma unroll
    for (int t = 0; t < 7; t++) { float p = __expf(sc[t][r] - m); sc[t][r] = p; ssum += p; }
    #pragma unroll
    for (int d = 8; d >= 1; d >>= 1) ssum += __shfl_xor(ssum, d);
    float is = 1.f / ssum;
    #pragma unroll
    for (int t = 0; t < 7; t++)
      ldsP[(w * 16 + g * 4 + r) * 136 + t * 16 + fr] = f2bf(sc[t][r] * is);
  }
  {
    u16* zp = &ldsP[(w * 16 + fr) * 136 + 112 + g * 6];
    #pragma unroll
    for (int i = 0; i < 6; i++) zp[i] = 0;
  }

  bf16x8 pa[4];
  #pragma unroll
  for (int kk = 0; kk < 4; kk++)
    pa[kk] = *(const bf16x8*)&ldsP[(w * 16 + fr) * 136 + kk * 32 + fo];
  const u16* vtbase = Vtb + (size_t)bh * 64 * 128;
  #pragma unroll
  for (int nt = 0; nt < 4; nt++) {
    f32x4 a = {};
    #pragma unroll
    for (int kk = 0; kk < 4; kk++) {
      bf16x8 vf = *(const bf16x8*)&vtbase[(size_t)(nt * 16 + fr) * 128 + kk * 32 + fo];
      a = mfma_16x16x32(pa[kk], vf, a);
    }
    #pragma unroll
    for (int r = 0; r < 4; r++) {
      size_t orow = (size_t)(b * 2048 + qb * 64 + w * 16 + g * 4 + r) * 1024 + h * 64 + nt * 16 + fr;
      Out[orow] = f2bf(a[r]);
    }
  }
}

// ---------------------------------------------------------------------------
extern "C" void kernel_launch(void* const* d_in, const int* in_sizes, int n_in,
                              void* d_out, int out_size, void* d_ws, size_t ws_size,
                              hipStream_t stream) {
  const float* video = (const float*)d_in[0];
  const float* text  = (const float*)d_in[1];
  const int*   text_mask = (const int*)d_in[2];
  const float* Wq_w = (const float*)d_in[3];
  const float* Wq_b = (const float*)d_in[4];
  const float* Wk_w = (const float*)d_in[5];
  const float* Wk_b = (const float*)d_in[6];
  const float* Wv_w = (const float*)d_in[7];
  const float* Wv_b = (const float*)d_in[8];
  const float* Wo_w = (const float*)d_in[9];
  const float* Wo_b = (const float*)d_in[10];
  const float* fc1_w = (const float*)d_in[11];
  const float* fc1_b = (const float*)d_in[12];
  const float* fc2_w = (const float*)d_in[13];
  const float* fc2_b = (const float*)d_in[14];
  const float* n2_g = (const float*)d_in[15];
  const float* n2_b = (const float*)d_in[16];
  const float* n3_g = (const float*)d_in[17];
  const float* n3_b = (const float*)d_in[18];

  char* ws = (char*)d_ws;
  size_t off = 0;
  auto alloc = [&](size_t bytes) {
    char* p = ws + off;
    off += (bytes + 255) & ~(size_t)255;
    return p;
  };
  u16* vbf = (u16*)alloc((size_t)8192 * 1024 * 2);     // 16 MB residual (bf16)
  u16* tbf = (u16*)alloc((size_t)400 * 512 * 2);
  u16* wqT = (u16*)alloc((size_t)1024 * 1024 * 2);
  u16* wkT = (u16*)alloc((size_t)1024 * 512 * 2);      // contiguous with wvT
  u16* wvT = (u16*)alloc((size_t)1024 * 512 * 2);
  u16* woT = (u16*)alloc((size_t)1024 * 1024 * 2);
  u16* f1T = (u16*)alloc((size_t)4096 * 1024 * 2);
  u16* f2T = (u16*)alloc((size_t)1024 * 4096 * 2);

  // Decide FF layout based on actual ws_size:
  //   big:   S region = 64 MB (h1 full 8192x4096 aliasing dead qbf/kbf/abf)
  //   small: S region = 33.6 MB (h1c chunk 8192x2048 aliasing qbf/kbf/abf)
  // remaining fixed tail: vtb 1 MB + dbf 16 MB.
  const size_t smallS = 35192832;           // round-12 layout
  const size_t bigS   = (size_t)8192 * 4096 * 2;   // 64 MB
  const size_t tailNeed = 1048576 + 256 + (size_t)8192 * 1024 * 2 + 256;
  const bool big = ws_size >= off + bigS + 256 + tailNeed;

  char* S = alloc(big ? bigS : smallS);
  u16* qbf  = (u16*)S;
  u16* kbf  = (u16*)(S + 16777216);
  u16* abf  = (u16*)(S + 16777216 + 1638400);
  u16* h1   = (u16*)S;                       // big: 8192x4096; small: 8192x2048
  u16* vtb  = (u16*)alloc((size_t)64 * 64 * 128 * 2);  // 1 MB V^T (not aliased)
  u16* dbf  = (u16*)alloc((size_t)8192 * 1024 * 2);
  float* fout = (float*)d_out;

  hipMemsetAsync(vtb, 0, (size_t)64 * 64 * 128 * 2, stream);

  pe_video_k<<<8192, 256, 0, stream>>>(video, vbf);
  pe_text_k<<<400, 128, 0, stream>>>(text, tbf);

  for (int l = 0; l < 4; ++l) {
    wconv2<<<dim3(32, 16), 256, 0, stream>>>(Wq_w + (size_t)l * 1024 * 1024, wqT, 1024, 1024);
    wconv2<<<dim3(32, 8), 256, 0, stream>>>(Wk_w + (size_t)l * 512 * 1024, wkT, 512, 1024);
    wconv2<<<dim3(32, 8), 256, 0, stream>>>(Wv_w + (size_t)l * 512 * 1024, wvT, 512, 1024);
    wconv2<<<dim3(32, 16), 256, 0, stream>>>(Wo_w + (size_t)l * 1024 * 1024, woT, 1024, 1024);
    wconv2<<<dim3(128, 16), 256, 0, stream>>>(fc1_w + (size_t)l * 1024 * 4096, f1T, 1024, 4096);
    wconv2<<<dim3(32, 64), 256, 0, stream>>>(fc2_w + (size_t)l * 4096 * 1024, f2T, 4096, 1024);

    gemm_ring<4, true, false, false><<<dim3(64, 4), 512, 0, stream>>>(
        vbf, 1024, wqT, 1024, Wq_b + l * 1024, qbf, 1024, 8192, 1024, 1024);
    gemm_kv<<<dim3(4, 16), 256, 0, stream>>>(
        tbf, wkT, Wk_b + l * 1024, Wv_b + l * 1024, kbf, vtb, 400, 512);
    attn_v2<<<dim3(32, 64), 256, 0, stream>>>(qbf, kbf, vtb, text_mask, abf);
    gemm_ring<4, true, false, false><<<dim3(64, 4), 512, 0, stream>>>(
        abf, 1024, woT, 1024, Wo_b + l * 1024, dbf, 1024, 8192, 1024, 1024);
    ln2<false><<<8192, 256, 0, stream>>>(vbf, dbf, n2_g + l * 1024, n2_b + l * 1024, vbf, nullptr);

    if (big) {
      // FF1 once: h1[8192][4096] = relu(vbf @ f1T^T + b1)
      gemm_ring<8, true, true, false><<<dim3(32, 16), 512, 0, stream>>>(
          vbf, 1024, f1T, 1024, fc1_b + l * 4096, h1, 4096, 8192, 4096, 1024);
      // FF2 once: dbf = h1 @ f2T^T + b2   (K=4096, no ACC pass)
      gemm_ring<4, true, false, false><<<dim3(64, 4), 512, 0, stream>>>(
          h1, 4096, f2T, 4096, fc2_b + l * 1024, dbf, 1024, 8192, 1024, 4096);
    } else {
      for (int c = 0; c < 2; ++c) {
        gemm_ring<8, true, true, false><<<dim3(32, 8), 512, 0, stream>>>(
            vbf, 1024, f1T + (size_t)c * 2048 * 1024, 1024,
            fc1_b + l * 4096 + c * 2048, h1, 2048, 8192, 2048, 1024);
        if (c == 0)
          gemm_ring<4, true, false, false><<<dim3(64, 4), 512, 0, stream>>>(
              h1, 2048, f2T + (size_t)c * 2048, 4096,
              fc2_b + l * 1024, dbf, 1024, 8192, 1024, 2048);
        else
          gemm_ring<4, true, false, true><<<dim3(64, 4), 512, 0, stream>>>(
              h1, 2048, f2T + (size_t)c * 2048, 4096,
              nullptr, dbf, 1024, 8192, 1024, 2048);
      }
    }
    if (l == 3)
      ln2<true><<<8192, 256, 0, stream>>>(vbf, dbf, n3_g + l * 1024, n3_b + l * 1024, nullptr, fout);
    else
      ln2<false><<<8192, 256, 0, stream>>>(vbf, dbf, n3_g + l * 1024, n3_b + l * 1024, vbf, nullptr);
  }
}